// Round 6
// baseline (1555.696 us; speedup 1.0000x reference)
//
#include <hip/hip_runtime.h>

#define NNODES 65536
#define NEDGES 1048576
#define NGRAPH 64
#define NPERG  1024
#define KEEP   512
#define M2     (NGRAPH * KEEP)   // 32768
#define HD     128
#define NC     10

// canonical weight block offsets (floats)
#define OW1 0
#define OW2 16384
#define OWL 32768
#define OB1 34048
#define OB2 34176
#define OP  34304
#define OBL 34432
#define NCVT 34448

__device__ __forceinline__ float bf2f(unsigned short u) {
    return __uint_as_float(((unsigned int)u) << 16);
}
__device__ __forceinline__ unsigned short f2bf(float f) {
    unsigned int u = __float_as_uint(f);
    unsigned int r = (u + 0x7FFFu + ((u >> 16) & 1u)) >> 16;
    return (unsigned short)r;
}

// ---------------- dtype detector: 1 = bf16 storage, 0 = fp32 storage ---------
__global__ void detect_kernel(const unsigned short* __restrict__ w1u, int* __restrict__ flag) {
    __shared__ int cnt;
    int t = threadIdx.x;  // 256
    if (t == 0) cnt = 0;
    __syncthreads();
    int local = 0;
    for (int i = t; i < 512; i += 256) {
        unsigned short u = w1u[2 * i];
        int e = (u >> 7) & 0xFF;
        if (e >= 100 && e <= 140) local++;
    }
    atomicAdd(&cnt, local);
    __syncthreads();
    if (t == 0) flag[0] = (cnt >= 384) ? 1 : 0;
}

// ---------------- canonicalize small weights to fp32 -------------------------
__global__ void cvt_kernel(const void* __restrict__ W1, const void* __restrict__ b1,
                           const void* __restrict__ p, const void* __restrict__ W2,
                           const void* __restrict__ b2, const void* __restrict__ Wl,
                           const void* __restrict__ bl, const int* __restrict__ flag,
                           float* __restrict__ out) {
    int gid = blockIdx.x * 256 + threadIdx.x;
    if (gid >= NCVT) return;
    const void* srcp; int idx;
    if (gid < OB1) {
        if (gid < OW2)      { srcp = W1; idx = gid - OW1; }
        else if (gid < OWL) { srcp = W2; idx = gid - OW2; }
        else                { srcp = Wl; idx = gid - OWL; }
    } else {
        if (gid < OB2)      { srcp = b1; idx = gid - OB1; }
        else if (gid < OP)  { srcp = b2; idx = gid - OB2; }
        else if (gid < OBL) { srcp = p;  idx = gid - OP; }
        else                { srcp = bl; idx = gid - OBL; }
    }
    if (gid >= OWL && gid < OB1 && idx >= 1280) { out[gid] = 0.f; return; }   // Wl pad
    if (gid >= OBL && idx >= NC) { out[gid] = 0.f; return; }                  // bl pad
    float v;
    if (flag[0]) v = bf2f(((const unsigned short*)srcp)[idx]);
    else         v = ((const float*)srcp)[idx];
    out[gid] = v;
}

// ---------------- init: deg=0, new_id=-1, ghist=0 ----------------------------
__global__ void init_kernel(int* __restrict__ deg1, int* __restrict__ deg2,
                            int* __restrict__ new_id, int* __restrict__ ghist) {
    int i = blockIdx.x * 256 + threadIdx.x;  // NNODES threads
    deg1[i] = 0;
    new_id[i] = -1;
    if (i < M2) deg2[i] = 0;
    if (i < NGRAPH) ghist[i] = 0;
}

// ---------------- edge binning: histogram -> scan -> placement ---------------
__global__ __launch_bounds__(256) void hist_kernel(const int* __restrict__ src,
                                                   int* __restrict__ ghist) {
    __shared__ int lh[NGRAPH];
    int tid = threadIdx.x;
    if (tid < NGRAPH) lh[tid] = 0;
    __syncthreads();
    int e0 = blockIdx.x * 4096;  // 256 blocks
    for (int k = 0; k < 16; k++) atomicAdd(&lh[src[e0 + k * 256 + tid] >> 10], 1);
    __syncthreads();
    if (tid < NGRAPH) atomicAdd(&ghist[tid], lh[tid]);
}
__global__ void scan_kernel(const int* __restrict__ ghist, int* __restrict__ gbase,
                            int* __restrict__ gcursor, int* __restrict__ gcnt) {
    if (threadIdx.x == 0) {
        int s = 0;
        for (int g = 0; g < NGRAPH; g++) {
            gbase[g] = s; gcursor[g] = s; gcnt[g] = ghist[g]; s += ghist[g];
        }
    }
}
__global__ __launch_bounds__(256) void binpass_kernel(const int* __restrict__ src,
                                                      const int* __restrict__ dst,
                                                      int* __restrict__ gcursor,
                                                      unsigned int* __restrict__ elist) {
    __shared__ int lh[NGRAPH];
    __shared__ int lbase[NGRAPH];
    int tid = threadIdx.x;
    int e0 = blockIdx.x * 4096;  // 256 blocks
    if (tid < NGRAPH) lh[tid] = 0;
    __syncthreads();
    int gs[16]; unsigned int pk[16];
    for (int k = 0; k < 16; k++) {
        int e = e0 + k * 256 + tid;
        int s = src[e], d = dst[e];
        gs[k] = s >> 10;
        pk[k] = (unsigned)(s & 1023) | ((unsigned)(d & 1023) << 10);
        atomicAdd(&lh[gs[k]], 1);
    }
    __syncthreads();
    if (tid < NGRAPH) { lbase[tid] = atomicAdd(&gcursor[tid], lh[tid]); lh[tid] = 0; }
    __syncthreads();
    for (int k = 0; k < 16; k++) {
        int g = gs[k];
        int pos = lbase[g] + atomicAdd(&lh[g], 1);
        elist[pos] = pk[k];
    }
}

// ---------------- GEMM1: C[M,128] = A(flagged dtype)[M,128] @ W[128,128] -----
__global__ __launch_bounds__(256) void gemm_a_kernel(const void* __restrict__ Araw,
                                                     const float* __restrict__ W,
                                                     float* __restrict__ C,
                                                     const int* __restrict__ flag) {
    __shared__ float As[64 * HD];  // 32 KB
    int tid = threadIdx.x;
    int row0 = blockIdx.x * 64;
    if (flag[0]) {
        const unsigned short* Au = (const unsigned short*)Araw + (size_t)row0 * HD;
        for (int i = tid; i < 64 * HD; i += 256) As[i] = bf2f(Au[i]);
    } else {
        const float* Af = (const float*)Araw + (size_t)row0 * HD;
        for (int i = tid; i < 64 * HD / 4; i += 256)
            reinterpret_cast<float4*>(As)[i] = reinterpret_cast<const float4*>(Af)[i];
    }
    __syncthreads();
    int cg = tid & 31;
    int rg = tid >> 5;
    float acc[8][4];
#pragma unroll
    for (int r = 0; r < 8; r++)
#pragma unroll
        for (int c = 0; c < 4; c++) acc[r][c] = 0.f;
    for (int k = 0; k < HD; k++) {
        float4 wv = reinterpret_cast<const float4*>(W + k * HD)[cg];
#pragma unroll
        for (int r = 0; r < 8; r++) {
            float av = As[(rg * 8 + r) * HD + k];
            acc[r][0] += av * wv.x;
            acc[r][1] += av * wv.y;
            acc[r][2] += av * wv.z;
            acc[r][3] += av * wv.w;
        }
    }
#pragma unroll
    for (int r = 0; r < 8; r++) {
        float4 o = {acc[r][0], acc[r][1], acc[r][2], acc[r][3]};
        reinterpret_cast<float4*>(C + (size_t)(row0 + rg * 8 + r) * HD)[cg] = o;
    }
}

// ---------------- GEMM (fp32 A) for conv2 ------------------------------------
__global__ __launch_bounds__(256) void gemm_f32(const float* __restrict__ A,
                                                const float* __restrict__ W,
                                                float* __restrict__ C) {
    __shared__ float As[64 * HD];
    int tid = threadIdx.x;
    int row0 = blockIdx.x * 64;
    for (int i = tid; i < 64 * HD / 4; i += 256)
        reinterpret_cast<float4*>(As)[i] =
            reinterpret_cast<const float4*>(A + (size_t)row0 * HD)[i];
    __syncthreads();
    int cg = tid & 31;
    int rg = tid >> 5;
    float acc[8][4];
#pragma unroll
    for (int r = 0; r < 8; r++)
#pragma unroll
        for (int c = 0; c < 4; c++) acc[r][c] = 0.f;
    for (int k = 0; k < HD; k++) {
        float4 wv = reinterpret_cast<const float4*>(W + k * HD)[cg];
#pragma unroll
        for (int r = 0; r < 8; r++) {
            float av = As[(rg * 8 + r) * HD + k];
            acc[r][0] += av * wv.x;
            acc[r][1] += av * wv.y;
            acc[r][2] += av * wv.z;
            acc[r][3] += av * wv.w;
        }
    }
#pragma unroll
    for (int r = 0; r < 8; r++) {
        float4 o = {acc[r][0], acc[r][1], acc[r][2], acc[r][3]};
        reinterpret_cast<float4*>(C + (size_t)(row0 + rg * 8 + r) * HD)[cg] = o;
    }
}

// ---------------- p-norm -----------------------------------------------------
__global__ void pnorm_kernel(const float* __restrict__ p, float* __restrict__ invnorm) {
    int t = threadIdx.x;  // 128
    float v = p[t];
    v = v * v;
    for (int off = 32; off; off >>= 1) v += __shfl_down(v, off);
    __shared__ float s[2];
    if ((t & 63) == 0) s[t >> 6] = v;
    __syncthreads();
    if (t == 0) invnorm[0] = 1.0f / sqrtf(s[0] + s[1]);
}

// ---------------- degree / dinv ----------------------------------------------
__global__ void deg1_kernel(const int* __restrict__ dst, int* __restrict__ deg) {
    int e = blockIdx.x * 256 + threadIdx.x;
    atomicAdd(&deg[dst[e]], 1);
}
__global__ void deg2_kernel(const int* __restrict__ src, const int* __restrict__ dst,
                            const int* __restrict__ new_id, int* __restrict__ deg) {
    int e = blockIdx.x * 256 + threadIdx.x;
    int ns = new_id[src[e]], nd = new_id[dst[e]];
    if ((ns | nd) >= 0) atomicAdd(&deg[nd], 1);
}
__global__ void dinv_kernel(const int* __restrict__ deg, float* __restrict__ dinv) {
    int i = blockIdx.x * 256 + threadIdx.x;
    dinv[i] = rsqrtf((float)deg[i] + 1.0f);
}

// ---------------- fused conv1 aggregate: LDS accum + selfinit + relu ---------
// One block per (graph, 16-channel chunk): 64 KB LDS accumulator.
__global__ __launch_bounds__(256) void s1_fused(const unsigned int* __restrict__ elist,
                                                const int* __restrict__ gbase,
                                                const int* __restrict__ gcnt,
                                                const float* __restrict__ dinv,
                                                const float* __restrict__ xw,
                                                const float* __restrict__ b1,
                                                float* __restrict__ h) {
    __shared__ float acc[NPERG * 16];  // 64 KB
    int g = blockIdx.x >> 3, ch0 = (blockIdx.x & 7) * 16;
    int tid = threadIdx.x;
    for (int i = tid; i < NPERG * 16; i += 256) acc[i] = 0.f;
    __syncthreads();
    int base = gbase[g], cnt = gcnt[g];
    int sub = tid >> 4;   // edge sub-slot 0..15
    int c = tid & 15;     // channel within chunk
    const float* dg = dinv + g * NPERG;
    const float* xg = xw + (size_t)g * NPERG * HD;
    for (int j = sub; j < cnt; j += 16) {
        unsigned int pk = elist[base + j];
        int s = pk & 1023, d = (pk >> 10) & 1023;
        float coef = dg[s] * dg[d];
        float v = coef * xg[s * HD + ch0 + c];
        atomicAdd(&acc[d * 16 + c], v);
    }
    __syncthreads();
    for (int i = tid; i < NPERG * 16; i += 256) {
        int n = i >> 4, cc = i & 15;
        float di = dg[n];
        float val = acc[i] + di * di * xg[n * HD + ch0 + cc] + b1[ch0 + cc];
        h[(size_t)(g * NPERG + n) * HD + ch0 + cc] = fmaxf(val, 0.f);
    }
}

// ---------------- fused conv2 aggregate: LDS accum + mask + selfinit + relu --
// One block per (graph, 32-channel chunk): 64 KB LDS accumulator.
__global__ __launch_bounds__(256) void s2_fused(const unsigned int* __restrict__ elist,
                                                const int* __restrict__ gbase,
                                                const int* __restrict__ gcnt,
                                                const int* __restrict__ new_id,
                                                const float* __restrict__ dinv2,
                                                const float* __restrict__ xw2,
                                                const float* __restrict__ b2,
                                                float* __restrict__ h3) {
    __shared__ float acc[KEEP * 32];  // 64 KB
    int g = blockIdx.x >> 2, ch0 = (blockIdx.x & 3) * 32;
    int tid = threadIdx.x;
    for (int i = tid; i < KEEP * 32; i += 256) acc[i] = 0.f;
    __syncthreads();
    int base = gbase[g], cnt = gcnt[g];
    int sub = tid >> 5;   // edge sub-slot 0..7
    int c = tid & 31;     // channel within chunk
    const int* nidg = new_id + g * NPERG;
    const float* d2g = dinv2 + g * KEEP;
    const float* x2g = xw2 + (size_t)g * KEEP * HD;
    for (int j = sub; j < cnt; j += 8) {
        unsigned int pk = elist[base + j];
        int s = pk & 1023, d = (pk >> 10) & 1023;
        int ns = nidg[s], nd = nidg[d];
        if ((ns | nd) >= 0) {
            int sl = ns & (KEEP - 1), dl = nd & (KEEP - 1);
            float coef = d2g[sl] * d2g[dl];
            float v = coef * x2g[sl * HD + ch0 + c];
            atomicAdd(&acc[dl * 32 + c], v);
        }
    }
    __syncthreads();
    for (int i = tid; i < KEEP * 32; i += 256) {
        int n = i >> 5, cc = i & 31;
        float di = d2g[n];
        float val = acc[i] + di * di * x2g[n * HD + ch0 + cc] + b2[ch0 + cc];
        h3[(size_t)(g * KEEP + n) * HD + ch0 + cc] = fmaxf(val, 0.f);
    }
}

// ---------------- score = tanh(h.p * invnorm) --------------------------------
__global__ __launch_bounds__(256) void score_kernel(const float* __restrict__ h,
                                                    const float* __restrict__ p,
                                                    const float* __restrict__ invnorm,
                                                    float* __restrict__ score) {
    int gid = blockIdx.x * 256 + threadIdx.x;
    int row = gid >> 6, lane = gid & 63;
    float v = h[(size_t)row * HD + lane] * p[lane] +
              h[(size_t)row * HD + lane + 64] * p[lane + 64];
    for (int off = 32; off; off >>= 1) v += __shfl_down(v, off);
    if (lane == 0) score[row] = tanhf(v * invnorm[0]);
}

// ---------------- per-graph top-512 via bitonic sort of 1024 -----------------
__global__ __launch_bounds__(1024) void topk_kernel(const float* __restrict__ score,
                                                    float* __restrict__ vals,
                                                    int* __restrict__ perm,
                                                    int* __restrict__ new_id) {
    __shared__ float sv[1024];
    __shared__ int si[1024];
    int g = blockIdx.x, t = threadIdx.x;
    sv[t] = score[g * NPERG + t];
    si[t] = t;
    __syncthreads();
    for (int k = 2; k <= 1024; k <<= 1) {
        for (int j = k >> 1; j > 0; j >>= 1) {
            int l = t ^ j;
            if (l > t) {
                bool desc = ((t & k) == 0);
                float va = sv[t], vb = sv[l];
                int ia = si[t], ib = si[l];
                bool gab = (va > vb) || (va == vb && ia < ib);  // lax.top_k tie rule
                if (gab != desc) { sv[t] = vb; si[t] = ib; sv[l] = va; si[l] = ia; }
            }
            __syncthreads();
        }
    }
    if (t < KEEP) {
        int node = g * NPERG + si[t];
        int slot = g * KEEP + t;
        vals[slot] = sv[t];
        perm[slot] = node;
        new_id[node] = slot;
    }
}

// ---------------- gather + gate (fp32) ---------------------------------------
__global__ void gather_kernel(const float* __restrict__ h, const int* __restrict__ perm,
                              const float* __restrict__ vals, float* __restrict__ h2) {
    int gid = blockIdx.x * 256 + threadIdx.x;
    int i = gid >> 7, c = gid & 127;
    h2[gid] = h[(size_t)perm[i] * HD + c] * vals[i];
}

// ---------------- mean-pool + linear; output dtype follows flag --------------
__global__ __launch_bounds__(512) void pool_kernel(const float* __restrict__ h3,
                                                   const float* __restrict__ Wl,
                                                   const float* __restrict__ bl,
                                                   void* __restrict__ outv,
                                                   const int* __restrict__ flag) {
    int g = blockIdx.x, t = threadIdx.x;  // 512
    int c = t & 127, rg = t >> 7;
    const float* base = h3 + (size_t)g * KEEP * HD;
    float sum = 0.f;
    for (int k = rg; k < KEEP; k += 4) sum += base[(size_t)k * HD + c];
    __shared__ float sp[4][128];
    sp[rg][c] = sum;
    __syncthreads();
    if (t < 128) sp[0][t] = (sp[0][t] + sp[1][t] + sp[2][t] + sp[3][t]) * (1.0f / KEEP);
    __syncthreads();
    if (t < NC) {
        float acc = bl[t];
        for (int hh = 0; hh < HD; hh++) acc += sp[0][hh] * Wl[hh * NC + t];
        if (flag[0]) ((unsigned short*)outv)[g * NC + t] = f2bf(acc);
        else         ((float*)outv)[g * NC + t] = acc;
    }
}

extern "C" void kernel_launch(void* const* d_in, const int* in_sizes, int n_in,
                              void* d_out, int out_size, void* d_ws, size_t ws_size,
                              hipStream_t stream) {
    const int* ei   = (const int*)d_in[1];
    const int* srcv = ei;
    const int* dstv = ei + NEDGES;

    char* w = (char*)d_ws;
    const size_t MB = 1u << 20;
    float* dinv1   = (float*)(w + 0);
    float* score   = (float*)(w + 256 * 1024);
    float* vals    = (float*)(w + 512 * 1024);
    int*   perm    = (int*)(w + 640 * 1024);
    int*   new_id  = (int*)(w + 768 * 1024);
    int*   deg1    = (int*)(w + 1024 * 1024);
    int*   deg2i   = (int*)(w + 1280 * 1024);
    float* dinv2   = (float*)(w + 1408 * 1024);
    float* invnorm = (float*)(w + 1536 * 1024);
    int*   flag    = (int*)(w + 1536 * 1024 + 64);
    float* cw      = (float*)(w + 1664 * 1024);   // canonical fp32 weights
    float* xw1  = (float*)(w + 2 * MB);           // [2,34) MB
    float* agg  = (float*)(w + 34 * MB);          // [34,66) MB   (h)
    float* h2   = (float*)(w + 2 * MB);           // [2,18) MB    (xw1 dead)
    float* xw2  = (float*)(w + 18 * MB);          // [18,34) MB   (xw1 dead)
    float* agg2 = (float*)(w + 34 * MB);          // [34,50) MB   (h dead)
    unsigned int* elist = (unsigned int*)(w + 66 * MB);  // [66,70) MB
    int* ghist   = (int*)(w + 70 * MB);
    int* gbase   = (int*)(w + 70 * MB + 1024);
    int* gcursor = (int*)(w + 70 * MB + 2048);
    int* gcnt    = (int*)(w + 70 * MB + 3072);

    float* W1f = cw + OW1; float* W2f = cw + OW2; float* Wlf = cw + OWL;
    float* b1f = cw + OB1; float* b2f = cw + OB2; float* pf  = cw + OP;
    float* blf = cw + OBL;

    detect_kernel<<<1, 256, 0, stream>>>((const unsigned short*)d_in[3], flag);
    cvt_kernel<<<(NCVT + 255) / 256, 256, 0, stream>>>(d_in[3], d_in[4], d_in[5], d_in[6],
                                                       d_in[7], d_in[8], d_in[9], flag, cw);
    init_kernel<<<NNODES / 256, 256, 0, stream>>>(deg1, deg2i, new_id, ghist);
    pnorm_kernel<<<1, 128, 0, stream>>>(pf, invnorm);
    // edge binning (graph = src>>10; order within graph irrelevant)
    hist_kernel<<<256, 256, 0, stream>>>(srcv, ghist);
    scan_kernel<<<1, 64, 0, stream>>>(ghist, gbase, gcursor, gcnt);
    binpass_kernel<<<256, 256, 0, stream>>>(srcv, dstv, gcursor, elist);
    // conv1
    gemm_a_kernel<<<NNODES / 64, 256, 0, stream>>>(d_in[0], W1f, xw1, flag);
    deg1_kernel<<<NEDGES / 256, 256, 0, stream>>>(dstv, deg1);
    dinv_kernel<<<NNODES / 256, 256, 0, stream>>>(deg1, dinv1);
    s1_fused<<<NGRAPH * 8, 256, 0, stream>>>(elist, gbase, gcnt, dinv1, xw1, b1f, agg);
    // top-k pooling
    score_kernel<<<NNODES / 4, 256, 0, stream>>>(agg, pf, invnorm, score);
    topk_kernel<<<NGRAPH, 1024, 0, stream>>>(score, vals, perm, new_id);
    gather_kernel<<<M2 * HD / 256, 256, 0, stream>>>(agg, perm, vals, h2);
    // conv2
    gemm_f32<<<M2 / 64, 256, 0, stream>>>(h2, W2f, xw2);
    deg2_kernel<<<NEDGES / 256, 256, 0, stream>>>(srcv, dstv, new_id, deg2i);
    dinv_kernel<<<M2 / 256, 256, 0, stream>>>(deg2i, dinv2);
    s2_fused<<<NGRAPH * 4, 256, 0, stream>>>(elist, gbase, gcnt, new_id, dinv2, xw2, b2f, agg2);
    // readout
    pool_kernel<<<NGRAPH, 512, 0, stream>>>(agg2, Wlf, blf, d_out, flag);

    (void)in_sizes; (void)n_in; (void)out_size; (void)ws_size;
}

// Round 7
// 445.016 us; speedup vs baseline: 3.4958x; 3.4958x over previous
//
#include <hip/hip_runtime.h>

#define NNODES 65536
#define NEDGES 1048576
#define NGRAPH 64
#define NPERG  1024
#define KEEP   512
#define M2     (NGRAPH * KEEP)   // 32768
#define HD     128
#define NC     10

// canonical weight block offsets (floats)
#define OW1 0
#define OW2 16384
#define OWL 32768
#define OB1 34048
#define OB2 34176
#define OP  34304
#define OBL 34432
#define NCVT 34448

__device__ __forceinline__ float bf2f(unsigned short u) {
    return __uint_as_float(((unsigned int)u) << 16);
}
__device__ __forceinline__ unsigned short f2bf(float f) {
    unsigned int u = __float_as_uint(f);
    unsigned int r = (u + 0x7FFFu + ((u >> 16) & 1u)) >> 16;
    return (unsigned short)r;
}

// ---------------- dtype detector: 1 = bf16 storage, 0 = fp32 storage ---------
__global__ void detect_kernel(const unsigned short* __restrict__ w1u, int* __restrict__ flag) {
    __shared__ int cnt;
    int t = threadIdx.x;  // 256
    if (t == 0) cnt = 0;
    __syncthreads();
    int local = 0;
    for (int i = t; i < 512; i += 256) {
        unsigned short u = w1u[2 * i];
        int e = (u >> 7) & 0xFF;
        if (e >= 100 && e <= 140) local++;
    }
    atomicAdd(&cnt, local);
    __syncthreads();
    if (t == 0) flag[0] = (cnt >= 384) ? 1 : 0;
}

// ---------------- canonicalize small weights to fp32 -------------------------
__global__ void cvt_kernel(const void* __restrict__ W1, const void* __restrict__ b1,
                           const void* __restrict__ p, const void* __restrict__ W2,
                           const void* __restrict__ b2, const void* __restrict__ Wl,
                           const void* __restrict__ bl, const int* __restrict__ flag,
                           float* __restrict__ out) {
    int gid = blockIdx.x * 256 + threadIdx.x;
    if (gid >= NCVT) return;
    const void* srcp; int idx;
    if (gid < OB1) {
        if (gid < OW2)      { srcp = W1; idx = gid - OW1; }
        else if (gid < OWL) { srcp = W2; idx = gid - OW2; }
        else                { srcp = Wl; idx = gid - OWL; }
    } else {
        if (gid < OB2)      { srcp = b1; idx = gid - OB1; }
        else if (gid < OP)  { srcp = b2; idx = gid - OB2; }
        else if (gid < OBL) { srcp = p;  idx = gid - OP; }
        else                { srcp = bl; idx = gid - OBL; }
    }
    if (gid >= OWL && gid < OB1 && idx >= 1280) { out[gid] = 0.f; return; }   // Wl pad
    if (gid >= OBL && idx >= NC) { out[gid] = 0.f; return; }                  // bl pad
    float v;
    if (flag[0]) v = bf2f(((const unsigned short*)srcp)[idx]);
    else         v = ((const float*)srcp)[idx];
    out[gid] = v;
}

// ---------------- init: deg=0, new_id=-1 -------------------------------------
__global__ void init_kernel(int* __restrict__ deg1, int* __restrict__ deg2,
                            int* __restrict__ new_id) {
    int i = blockIdx.x * 256 + threadIdx.x;  // NNODES threads
    deg1[i] = 0;
    new_id[i] = -1;
    if (i < M2) deg2[i] = 0;
}

// ---------------- GEMM1: C[M,128] = A(flagged dtype)[M,128] @ W[128,128] -----
__global__ __launch_bounds__(256) void gemm_a_kernel(const void* __restrict__ Araw,
                                                     const float* __restrict__ W,
                                                     float* __restrict__ C,
                                                     const int* __restrict__ flag) {
    __shared__ float As[64 * HD];  // 32 KB
    int tid = threadIdx.x;
    int row0 = blockIdx.x * 64;
    if (flag[0]) {
        const unsigned short* Au = (const unsigned short*)Araw + (size_t)row0 * HD;
        for (int i = tid; i < 64 * HD; i += 256) As[i] = bf2f(Au[i]);
    } else {
        const float* Af = (const float*)Araw + (size_t)row0 * HD;
        for (int i = tid; i < 64 * HD / 4; i += 256)
            reinterpret_cast<float4*>(As)[i] = reinterpret_cast<const float4*>(Af)[i];
    }
    __syncthreads();
    int cg = tid & 31;
    int rg = tid >> 5;
    float acc[8][4];
#pragma unroll
    for (int r = 0; r < 8; r++)
#pragma unroll
        for (int c = 0; c < 4; c++) acc[r][c] = 0.f;
    for (int k = 0; k < HD; k++) {
        float4 wv = reinterpret_cast<const float4*>(W + k * HD)[cg];
#pragma unroll
        for (int r = 0; r < 8; r++) {
            float av = As[(rg * 8 + r) * HD + k];
            acc[r][0] += av * wv.x;
            acc[r][1] += av * wv.y;
            acc[r][2] += av * wv.z;
            acc[r][3] += av * wv.w;
        }
    }
#pragma unroll
    for (int r = 0; r < 8; r++) {
        float4 o = {acc[r][0], acc[r][1], acc[r][2], acc[r][3]};
        reinterpret_cast<float4*>(C + (size_t)(row0 + rg * 8 + r) * HD)[cg] = o;
    }
}

// ---------------- GEMM (fp32 A) for conv2 ------------------------------------
__global__ __launch_bounds__(256) void gemm_f32(const float* __restrict__ A,
                                                const float* __restrict__ W,
                                                float* __restrict__ C) {
    __shared__ float As[64 * HD];
    int tid = threadIdx.x;
    int row0 = blockIdx.x * 64;
    for (int i = tid; i < 64 * HD / 4; i += 256)
        reinterpret_cast<float4*>(As)[i] =
            reinterpret_cast<const float4*>(A + (size_t)row0 * HD)[i];
    __syncthreads();
    int cg = tid & 31;
    int rg = tid >> 5;
    float acc[8][4];
#pragma unroll
    for (int r = 0; r < 8; r++)
#pragma unroll
        for (int c = 0; c < 4; c++) acc[r][c] = 0.f;
    for (int k = 0; k < HD; k++) {
        float4 wv = reinterpret_cast<const float4*>(W + k * HD)[cg];
#pragma unroll
        for (int r = 0; r < 8; r++) {
            float av = As[(rg * 8 + r) * HD + k];
            acc[r][0] += av * wv.x;
            acc[r][1] += av * wv.y;
            acc[r][2] += av * wv.z;
            acc[r][3] += av * wv.w;
        }
    }
#pragma unroll
    for (int r = 0; r < 8; r++) {
        float4 o = {acc[r][0], acc[r][1], acc[r][2], acc[r][3]};
        reinterpret_cast<float4*>(C + (size_t)(row0 + rg * 8 + r) * HD)[cg] = o;
    }
}

// ---------------- p-norm -----------------------------------------------------
__global__ void pnorm_kernel(const float* __restrict__ p, float* __restrict__ invnorm) {
    int t = threadIdx.x;  // 128
    float v = p[t];
    v = v * v;
    for (int off = 32; off; off >>= 1) v += __shfl_down(v, off);
    __shared__ float s[2];
    if ((t & 63) == 0) s[t >> 6] = v;
    __syncthreads();
    if (t == 0) invnorm[0] = 1.0f / sqrtf(s[0] + s[1]);
}

// ---------------- degree / dinv ----------------------------------------------
__global__ void deg1_kernel(const int* __restrict__ dst, int* __restrict__ deg) {
    int e = blockIdx.x * 256 + threadIdx.x;
    atomicAdd(&deg[dst[e]], 1);
}
__global__ void deg2_kernel(const int* __restrict__ src, const int* __restrict__ dst,
                            const int* __restrict__ new_id, int* __restrict__ deg) {
    int e = blockIdx.x * 256 + threadIdx.x;
    int ns = new_id[src[e]], nd = new_id[dst[e]];
    if ((ns | nd) >= 0) atomicAdd(&deg[nd], 1);
}
__global__ void dinv_kernel(const int* __restrict__ deg, float* __restrict__ dinv) {
    int i = blockIdx.x * 256 + threadIdx.x;
    dinv[i] = rsqrtf((float)deg[i] + 1.0f);
}

// ---------------- CSR build: exclusive scan of deg1 + placement --------------
__global__ void scanA_kernel(const int* __restrict__ deg, int* __restrict__ bsum) {
    __shared__ int sh[256];
    int b = blockIdx.x, t = threadIdx.x;
    sh[t] = deg[b * 256 + t];
    __syncthreads();
    for (int off = 128; off; off >>= 1) {
        if (t < off) sh[t] += sh[t + off];
        __syncthreads();
    }
    if (t == 0) bsum[b] = sh[0];
}
__global__ void scanB_kernel(const int* __restrict__ bsum, int* __restrict__ bbase) {
    __shared__ int s[256];
    int t = threadIdx.x;
    int v = bsum[t];
    s[t] = v;
    __syncthreads();
    for (int off = 1; off < 256; off <<= 1) {
        int x = (t >= off) ? s[t - off] : 0;
        __syncthreads();
        s[t] += x;
        __syncthreads();
    }
    bbase[t] = s[t] - v;  // exclusive
}
__global__ void scanC_kernel(const int* __restrict__ deg, const int* __restrict__ bbase,
                             int* __restrict__ node_base, int* __restrict__ cursor) {
    __shared__ int s[256];
    int b = blockIdx.x, t = threadIdx.x;
    int v = deg[b * 256 + t];
    s[t] = v;
    __syncthreads();
    for (int off = 1; off < 256; off <<= 1) {
        int x = (t >= off) ? s[t - off] : 0;
        __syncthreads();
        s[t] += x;
        __syncthreads();
    }
    int excl = s[t] - v + bbase[b];
    node_base[b * 256 + t] = excl;
    cursor[b * 256 + t] = excl;
}
__global__ void csr_build_kernel(const int* __restrict__ src, const int* __restrict__ dst,
                                 int* __restrict__ cursor, unsigned short* __restrict__ csr16) {
    int e = blockIdx.x * 256 + threadIdx.x;
    int pos = atomicAdd(&cursor[dst[e]], 1);
    csr16[pos] = (unsigned short)(src[e] & (NPERG - 1));  // edges are intra-graph
}

// ---------------- conv1 aggregate, pull mode: wave per node ------------------
// h[n,:] = relu( dinv[n]*Σ_s dinv[s]*xw[s,:] + dinv[n]^2*xw[n,:] + b1 )
__global__ __launch_bounds__(256) void s1_pull(const unsigned short* __restrict__ csr16,
                                               const int* __restrict__ node_base,
                                               const int* __restrict__ deg,
                                               const float* __restrict__ dinv,
                                               const float* __restrict__ xw,
                                               const float* __restrict__ b1,
                                               float* __restrict__ h) {
    int n = (blockIdx.x * 256 + threadIdx.x) >> 6;  // node id
    int lane = threadIdx.x & 63;
    int gb = n & ~(NPERG - 1);  // graph base (intra-graph edges)
    int base = node_base[n], cnt = deg[n];
    float acc0 = 0.f, acc1 = 0.f;
    for (int j0 = 0; j0 < cnt; j0 += 64) {
        int myj = j0 + lane;
        int s = 0; float ds = 0.f;
        if (myj < cnt) {
            s = gb + csr16[base + myj];
            ds = dinv[s];
        }
        int mm = min(64, cnt - j0);
        for (int k = 0; k < mm; k++) {
            int sk = __shfl(s, k);
            float dk = __shfl(ds, k);
            acc0 += dk * xw[(size_t)sk * HD + lane];
            acc1 += dk * xw[(size_t)sk * HD + 64 + lane];
        }
    }
    float dn = dinv[n];
    float self = dn * dn;
    float v0 = dn * acc0 + self * xw[(size_t)n * HD + lane] + b1[lane];
    float v1 = dn * acc1 + self * xw[(size_t)n * HD + 64 + lane] + b1[64 + lane];
    h[(size_t)n * HD + lane] = fmaxf(v0, 0.f);
    h[(size_t)n * HD + 64 + lane] = fmaxf(v1, 0.f);
}

// ---------------- conv2 aggregate, pull mode with new_id mask ----------------
__global__ __launch_bounds__(256) void s2_pull(const unsigned short* __restrict__ csr16,
                                               const int* __restrict__ node_base,
                                               const int* __restrict__ deg,
                                               const int* __restrict__ perm,
                                               const int* __restrict__ new_id,
                                               const float* __restrict__ dinv2,
                                               const float* __restrict__ xw2,
                                               const float* __restrict__ b2,
                                               float* __restrict__ h3) {
    int m = (blockIdx.x * 256 + threadIdx.x) >> 6;  // kept-slot id
    int lane = threadIdx.x & 63;
    int node = perm[m];             // original node id
    int gb = node & ~(NPERG - 1);
    int base = node_base[node], cnt = deg[node];
    float acc0 = 0.f, acc1 = 0.f;
    for (int j0 = 0; j0 < cnt; j0 += 64) {
        int myj = j0 + lane;
        int ns = -1;
        if (myj < cnt) ns = new_id[gb + csr16[base + myj]];
        float ds = (ns >= 0) ? dinv2[ns] : 0.f;
        int mm = min(64, cnt - j0);
        for (int k = 0; k < mm; k++) {
            int nk = __shfl(ns, k);
            if (nk >= 0) {
                float dk = __shfl(ds, k);
                acc0 += dk * xw2[(size_t)nk * HD + lane];
                acc1 += dk * xw2[(size_t)nk * HD + 64 + lane];
            }
        }
    }
    float dn = dinv2[m];
    float self = dn * dn;
    float v0 = dn * acc0 + self * xw2[(size_t)m * HD + lane] + b2[lane];
    float v1 = dn * acc1 + self * xw2[(size_t)m * HD + 64 + lane] + b2[64 + lane];
    h3[(size_t)m * HD + lane] = fmaxf(v0, 0.f);
    h3[(size_t)m * HD + 64 + lane] = fmaxf(v1, 0.f);
}

// ---------------- score = tanh(h.p * invnorm) --------------------------------
__global__ __launch_bounds__(256) void score_kernel(const float* __restrict__ h,
                                                    const float* __restrict__ p,
                                                    const float* __restrict__ invnorm,
                                                    float* __restrict__ score) {
    int gid = blockIdx.x * 256 + threadIdx.x;
    int row = gid >> 6, lane = gid & 63;
    float v = h[(size_t)row * HD + lane] * p[lane] +
              h[(size_t)row * HD + lane + 64] * p[lane + 64];
    for (int off = 32; off; off >>= 1) v += __shfl_down(v, off);
    if (lane == 0) score[row] = tanhf(v * invnorm[0]);
}

// ---------------- per-graph top-512 via bitonic sort of 1024 -----------------
__global__ __launch_bounds__(1024) void topk_kernel(const float* __restrict__ score,
                                                    float* __restrict__ vals,
                                                    int* __restrict__ perm,
                                                    int* __restrict__ new_id) {
    __shared__ float sv[1024];
    __shared__ int si[1024];
    int g = blockIdx.x, t = threadIdx.x;
    sv[t] = score[g * NPERG + t];
    si[t] = t;
    __syncthreads();
    for (int k = 2; k <= 1024; k <<= 1) {
        for (int j = k >> 1; j > 0; j >>= 1) {
            int l = t ^ j;
            if (l > t) {
                bool desc = ((t & k) == 0);
                float va = sv[t], vb = sv[l];
                int ia = si[t], ib = si[l];
                bool gab = (va > vb) || (va == vb && ia < ib);  // lax.top_k tie rule
                if (gab != desc) { sv[t] = vb; si[t] = ib; sv[l] = va; si[l] = ia; }
            }
            __syncthreads();
        }
    }
    if (t < KEEP) {
        int node = g * NPERG + si[t];
        int slot = g * KEEP + t;
        vals[slot] = sv[t];
        perm[slot] = node;
        new_id[node] = slot;
    }
}

// ---------------- gather + gate (fp32) ---------------------------------------
__global__ void gather_kernel(const float* __restrict__ h, const int* __restrict__ perm,
                              const float* __restrict__ vals, float* __restrict__ h2) {
    int gid = blockIdx.x * 256 + threadIdx.x;
    int i = gid >> 7, c = gid & 127;
    h2[gid] = h[(size_t)perm[i] * HD + c] * vals[i];
}

// ---------------- mean-pool + linear; output dtype follows flag --------------
__global__ __launch_bounds__(512) void pool_kernel(const float* __restrict__ h3,
                                                   const float* __restrict__ Wl,
                                                   const float* __restrict__ bl,
                                                   void* __restrict__ outv,
                                                   const int* __restrict__ flag) {
    int g = blockIdx.x, t = threadIdx.x;  // 512
    int c = t & 127, rg = t >> 7;
    const float* base = h3 + (size_t)g * KEEP * HD;
    float sum = 0.f;
    for (int k = rg; k < KEEP; k += 4) sum += base[(size_t)k * HD + c];
    __shared__ float sp[4][128];
    sp[rg][c] = sum;
    __syncthreads();
    if (t < 128) sp[0][t] = (sp[0][t] + sp[1][t] + sp[2][t] + sp[3][t]) * (1.0f / KEEP);
    __syncthreads();
    if (t < NC) {
        float acc = bl[t];
        for (int hh = 0; hh < HD; hh++) acc += sp[0][hh] * Wl[hh * NC + t];
        if (flag[0]) ((unsigned short*)outv)[g * NC + t] = f2bf(acc);
        else         ((float*)outv)[g * NC + t] = acc;
    }
}

extern "C" void kernel_launch(void* const* d_in, const int* in_sizes, int n_in,
                              void* d_out, int out_size, void* d_ws, size_t ws_size,
                              hipStream_t stream) {
    const int* ei   = (const int*)d_in[1];
    const int* srcv = ei;
    const int* dstv = ei + NEDGES;

    char* w = (char*)d_ws;
    const size_t MB = 1u << 20;
    float* dinv1   = (float*)(w + 0);
    float* score   = (float*)(w + 256 * 1024);
    float* vals    = (float*)(w + 512 * 1024);
    int*   perm    = (int*)(w + 640 * 1024);
    int*   new_id  = (int*)(w + 768 * 1024);
    int*   deg1    = (int*)(w + 1024 * 1024);
    int*   deg2i   = (int*)(w + 1280 * 1024);
    float* dinv2   = (float*)(w + 1408 * 1024);
    float* invnorm = (float*)(w + 1536 * 1024);
    int*   flag    = (int*)(w + 1536 * 1024 + 64);
    int*   bsum    = (int*)(w + 1537 * 1024);
    int*   bbase   = (int*)(w + 1538 * 1024);
    float* cw      = (float*)(w + 1664 * 1024);   // canonical fp32 weights
    float* xw1  = (float*)(w + 2 * MB);           // [2,34) MB
    float* agg  = (float*)(w + 34 * MB);          // [34,66) MB   (h)
    float* h2   = (float*)(w + 2 * MB);           // [2,18) MB    (xw1 dead)
    float* xw2  = (float*)(w + 18 * MB);          // [18,34) MB   (xw1 dead)
    float* agg2 = (float*)(w + 34 * MB);          // [34,50) MB   (h dead)
    unsigned short* csr16 = (unsigned short*)(w + 66 * MB);  // [66,68) MB
    int* node_base = (int*)(w + 68 * MB);                    // 256 KB
    int* cursor    = (int*)(w + 68 * MB + 256 * 1024);       // 256 KB

    float* W1f = cw + OW1; float* W2f = cw + OW2; float* Wlf = cw + OWL;
    float* b1f = cw + OB1; float* b2f = cw + OB2; float* pf  = cw + OP;
    float* blf = cw + OBL;

    detect_kernel<<<1, 256, 0, stream>>>((const unsigned short*)d_in[3], flag);
    cvt_kernel<<<(NCVT + 255) / 256, 256, 0, stream>>>(d_in[3], d_in[4], d_in[5], d_in[6],
                                                       d_in[7], d_in[8], d_in[9], flag, cw);
    init_kernel<<<NNODES / 256, 256, 0, stream>>>(deg1, deg2i, new_id);
    pnorm_kernel<<<1, 128, 0, stream>>>(pf, invnorm);
    // conv1 transform
    gemm_a_kernel<<<NNODES / 64, 256, 0, stream>>>(d_in[0], W1f, xw1, flag);
    // degrees + CSR by dst
    deg1_kernel<<<NEDGES / 256, 256, 0, stream>>>(dstv, deg1);
    dinv_kernel<<<NNODES / 256, 256, 0, stream>>>(deg1, dinv1);
    scanA_kernel<<<256, 256, 0, stream>>>(deg1, bsum);
    scanB_kernel<<<1, 256, 0, stream>>>(bsum, bbase);
    scanC_kernel<<<256, 256, 0, stream>>>(deg1, bbase, node_base, cursor);
    csr_build_kernel<<<NEDGES / 256, 256, 0, stream>>>(srcv, dstv, cursor, csr16);
    // conv1 aggregate (pull) + bias + relu
    s1_pull<<<NNODES * 64 / 256, 256, 0, stream>>>(csr16, node_base, deg1, dinv1, xw1, b1f, agg);
    // top-k pooling
    score_kernel<<<NNODES / 4, 256, 0, stream>>>(agg, pf, invnorm, score);
    topk_kernel<<<NGRAPH, 1024, 0, stream>>>(score, vals, perm, new_id);
    gather_kernel<<<M2 * HD / 256, 256, 0, stream>>>(agg, perm, vals, h2);
    // conv2
    gemm_f32<<<M2 / 64, 256, 0, stream>>>(h2, W2f, xw2);
    deg2_kernel<<<NEDGES / 256, 256, 0, stream>>>(srcv, dstv, new_id, deg2i);
    dinv_kernel<<<M2 / 256, 256, 0, stream>>>(deg2i, dinv2);
    s2_pull<<<M2 * 64 / 256, 256, 0, stream>>>(csr16, node_base, deg1, perm, new_id, dinv2,
                                               xw2, b2f, agg2);
    // readout
    pool_kernel<<<NGRAPH, 512, 0, stream>>>(agg2, Wlf, blf, d_out, flag);

    (void)in_sizes; (void)n_in; (void)out_size; (void)ws_size;
}

// Round 8
// 348.440 us; speedup vs baseline: 4.4647x; 1.2772x over previous
//
#include <hip/hip_runtime.h>

#define NNODES 65536
#define NEDGES 1048576
#define NGRAPH 64
#define NPERG  1024
#define KEEP   512
#define M2     (NGRAPH * KEEP)   // 32768
#define HD     128
#define NC     10
#define EMAX   20480             // per-graph edge capacity (avg 16384, sigma~127)

// canonical weight block offsets (floats)
#define OW1 0
#define OW2 16384
#define OWL 32768
#define OB1 34048
#define OB2 34176
#define OP  34304
#define OBL 34432
#define NCVT 34448

__device__ __forceinline__ float bf2f(unsigned short u) {
    return __uint_as_float(((unsigned int)u) << 16);
}
__device__ __forceinline__ unsigned short f2bf(float f) {
    unsigned int u = __float_as_uint(f);
    unsigned int r = (u + 0x7FFFu + ((u >> 16) & 1u)) >> 16;
    return (unsigned short)r;
}

// ---------------- prep: detect dtype + cvt weights + pnorm + init ------------
// blocks [0,135): cvt; block 135: pnorm; blocks [136,392): new_id=-1, ghist=0
__global__ __launch_bounds__(256) void prep_kernel(
    const void* __restrict__ W1, const void* __restrict__ b1, const void* __restrict__ p,
    const void* __restrict__ W2, const void* __restrict__ b2, const void* __restrict__ Wl,
    const void* __restrict__ bl, int* __restrict__ flag, float* __restrict__ cw,
    float* __restrict__ invnorm, int* __restrict__ new_id, int* __restrict__ ghist) {
    int bid = blockIdx.x, t = threadIdx.x;
    // per-block redundant dtype detect on W1 (L2-hot, ~1KB)
    const unsigned short* w1u = (const unsigned short*)W1;
    int local = 0;
    for (int i = t; i < 512; i += 256) {
        unsigned short u = w1u[2 * i];
        int e = (u >> 7) & 0xFF;
        local += (e >= 100 && e <= 140) ? 1 : 0;
    }
    __shared__ int red[256];
    red[t] = local;
    __syncthreads();
    for (int off = 128; off; off >>= 1) {
        if (t < off) red[t] += red[t + off];
        __syncthreads();
    }
    int fl = (red[0] >= 384) ? 1 : 0;
    if (bid == 0 && t == 0) flag[0] = fl;

    if (bid < 135) {
        int gid = bid * 256 + t;
        if (gid < NCVT) {
            const void* srcp; int idx;
            if (gid < OB1) {
                if (gid < OW2)      { srcp = W1; idx = gid - OW1; }
                else if (gid < OWL) { srcp = W2; idx = gid - OW2; }
                else                { srcp = Wl; idx = gid - OWL; }
            } else {
                if (gid < OB2)      { srcp = b1; idx = gid - OB1; }
                else if (gid < OP)  { srcp = b2; idx = gid - OB2; }
                else if (gid < OBL) { srcp = p;  idx = gid - OP; }
                else                { srcp = bl; idx = gid - OBL; }
            }
            float v;
            if (gid >= OWL && gid < OB1 && idx >= 1280) v = 0.f;       // Wl pad
            else if (gid >= OBL && idx >= NC) v = 0.f;                  // bl pad
            else if (fl) v = bf2f(((const unsigned short*)srcp)[idx]);
            else v = ((const float*)srcp)[idx];
            cw[gid] = v;
        }
    } else if (bid == 135) {
        __shared__ float s2a[128];
        float pv = 0.f;
        if (t < 128) pv = fl ? bf2f(((const unsigned short*)p)[t]) : ((const float*)p)[t];
        if (t < 128) s2a[t] = pv * pv;
        __syncthreads();
        for (int off = 64; off; off >>= 1) {
            if (t < off) s2a[t] += s2a[t + off];
            __syncthreads();
        }
        if (t == 0) invnorm[0] = 1.0f / sqrtf(s2a[0]);
    } else {
        int i = (bid - 136) * 256 + t;
        new_id[i] = -1;
        if (i < NGRAPH) ghist[i] = 0;
    }
}

// ---------------- edge binning by graph --------------------------------------
__global__ __launch_bounds__(256) void hist_kernel(const int* __restrict__ src,
                                                   int* __restrict__ ghist) {
    __shared__ int lh[NGRAPH];
    int tid = threadIdx.x;
    if (tid < NGRAPH) lh[tid] = 0;
    __syncthreads();
    int e0 = blockIdx.x * 4096;  // 256 blocks
    for (int k = 0; k < 16; k++) atomicAdd(&lh[src[e0 + k * 256 + tid] >> 10], 1);
    __syncthreads();
    if (tid < NGRAPH) atomicAdd(&ghist[tid], lh[tid]);
}
__global__ void scan_kernel(const int* __restrict__ ghist, int* __restrict__ gbase,
                            int* __restrict__ gcursor, int* __restrict__ gcnt) {
    if (threadIdx.x == 0) {
        int s = 0;
        for (int g = 0; g < NGRAPH; g++) {
            gbase[g] = s; gcursor[g] = s; gcnt[g] = ghist[g]; s += ghist[g];
        }
    }
}
__global__ __launch_bounds__(256) void binpass_kernel(const int* __restrict__ src,
                                                      const int* __restrict__ dst,
                                                      int* __restrict__ gcursor,
                                                      unsigned int* __restrict__ elist) {
    __shared__ int lh[NGRAPH];
    __shared__ int lbase[NGRAPH];
    int tid = threadIdx.x;
    int e0 = blockIdx.x * 4096;  // 256 blocks
    if (tid < NGRAPH) lh[tid] = 0;
    __syncthreads();
    int gs[16]; unsigned int pk[16];
    for (int k = 0; k < 16; k++) {
        int e = e0 + k * 256 + tid;
        int s = src[e], d = dst[e];
        gs[k] = s >> 10;
        pk[k] = (unsigned)(s & 1023) | ((unsigned)(d & 1023) << 10);
        atomicAdd(&lh[gs[k]], 1);
    }
    __syncthreads();
    if (tid < NGRAPH) { lbase[tid] = atomicAdd(&gcursor[tid], lh[tid]); lh[tid] = 0; }
    __syncthreads();
    for (int k = 0; k < 16; k++) {
        int g = gs[k];
        int pos = lbase[g] + atomicAdd(&lh[g], 1);
        elist[pos] = pk[k];
    }
}

// ---------------- per-graph LDS counting-sort CSR + deg1 + dinv1 -------------
__global__ __launch_bounds__(1024) void csr_sort_kernel(
    const unsigned int* __restrict__ elist, const int* __restrict__ gbase,
    const int* __restrict__ gcnt, unsigned short* __restrict__ csr16,
    int* __restrict__ node_base, int* __restrict__ deg_out, float* __restrict__ dinv_out) {
    __shared__ unsigned short sc[EMAX];  // 40 KB
    __shared__ int cnt[NPERG];           // 4 KB (becomes inclusive scan)
    __shared__ int cur[NPERG];           // 4 KB
    int g = blockIdx.x, t = threadIdx.x;
    cnt[t] = 0;
    __syncthreads();
    int base = gbase[g];
    int n = gcnt[g]; if (n > EMAX) n = EMAX;
    for (int j = t; j < n; j += 1024) atomicAdd(&cnt[(elist[base + j] >> 10) & 1023], 1);
    __syncthreads();
    int v = cnt[t];
    // inclusive Hillis-Steele scan over 1024 entries (in place, double-sync)
    for (int off = 1; off < 1024; off <<= 1) {
        int x = (t >= off) ? cnt[t - off] : 0;
        __syncthreads();
        cnt[t] += x;
        __syncthreads();
    }
    int excl = cnt[t] - v;
    cur[t] = excl;
    deg_out[g * NPERG + t] = v;
    dinv_out[g * NPERG + t] = rsqrtf((float)v + 1.0f);
    node_base[g * NPERG + t] = base + excl;
    __syncthreads();
    for (int j = t; j < n; j += 1024) {
        unsigned int pk = elist[base + j];
        int d = (pk >> 10) & 1023;
        int pos = atomicAdd(&cur[d], 1);
        sc[pos] = (unsigned short)(pk & 1023);
    }
    __syncthreads();
    for (int j = t; j < n; j += 1024) csr16[base + j] = sc[j];
}

// ---------------- GEMM1: C[M,128] = A(flagged dtype)[M,128] @ W[128,128] -----
__global__ __launch_bounds__(256) void gemm_a_kernel(const void* __restrict__ Araw,
                                                     const float* __restrict__ W,
                                                     float* __restrict__ C,
                                                     const int* __restrict__ flag) {
    __shared__ float As[64 * HD];  // 32 KB
    int tid = threadIdx.x;
    int row0 = blockIdx.x * 64;
    if (flag[0]) {
        const unsigned short* Au = (const unsigned short*)Araw + (size_t)row0 * HD;
        for (int i = tid; i < 64 * HD; i += 256) As[i] = bf2f(Au[i]);
    } else {
        const float* Af = (const float*)Araw + (size_t)row0 * HD;
        for (int i = tid; i < 64 * HD / 4; i += 256)
            reinterpret_cast<float4*>(As)[i] = reinterpret_cast<const float4*>(Af)[i];
    }
    __syncthreads();
    int cg = tid & 31;
    int rg = tid >> 5;
    float acc[8][4];
#pragma unroll
    for (int r = 0; r < 8; r++)
#pragma unroll
        for (int c = 0; c < 4; c++) acc[r][c] = 0.f;
    for (int k = 0; k < HD; k++) {
        float4 wv = reinterpret_cast<const float4*>(W + k * HD)[cg];
#pragma unroll
        for (int r = 0; r < 8; r++) {
            float av = As[(rg * 8 + r) * HD + k];
            acc[r][0] += av * wv.x;
            acc[r][1] += av * wv.y;
            acc[r][2] += av * wv.z;
            acc[r][3] += av * wv.w;
        }
    }
#pragma unroll
    for (int r = 0; r < 8; r++) {
        float4 o = {acc[r][0], acc[r][1], acc[r][2], acc[r][3]};
        reinterpret_cast<float4*>(C + (size_t)(row0 + rg * 8 + r) * HD)[cg] = o;
    }
}

// ---------------- conv1 aggregate (pull, wave/node) + bias + relu + score ----
__global__ __launch_bounds__(256) void s1_pull(const unsigned short* __restrict__ csr16,
                                               const int* __restrict__ node_base,
                                               const int* __restrict__ deg,
                                               const float* __restrict__ dinv,
                                               const float* __restrict__ xw,
                                               const float* __restrict__ b1,
                                               const float* __restrict__ pvec,
                                               const float* __restrict__ invnorm,
                                               float* __restrict__ h,
                                               float* __restrict__ score) {
    int n = (blockIdx.x * 256 + threadIdx.x) >> 6;  // node id
    int lane = threadIdx.x & 63;
    int gb = n & ~(NPERG - 1);
    int base = node_base[n], cnt = deg[n];
    const float2* xf2 = (const float2*)xw;  // row stride 64 float2
    float a0 = 0.f, a1 = 0.f;
    for (int j0 = 0; j0 < cnt; j0 += 64) {
        int myj = j0 + lane;
        int s = 0; float ds = 0.f;
        if (myj < cnt) {
            s = gb + csr16[base + myj];
            ds = dinv[s];
        }
        int mm = min(64, cnt - j0);
        for (int k = 0; k < mm; k++) {
            int sk = __shfl(s, k);
            float dk = __shfl(ds, k);
            float2 v = xf2[(size_t)sk * 64 + lane];
            a0 += dk * v.x;
            a1 += dk * v.y;
        }
    }
    float dn = dinv[n];
    float self = dn * dn;
    float2 xs = xf2[(size_t)n * 64 + lane];
    float2 bb = ((const float2*)b1)[lane];
    float h0 = fmaxf(dn * a0 + self * xs.x + bb.x, 0.f);
    float h1 = fmaxf(dn * a1 + self * xs.y + bb.y, 0.f);
    float2 ho = {h0, h1};
    ((float2*)h)[(size_t)n * 64 + lane] = ho;
    // fused score = tanh(dot(h_row, p) * invnorm)
    float2 pp = ((const float2*)pvec)[lane];
    float sv = h0 * pp.x + h1 * pp.y;
    for (int off = 32; off; off >>= 1) sv += __shfl_down(sv, off);
    if (lane == 0) score[n] = tanhf(sv * invnorm[0]);
}

// ---------------- top-512 bitonic + fused deg2/dinv2 -------------------------
__global__ __launch_bounds__(1024) void topk_kernel(const float* __restrict__ score,
                                                    const unsigned int* __restrict__ elist,
                                                    const int* __restrict__ gbase,
                                                    const int* __restrict__ gcnt,
                                                    float* __restrict__ vals,
                                                    int* __restrict__ perm,
                                                    int* __restrict__ new_id,
                                                    float* __restrict__ dinv2) {
    __shared__ float sv[1024];
    __shared__ int si[1024];
    __shared__ short nid[1024];
    __shared__ int d2[KEEP];
    int g = blockIdx.x, t = threadIdx.x;
    sv[t] = score[g * NPERG + t];
    si[t] = t;
    nid[t] = -1;
    if (t < KEEP) d2[t] = 0;
    __syncthreads();
    for (int k = 2; k <= 1024; k <<= 1) {
        for (int j = k >> 1; j > 0; j >>= 1) {
            int l = t ^ j;
            if (l > t) {
                bool desc = ((t & k) == 0);
                float va = sv[t], vb = sv[l];
                int ia = si[t], ib = si[l];
                bool gab = (va > vb) || (va == vb && ia < ib);  // lax.top_k tie rule
                if (gab != desc) { sv[t] = vb; si[t] = ib; sv[l] = va; si[l] = ia; }
            }
            __syncthreads();
        }
    }
    if (t < KEEP) {
        int node = g * NPERG + si[t];
        int slot = g * KEEP + t;
        vals[slot] = sv[t];
        perm[slot] = node;
        new_id[node] = slot;
        nid[si[t]] = (short)t;
    }
    __syncthreads();
    // fused deg2: count surviving edges per kept dst (intra-graph)
    int base = gbase[g], n = gcnt[g];
    for (int j = t; j < n; j += 1024) {
        unsigned int pk = elist[base + j];
        int s = pk & 1023, d = (pk >> 10) & 1023;
        short ns = nid[s], nd = nid[d];
        if (ns >= 0 && nd >= 0) atomicAdd(&d2[nd], 1);
    }
    __syncthreads();
    if (t < KEEP) dinv2[g * KEEP + t] = rsqrtf((float)d2[t] + 1.0f);
}

// ---------------- GEMM2 with fused gather+gate A-staging ---------------------
__global__ __launch_bounds__(256) void gemm_gather(const float* __restrict__ h,
                                                   const int* __restrict__ perm,
                                                   const float* __restrict__ vals,
                                                   const float* __restrict__ W,
                                                   float* __restrict__ C) {
    __shared__ float As[64 * HD];
    int tid = threadIdx.x;
    int row0 = blockIdx.x * 64;
    for (int i4 = tid; i4 < 64 * 32; i4 += 256) {
        int r = i4 >> 5, c4 = i4 & 31;
        int m = row0 + r;
        float sc = vals[m];
        float4 v = reinterpret_cast<const float4*>(h + (size_t)perm[m] * HD)[c4];
        v.x *= sc; v.y *= sc; v.z *= sc; v.w *= sc;
        reinterpret_cast<float4*>(As)[i4] = v;
    }
    __syncthreads();
    int cg = tid & 31;
    int rg = tid >> 5;
    float acc[8][4];
#pragma unroll
    for (int r = 0; r < 8; r++)
#pragma unroll
        for (int c = 0; c < 4; c++) acc[r][c] = 0.f;
    for (int k = 0; k < HD; k++) {
        float4 wv = reinterpret_cast<const float4*>(W + k * HD)[cg];
#pragma unroll
        for (int r = 0; r < 8; r++) {
            float av = As[(rg * 8 + r) * HD + k];
            acc[r][0] += av * wv.x;
            acc[r][1] += av * wv.y;
            acc[r][2] += av * wv.z;
            acc[r][3] += av * wv.w;
        }
    }
#pragma unroll
    for (int r = 0; r < 8; r++) {
        float4 o = {acc[r][0], acc[r][1], acc[r][2], acc[r][3]};
        reinterpret_cast<float4*>(C + (size_t)(row0 + rg * 8 + r) * HD)[cg] = o;
    }
}

// ---------------- conv2 aggregate (pull) with new_id mask --------------------
__global__ __launch_bounds__(256) void s2_pull(const unsigned short* __restrict__ csr16,
                                               const int* __restrict__ node_base,
                                               const int* __restrict__ deg,
                                               const int* __restrict__ perm,
                                               const int* __restrict__ new_id,
                                               const float* __restrict__ dinv2,
                                               const float* __restrict__ xw2,
                                               const float* __restrict__ b2,
                                               float* __restrict__ h3) {
    int m = (blockIdx.x * 256 + threadIdx.x) >> 6;  // kept-slot id
    int lane = threadIdx.x & 63;
    int node = perm[m];
    int gb = node & ~(NPERG - 1);
    int base = node_base[node], cnt = deg[node];
    const float2* xf2 = (const float2*)xw2;
    float a0 = 0.f, a1 = 0.f;
    for (int j0 = 0; j0 < cnt; j0 += 64) {
        int myj = j0 + lane;
        int ns = -1;
        if (myj < cnt) ns = new_id[gb + csr16[base + myj]];
        float ds = (ns >= 0) ? dinv2[ns] : 0.f;
        int mm = min(64, cnt - j0);
        for (int k = 0; k < mm; k++) {
            int nk = __shfl(ns, k);
            if (nk >= 0) {
                float dk = __shfl(ds, k);
                float2 v = xf2[(size_t)nk * 64 + lane];
                a0 += dk * v.x;
                a1 += dk * v.y;
            }
        }
    }
    float dn = dinv2[m];
    float self = dn * dn;
    float2 xs = xf2[(size_t)m * 64 + lane];
    float2 bb = ((const float2*)b2)[lane];
    float2 ho;
    ho.x = fmaxf(dn * a0 + self * xs.x + bb.x, 0.f);
    ho.y = fmaxf(dn * a1 + self * xs.y + bb.y, 0.f);
    ((float2*)h3)[(size_t)m * 64 + lane] = ho;
}

// ---------------- mean-pool + linear; output dtype follows flag --------------
__global__ __launch_bounds__(512) void pool_kernel(const float* __restrict__ h3,
                                                   const float* __restrict__ Wl,
                                                   const float* __restrict__ bl,
                                                   void* __restrict__ outv,
                                                   const int* __restrict__ flag) {
    int g = blockIdx.x, t = threadIdx.x;  // 512
    int c = t & 127, rg = t >> 7;
    const float* base = h3 + (size_t)g * KEEP * HD;
    float sum = 0.f;
    for (int k = rg; k < KEEP; k += 4) sum += base[(size_t)k * HD + c];
    __shared__ float sp[4][128];
    sp[rg][c] = sum;
    __syncthreads();
    if (t < 128) sp[0][t] = (sp[0][t] + sp[1][t] + sp[2][t] + sp[3][t]) * (1.0f / KEEP);
    __syncthreads();
    if (t < NC) {
        float acc = bl[t];
        for (int hh = 0; hh < HD; hh++) acc += sp[0][hh] * Wl[hh * NC + t];
        if (flag[0]) ((unsigned short*)outv)[g * NC + t] = f2bf(acc);
        else         ((float*)outv)[g * NC + t] = acc;
    }
}

extern "C" void kernel_launch(void* const* d_in, const int* in_sizes, int n_in,
                              void* d_out, int out_size, void* d_ws, size_t ws_size,
                              hipStream_t stream) {
    const int* ei   = (const int*)d_in[1];
    const int* srcv = ei;
    const int* dstv = ei + NEDGES;

    char* w = (char*)d_ws;
    const size_t MB = 1u << 20;
    const size_t KB = 1024;
    float* dinv1     = (float*)(w + 0);                 // 256 KB
    float* score     = (float*)(w + 256 * KB);          // 256 KB
    float* vals      = (float*)(w + 512 * KB);          // 128 KB
    int*   perm      = (int*)(w + 640 * KB);            // 128 KB
    int*   new_id    = (int*)(w + 768 * KB);            // 256 KB
    int*   deg1      = (int*)(w + 1024 * KB);           // 256 KB
    int*   node_base = (int*)(w + 1280 * KB);           // 256 KB
    float* dinv2     = (float*)(w + 1536 * KB);         // 128 KB
    float* invnorm   = (float*)(w + 1664 * KB);
    int*   flag      = (int*)(w + 1664 * KB + 64);
    int*   ghist     = (int*)(w + 1664 * KB + 1024);
    int*   gbase     = (int*)(w + 1664 * KB + 2048);
    int*   gcursor   = (int*)(w + 1664 * KB + 3072);
    int*   gcnt      = (int*)(w + 1664 * KB + 4096);
    float* cw        = (float*)(w + 1700 * KB);         // 135 KB canonical weights
    float* xw1  = (float*)(w + 2 * MB);                 // [2,34) MB
    float* agg  = (float*)(w + 34 * MB);                // [34,66) MB  (h)
    float* xw2  = (float*)(w + 2 * MB);                 // xw1 dead after s1
    float* agg2 = (float*)(w + 34 * MB);                // h dead after gemm_gather
    unsigned int* elist    = (unsigned int*)(w + 66 * MB);   // [66,70) MB
    unsigned short* csr16  = (unsigned short*)(w + 70 * MB); // [70,72) MB

    float* W1f = cw + OW1; float* W2f = cw + OW2; float* Wlf = cw + OWL;
    float* b1f = cw + OB1; float* b2f = cw + OB2; float* pf  = cw + OP;
    float* blf = cw + OBL;

    prep_kernel<<<392, 256, 0, stream>>>(d_in[3], d_in[4], d_in[5], d_in[6], d_in[7],
                                         d_in[8], d_in[9], flag, cw, invnorm, new_id, ghist);
    hist_kernel<<<256, 256, 0, stream>>>(srcv, ghist);
    scan_kernel<<<1, 64, 0, stream>>>(ghist, gbase, gcursor, gcnt);
    binpass_kernel<<<256, 256, 0, stream>>>(srcv, dstv, gcursor, elist);
    gemm_a_kernel<<<NNODES / 64, 256, 0, stream>>>(d_in[0], W1f, xw1, flag);
    csr_sort_kernel<<<NGRAPH, 1024, 0, stream>>>(elist, gbase, gcnt, csr16, node_base,
                                                 deg1, dinv1);
    s1_pull<<<NNODES / 4, 256, 0, stream>>>(csr16, node_base, deg1, dinv1, xw1, b1f, pf,
                                            invnorm, agg, score);
    topk_kernel<<<NGRAPH, 1024, 0, stream>>>(score, elist, gbase, gcnt, vals, perm,
                                             new_id, dinv2);
    gemm_gather<<<M2 / 64, 256, 0, stream>>>(agg, perm, vals, W2f, xw2);
    s2_pull<<<M2 / 4, 256, 0, stream>>>(csr16, node_base, deg1, perm, new_id, dinv2,
                                        xw2, b2f, agg2);
    pool_kernel<<<NGRAPH, 512, 0, stream>>>(agg2, Wlf, blf, d_out, flag);

    (void)in_sizes; (void)n_in; (void)out_size; (void)ws_size;
}

// Round 9
// 322.061 us; speedup vs baseline: 4.8304x; 1.0819x over previous
//
#include <hip/hip_runtime.h>

#define NNODES 65536
#define NEDGES 1048576
#define NGRAPH 64
#define NPERG  1024
#define KEEP   512
#define M2     (NGRAPH * KEEP)   // 32768
#define HD     128
#define NC     10
#define EMAX   20480             // per-graph edge capacity (avg 16384, sigma~127)

// canonical weight block offsets (floats)
#define OW1 0
#define OW2 16384
#define OWL 32768
#define OB1 34048
#define OB2 34176
#define OP  34304
#define OBL 34432
#define NCVT 34448

__device__ __forceinline__ float bf2f(unsigned short u) {
    return __uint_as_float(((unsigned int)u) << 16);
}
__device__ __forceinline__ unsigned short f2bf(float f) {
    unsigned int u = __float_as_uint(f);
    unsigned int r = (u + 0x7FFFu + ((u >> 16) & 1u)) >> 16;
    return (unsigned short)r;
}

// ---------------- prep: detect dtype + cvt weights + pnorm + init ------------
__global__ __launch_bounds__(256) void prep_kernel(
    const void* __restrict__ W1, const void* __restrict__ b1, const void* __restrict__ p,
    const void* __restrict__ W2, const void* __restrict__ b2, const void* __restrict__ Wl,
    const void* __restrict__ bl, int* __restrict__ flag, float* __restrict__ cw,
    float* __restrict__ invnorm, int* __restrict__ new_id, int* __restrict__ ghist) {
    int bid = blockIdx.x, t = threadIdx.x;
    const unsigned short* w1u = (const unsigned short*)W1;
    int local = 0;
    for (int i = t; i < 512; i += 256) {
        unsigned short u = w1u[2 * i];
        int e = (u >> 7) & 0xFF;
        local += (e >= 100 && e <= 140) ? 1 : 0;
    }
    __shared__ int red[256];
    red[t] = local;
    __syncthreads();
    for (int off = 128; off; off >>= 1) {
        if (t < off) red[t] += red[t + off];
        __syncthreads();
    }
    int fl = (red[0] >= 384) ? 1 : 0;
    if (bid == 0 && t == 0) flag[0] = fl;

    if (bid < 135) {
        int gid = bid * 256 + t;
        if (gid < NCVT) {
            const void* srcp; int idx;
            if (gid < OB1) {
                if (gid < OW2)      { srcp = W1; idx = gid - OW1; }
                else if (gid < OWL) { srcp = W2; idx = gid - OW2; }
                else                { srcp = Wl; idx = gid - OWL; }
            } else {
                if (gid < OB2)      { srcp = b1; idx = gid - OB1; }
                else if (gid < OP)  { srcp = b2; idx = gid - OB2; }
                else if (gid < OBL) { srcp = p;  idx = gid - OP; }
                else                { srcp = bl; idx = gid - OBL; }
            }
            float v;
            if (gid >= OWL && gid < OB1 && idx >= 1280) v = 0.f;       // Wl pad
            else if (gid >= OBL && idx >= NC) v = 0.f;                  // bl pad
            else if (fl) v = bf2f(((const unsigned short*)srcp)[idx]);
            else v = ((const float*)srcp)[idx];
            cw[gid] = v;
        }
    } else if (bid == 135) {
        __shared__ float s2a[128];
        float pv = 0.f;
        if (t < 128) pv = fl ? bf2f(((const unsigned short*)p)[t]) : ((const float*)p)[t];
        if (t < 128) s2a[t] = pv * pv;
        __syncthreads();
        for (int off = 64; off; off >>= 1) {
            if (t < off) s2a[t] += s2a[t + off];
            __syncthreads();
        }
        if (t == 0) invnorm[0] = 1.0f / sqrtf(s2a[0]);
    } else {
        int i = (bid - 136) * 256 + t;
        new_id[i] = -1;
        if (i < NGRAPH) ghist[i] = 0;
    }
}

// ---------------- edge binning by graph --------------------------------------
__global__ __launch_bounds__(256) void hist_kernel(const int* __restrict__ src,
                                                   int* __restrict__ ghist) {
    __shared__ int lh[NGRAPH];
    int tid = threadIdx.x;
    if (tid < NGRAPH) lh[tid] = 0;
    __syncthreads();
    int e0 = blockIdx.x * 4096;  // 256 blocks
    for (int k = 0; k < 16; k++) atomicAdd(&lh[src[e0 + k * 256 + tid] >> 10], 1);
    __syncthreads();
    if (tid < NGRAPH) atomicAdd(&ghist[tid], lh[tid]);
}
__global__ void scan_kernel(const int* __restrict__ ghist, int* __restrict__ gbase,
                            int* __restrict__ gcursor, int* __restrict__ gcnt) {
    if (threadIdx.x == 0) {
        int s = 0;
        for (int g = 0; g < NGRAPH; g++) {
            gbase[g] = s; gcursor[g] = s; gcnt[g] = ghist[g]; s += ghist[g];
        }
    }
}
__global__ __launch_bounds__(256) void binpass_kernel(const int* __restrict__ src,
                                                      const int* __restrict__ dst,
                                                      int* __restrict__ gcursor,
                                                      unsigned int* __restrict__ elist) {
    __shared__ int lh[NGRAPH];
    __shared__ int lbase[NGRAPH];
    int tid = threadIdx.x;
    int e0 = blockIdx.x * 4096;  // 256 blocks
    if (tid < NGRAPH) lh[tid] = 0;
    __syncthreads();
    int gs[16]; unsigned int pk[16];
    for (int k = 0; k < 16; k++) {
        int e = e0 + k * 256 + tid;
        int s = src[e], d = dst[e];
        gs[k] = s >> 10;
        pk[k] = (unsigned)(s & 1023) | ((unsigned)(d & 1023) << 10);
        atomicAdd(&lh[gs[k]], 1);
    }
    __syncthreads();
    if (tid < NGRAPH) { lbase[tid] = atomicAdd(&gcursor[tid], lh[tid]); lh[tid] = 0; }
    __syncthreads();
    for (int k = 0; k < 16; k++) {
        int g = gs[k];
        int pos = lbase[g] + atomicAdd(&lh[g], 1);
        elist[pos] = pk[k];
    }
}

// ---------------- per-graph LDS counting-sort CSR + deg1 + dinv1 -------------
__global__ __launch_bounds__(1024) void csr_sort_kernel(
    const unsigned int* __restrict__ elist, const int* __restrict__ gbase,
    const int* __restrict__ gcnt, unsigned short* __restrict__ csr16,
    int* __restrict__ node_base, int* __restrict__ deg_out, float* __restrict__ dinv_out) {
    __shared__ unsigned short sc[EMAX];  // 40 KB
    __shared__ int cnt[NPERG];           // 4 KB
    __shared__ int cur[NPERG];           // 4 KB
    int g = blockIdx.x, t = threadIdx.x;
    cnt[t] = 0;
    __syncthreads();
    int base = gbase[g];
    int n = gcnt[g]; if (n > EMAX) n = EMAX;
    for (int j = t; j < n; j += 1024) atomicAdd(&cnt[(elist[base + j] >> 10) & 1023], 1);
    __syncthreads();
    int v = cnt[t];
    for (int off = 1; off < 1024; off <<= 1) {
        int x = (t >= off) ? cnt[t - off] : 0;
        __syncthreads();
        cnt[t] += x;
        __syncthreads();
    }
    int excl = cnt[t] - v;
    cur[t] = excl;
    deg_out[g * NPERG + t] = v;
    dinv_out[g * NPERG + t] = rsqrtf((float)v + 1.0f);
    node_base[g * NPERG + t] = base + excl;
    __syncthreads();
    for (int j = t; j < n; j += 1024) {
        unsigned int pk = elist[base + j];
        int d = (pk >> 10) & 1023;
        int pos = atomicAdd(&cur[d], 1);
        sc[pos] = (unsigned short)(pk & 1023);
    }
    __syncthreads();
    for (int j = t; j < n; j += 1024) csr16[base + j] = sc[j];
}

// ---------------- GEMM1: C = A(flagged dtype) @ W, float4 LDS reads ----------
__global__ __launch_bounds__(256) void gemm_a_kernel(const void* __restrict__ Araw,
                                                     const float* __restrict__ W,
                                                     float* __restrict__ C,
                                                     const int* __restrict__ flag) {
    __shared__ float As[64 * HD];  // 32 KB
    int tid = threadIdx.x;
    int row0 = blockIdx.x * 64;
    if (flag[0]) {
        const unsigned short* Au = (const unsigned short*)Araw + (size_t)row0 * HD;
        for (int i = tid; i < 64 * HD; i += 256) As[i] = bf2f(Au[i]);
    } else {
        const float* Af = (const float*)Araw + (size_t)row0 * HD;
        for (int i = tid; i < 64 * HD / 4; i += 256)
            reinterpret_cast<float4*>(As)[i] = reinterpret_cast<const float4*>(Af)[i];
    }
    __syncthreads();
    int cg = tid & 31;
    int rg = tid >> 5;
    const float4* As4 = reinterpret_cast<const float4*>(As);
    const float4* W4 = reinterpret_cast<const float4*>(W);
    float4 acc[8];
#pragma unroll
    for (int r = 0; r < 8; r++) acc[r] = {0.f, 0.f, 0.f, 0.f};
    for (int k4 = 0; k4 < 32; k4++) {
        float4 wv0 = W4[(k4 * 4 + 0) * 32 + cg];
        float4 wv1 = W4[(k4 * 4 + 1) * 32 + cg];
        float4 wv2 = W4[(k4 * 4 + 2) * 32 + cg];
        float4 wv3 = W4[(k4 * 4 + 3) * 32 + cg];
#pragma unroll
        for (int r = 0; r < 8; r++) {
            float4 av = As4[(rg * 8 + r) * 32 + k4];
            acc[r].x += av.x * wv0.x; acc[r].y += av.x * wv0.y;
            acc[r].z += av.x * wv0.z; acc[r].w += av.x * wv0.w;
            acc[r].x += av.y * wv1.x; acc[r].y += av.y * wv1.y;
            acc[r].z += av.y * wv1.z; acc[r].w += av.y * wv1.w;
            acc[r].x += av.z * wv2.x; acc[r].y += av.z * wv2.y;
            acc[r].z += av.z * wv2.z; acc[r].w += av.z * wv2.w;
            acc[r].x += av.w * wv3.x; acc[r].y += av.w * wv3.y;
            acc[r].z += av.w * wv3.z; acc[r].w += av.w * wv3.w;
        }
    }
#pragma unroll
    for (int r = 0; r < 8; r++)
        reinterpret_cast<float4*>(C + (size_t)(row0 + rg * 8 + r) * HD)[cg] = acc[r];
}

// ---------------- conv1 aggregate (pull) + bias + relu + score ---------------
// XCD-swizzled: graph g lives entirely on XCD b&7 (b%8 round-robin heuristic).
__global__ __launch_bounds__(256) void s1_pull(const unsigned short* __restrict__ csr16,
                                               const int* __restrict__ node_base,
                                               const int* __restrict__ deg,
                                               const float* __restrict__ dinv,
                                               const float* __restrict__ xw,
                                               const float* __restrict__ b1,
                                               const float* __restrict__ pvec,
                                               const float* __restrict__ invnorm,
                                               float* __restrict__ h,
                                               float* __restrict__ score) {
    int b = blockIdx.x;                 // 16384 blocks
    int xcd = b & 7, j = b >> 3;        // j: 0..2047
    int g = (j >> 8) * 8 + xcd;         // graph, 256 blocks each, same XCD
    int n = g * NPERG + (j & 255) * 4 + (threadIdx.x >> 6);
    int lane = threadIdx.x & 63;
    int gb = g * NPERG;
    int base = node_base[n], cnt = deg[n];
    const float2* xf2 = (const float2*)xw;
    float a0 = 0.f, a1 = 0.f;
    for (int j0 = 0; j0 < cnt; j0 += 64) {
        int myj = j0 + lane;
        int s = 0; float ds = 0.f;
        if (myj < cnt) {
            s = gb + csr16[base + myj];
            ds = dinv[s];
        }
        int mm = min(64, cnt - j0);
        for (int k = 0; k < mm; k++) {
            int sk = __shfl(s, k);
            float dk = __shfl(ds, k);
            float2 v = xf2[(size_t)sk * 64 + lane];
            a0 += dk * v.x;
            a1 += dk * v.y;
        }
    }
    float dn = dinv[n];
    float self = dn * dn;
    float2 xs = xf2[(size_t)n * 64 + lane];
    float2 bb = ((const float2*)b1)[lane];
    float h0 = fmaxf(dn * a0 + self * xs.x + bb.x, 0.f);
    float h1 = fmaxf(dn * a1 + self * xs.y + bb.y, 0.f);
    float2 ho = {h0, h1};
    ((float2*)h)[(size_t)n * 64 + lane] = ho;
    float2 pp = ((const float2*)pvec)[lane];
    float sv = h0 * pp.x + h1 * pp.y;
    for (int off = 32; off; off >>= 1) sv += __shfl_down(sv, off);
    if (lane == 0) score[n] = tanhf(sv * invnorm[0]);
}

// ---------------- top-512 bitonic + fused deg2/dinv2 -------------------------
__global__ __launch_bounds__(1024) void topk_kernel(const float* __restrict__ score,
                                                    const unsigned int* __restrict__ elist,
                                                    const int* __restrict__ gbase,
                                                    const int* __restrict__ gcnt,
                                                    float* __restrict__ vals,
                                                    int* __restrict__ perm,
                                                    int* __restrict__ new_id,
                                                    float* __restrict__ dinv2) {
    __shared__ float sv[1024];
    __shared__ int si[1024];
    __shared__ short nid[1024];
    __shared__ int d2[KEEP];
    int g = blockIdx.x, t = threadIdx.x;
    sv[t] = score[g * NPERG + t];
    si[t] = t;
    nid[t] = -1;
    if (t < KEEP) d2[t] = 0;
    __syncthreads();
    for (int k = 2; k <= 1024; k <<= 1) {
        for (int j = k >> 1; j > 0; j >>= 1) {
            int l = t ^ j;
            if (l > t) {
                bool desc = ((t & k) == 0);
                float va = sv[t], vb = sv[l];
                int ia = si[t], ib = si[l];
                bool gab = (va > vb) || (va == vb && ia < ib);  // lax.top_k tie rule
                if (gab != desc) { sv[t] = vb; si[t] = ib; sv[l] = va; si[l] = ia; }
            }
            __syncthreads();
        }
    }
    if (t < KEEP) {
        int node = g * NPERG + si[t];
        int slot = g * KEEP + t;
        vals[slot] = sv[t];
        perm[slot] = node;
        new_id[node] = slot;
        nid[si[t]] = (short)t;
    }
    __syncthreads();
    int base = gbase[g], n = gcnt[g];
    for (int j = t; j < n; j += 1024) {
        unsigned int pk = elist[base + j];
        int s = pk & 1023, d = (pk >> 10) & 1023;
        short ns = nid[s], nd = nid[d];
        if (ns >= 0 && nd >= 0) atomicAdd(&d2[nd], 1);
    }
    __syncthreads();
    if (t < KEEP) dinv2[g * KEEP + t] = rsqrtf((float)d2[t] + 1.0f);
}

// ---------------- GEMM2 with fused gather+gate A-staging ---------------------
__global__ __launch_bounds__(256) void gemm_gather(const float* __restrict__ h,
                                                   const int* __restrict__ perm,
                                                   const float* __restrict__ vals,
                                                   const float* __restrict__ W,
                                                   float* __restrict__ C) {
    __shared__ float As[64 * HD];
    int tid = threadIdx.x;
    int row0 = blockIdx.x * 64;
    for (int i4 = tid; i4 < 64 * 32; i4 += 256) {
        int r = i4 >> 5, c4 = i4 & 31;
        int m = row0 + r;
        float sc = vals[m];
        float4 v = reinterpret_cast<const float4*>(h + (size_t)perm[m] * HD)[c4];
        v.x *= sc; v.y *= sc; v.z *= sc; v.w *= sc;
        reinterpret_cast<float4*>(As)[i4] = v;
    }
    __syncthreads();
    int cg = tid & 31;
    int rg = tid >> 5;
    const float4* As4 = reinterpret_cast<const float4*>(As);
    const float4* W4 = reinterpret_cast<const float4*>(W);
    float4 acc[8];
#pragma unroll
    for (int r = 0; r < 8; r++) acc[r] = {0.f, 0.f, 0.f, 0.f};
    for (int k4 = 0; k4 < 32; k4++) {
        float4 wv0 = W4[(k4 * 4 + 0) * 32 + cg];
        float4 wv1 = W4[(k4 * 4 + 1) * 32 + cg];
        float4 wv2 = W4[(k4 * 4 + 2) * 32 + cg];
        float4 wv3 = W4[(k4 * 4 + 3) * 32 + cg];
#pragma unroll
        for (int r = 0; r < 8; r++) {
            float4 av = As4[(rg * 8 + r) * 32 + k4];
            acc[r].x += av.x * wv0.x; acc[r].y += av.x * wv0.y;
            acc[r].z += av.x * wv0.z; acc[r].w += av.x * wv0.w;
            acc[r].x += av.y * wv1.x; acc[r].y += av.y * wv1.y;
            acc[r].z += av.y * wv1.z; acc[r].w += av.y * wv1.w;
            acc[r].x += av.z * wv2.x; acc[r].y += av.z * wv2.y;
            acc[r].z += av.z * wv2.z; acc[r].w += av.z * wv2.w;
            acc[r].x += av.w * wv3.x; acc[r].y += av.w * wv3.y;
            acc[r].z += av.w * wv3.z; acc[r].w += av.w * wv3.w;
        }
    }
#pragma unroll
    for (int r = 0; r < 8; r++)
        reinterpret_cast<float4*>(C + (size_t)(row0 + rg * 8 + r) * HD)[cg] = acc[r];
}

// ---------------- conv2 aggregate (pull) with new_id mask, XCD-swizzled ------
__global__ __launch_bounds__(256) void s2_pull(const unsigned short* __restrict__ csr16,
                                               const int* __restrict__ node_base,
                                               const int* __restrict__ deg,
                                               const int* __restrict__ perm,
                                               const int* __restrict__ new_id,
                                               const float* __restrict__ dinv2,
                                               const float* __restrict__ xw2,
                                               const float* __restrict__ b2,
                                               float* __restrict__ h3) {
    int b = blockIdx.x;              // 8192 blocks
    int xcd = b & 7, j = b >> 3;     // j: 0..1023
    int g = (j >> 7) * 8 + xcd;      // graph, 128 blocks each
    int m = g * KEEP + (j & 127) * 4 + (threadIdx.x >> 6);
    int lane = threadIdx.x & 63;
    int node = perm[m];
    int gb = node & ~(NPERG - 1);
    int base = node_base[node], cnt = deg[node];
    const float2* xf2 = (const float2*)xw2;
    float a0 = 0.f, a1 = 0.f;
    for (int j0 = 0; j0 < cnt; j0 += 64) {
        int myj = j0 + lane;
        int ns = -1;
        if (myj < cnt) ns = new_id[gb + csr16[base + myj]];
        float ds = (ns >= 0) ? dinv2[ns] : 0.f;
        int mm = min(64, cnt - j0);
        for (int k = 0; k < mm; k++) {
            int nk = __shfl(ns, k);
            if (nk >= 0) {
                float dk = __shfl(ds, k);
                float2 v = xf2[(size_t)nk * 64 + lane];
                a0 += dk * v.x;
                a1 += dk * v.y;
            }
        }
    }
    float dn = dinv2[m];
    float self = dn * dn;
    float2 xs = xf2[(size_t)m * 64 + lane];
    float2 bb = ((const float2*)b2)[lane];
    float2 ho;
    ho.x = fmaxf(dn * a0 + self * xs.x + bb.x, 0.f);
    ho.y = fmaxf(dn * a1 + self * xs.y + bb.y, 0.f);
    ((float2*)h3)[(size_t)m * 64 + lane] = ho;
}

// ---------------- mean-pool + linear; output dtype follows flag --------------
__global__ __launch_bounds__(512) void pool_kernel(const float* __restrict__ h3,
                                                   const float* __restrict__ Wl,
                                                   const float* __restrict__ bl,
                                                   void* __restrict__ outv,
                                                   const int* __restrict__ flag) {
    int g = blockIdx.x, t = threadIdx.x;  // 512
    int c = t & 127, rg = t >> 7;
    const float* base = h3 + (size_t)g * KEEP * HD;
    float sum = 0.f;
    for (int k = rg; k < KEEP; k += 4) sum += base[(size_t)k * HD + c];
    __shared__ float sp[4][128];
    sp[rg][c] = sum;
    __syncthreads();
    if (t < 128) sp[0][t] = (sp[0][t] + sp[1][t] + sp[2][t] + sp[3][t]) * (1.0f / KEEP);
    __syncthreads();
    if (t < NC) {
        float acc = bl[t];
        for (int hh = 0; hh < HD; hh++) acc += sp[0][hh] * Wl[hh * NC + t];
        if (flag[0]) ((unsigned short*)outv)[g * NC + t] = f2bf(acc);
        else         ((float*)outv)[g * NC + t] = acc;
    }
}

extern "C" void kernel_launch(void* const* d_in, const int* in_sizes, int n_in,
                              void* d_out, int out_size, void* d_ws, size_t ws_size,
                              hipStream_t stream) {
    const int* ei   = (const int*)d_in[1];
    const int* srcv = ei;
    const int* dstv = ei + NEDGES;

    char* w = (char*)d_ws;
    const size_t MB = 1u << 20;
    const size_t KB = 1024;
    float* dinv1     = (float*)(w + 0);                 // 256 KB
    float* score     = (float*)(w + 256 * KB);          // 256 KB
    float* vals      = (float*)(w + 512 * KB);          // 128 KB
    int*   perm      = (int*)(w + 640 * KB);            // 128 KB
    int*   new_id    = (int*)(w + 768 * KB);            // 256 KB
    int*   deg1      = (int*)(w + 1024 * KB);           // 256 KB
    int*   node_base = (int*)(w + 1280 * KB);           // 256 KB
    float* dinv2     = (float*)(w + 1536 * KB);         // 128 KB
    float* invnorm   = (float*)(w + 1664 * KB);
    int*   flag      = (int*)(w + 1664 * KB + 64);
    int*   ghist     = (int*)(w + 1664 * KB + 1024);
    int*   gbase     = (int*)(w + 1664 * KB + 2048);
    int*   gcursor   = (int*)(w + 1664 * KB + 3072);
    int*   gcnt      = (int*)(w + 1664 * KB + 4096);
    float* cw        = (float*)(w + 1700 * KB);         // 135 KB canonical weights
    float* xw1  = (float*)(w + 2 * MB);                 // [2,34) MB
    float* agg  = (float*)(w + 34 * MB);                // [34,66) MB  (h)
    float* xw2  = (float*)(w + 2 * MB);                 // xw1 dead after s1
    float* agg2 = (float*)(w + 34 * MB);                // h dead after gemm_gather
    unsigned int* elist    = (unsigned int*)(w + 66 * MB);   // [66,70) MB
    unsigned short* csr16  = (unsigned short*)(w + 70 * MB); // [70,72) MB

    float* W1f = cw + OW1; float* W2f = cw + OW2; float* Wlf = cw + OWL;
    float* b1f = cw + OB1; float* b2f = cw + OB2; float* pf  = cw + OP;
    float* blf = cw + OBL;

    prep_kernel<<<392, 256, 0, stream>>>(d_in[3], d_in[4], d_in[5], d_in[6], d_in[7],
                                         d_in[8], d_in[9], flag, cw, invnorm, new_id, ghist);
    hist_kernel<<<256, 256, 0, stream>>>(srcv, ghist);
    scan_kernel<<<1, 64, 0, stream>>>(ghist, gbase, gcursor, gcnt);
    binpass_kernel<<<256, 256, 0, stream>>>(srcv, dstv, gcursor, elist);
    gemm_a_kernel<<<NNODES / 64, 256, 0, stream>>>(d_in[0], W1f, xw1, flag);
    csr_sort_kernel<<<NGRAPH, 1024, 0, stream>>>(elist, gbase, gcnt, csr16, node_base,
                                                 deg1, dinv1);
    s1_pull<<<NNODES / 4, 256, 0, stream>>>(csr16, node_base, deg1, dinv1, xw1, b1f, pf,
                                            invnorm, agg, score);
    topk_kernel<<<NGRAPH, 1024, 0, stream>>>(score, elist, gbase, gcnt, vals, perm,
                                             new_id, dinv2);
    gemm_gather<<<M2 / 64, 256, 0, stream>>>(agg, perm, vals, W2f, xw2);
    s2_pull<<<M2 / 4, 256, 0, stream>>>(csr16, node_base, deg1, perm, new_id, dinv2,
                                        xw2, b2f, agg2);
    pool_kernel<<<NGRAPH, 512, 0, stream>>>(agg2, Wlf, blf, d_out, flag);

    (void)in_sizes; (void)n_in; (void)out_size; (void)ws_size;
}

// Round 10
// 311.956 us; speedup vs baseline: 4.9869x; 1.0324x over previous
//
#include <hip/hip_runtime.h>

#define NNODES 65536
#define NEDGES 1048576
#define NGRAPH 64
#define NPERG  1024
#define KEEP   512
#define M2     (NGRAPH * KEEP)   // 32768
#define HD     128
#define NC     10
#define EMAX   20480             // per-graph edge capacity (avg 16384, sigma~127)

// canonical weight block offsets (floats)
#define OW1 0
#define OW2 16384
#define OWL 32768
#define OB1 34048
#define OB2 34176
#define OP  34304
#define OBL 34432
#define NCVT 34448

__device__ __forceinline__ float bf2f(unsigned short u) {
    return __uint_as_float(((unsigned int)u) << 16);
}
__device__ __forceinline__ unsigned short f2bf(float f) {
    unsigned int u = __float_as_uint(f);
    unsigned int r = (u + 0x7FFFu + ((u >> 16) & 1u)) >> 16;
    return (unsigned short)r;
}

// ---------------- prep: detect dtype + cvt weights + pnorm + init ------------
__global__ __launch_bounds__(256) void prep_kernel(
    const void* __restrict__ W1, const void* __restrict__ b1, const void* __restrict__ p,
    const void* __restrict__ W2, const void* __restrict__ b2, const void* __restrict__ Wl,
    const void* __restrict__ bl, int* __restrict__ flag, float* __restrict__ cw,
    float* __restrict__ invnorm, int* __restrict__ new_id, int* __restrict__ ghist) {
    int bid = blockIdx.x, t = threadIdx.x;
    const unsigned short* w1u = (const unsigned short*)W1;
    int local = 0;
    for (int i = t; i < 512; i += 256) {
        unsigned short u = w1u[2 * i];
        int e = (u >> 7) & 0xFF;
        local += (e >= 100 && e <= 140) ? 1 : 0;
    }
    __shared__ int red[256];
    red[t] = local;
    __syncthreads();
    for (int off = 128; off; off >>= 1) {
        if (t < off) red[t] += red[t + off];
        __syncthreads();
    }
    int fl = (red[0] >= 384) ? 1 : 0;
    if (bid == 0 && t == 0) flag[0] = fl;

    if (bid < 135) {
        int gid = bid * 256 + t;
        if (gid < NCVT) {
            const void* srcp; int idx;
            if (gid < OB1) {
                if (gid < OW2)      { srcp = W1; idx = gid - OW1; }
                else if (gid < OWL) { srcp = W2; idx = gid - OW2; }
                else                { srcp = Wl; idx = gid - OWL; }
            } else {
                if (gid < OB2)      { srcp = b1; idx = gid - OB1; }
                else if (gid < OP)  { srcp = b2; idx = gid - OB2; }
                else if (gid < OBL) { srcp = p;  idx = gid - OP; }
                else                { srcp = bl; idx = gid - OBL; }
            }
            float v;
            if (gid >= OWL && gid < OB1 && idx >= 1280) v = 0.f;       // Wl pad
            else if (gid >= OBL && idx >= NC) v = 0.f;                  // bl pad
            else if (fl) v = bf2f(((const unsigned short*)srcp)[idx]);
            else v = ((const float*)srcp)[idx];
            cw[gid] = v;
        }
    } else if (bid == 135) {
        __shared__ float s2a[128];
        float pv = 0.f;
        if (t < 128) pv = fl ? bf2f(((const unsigned short*)p)[t]) : ((const float*)p)[t];
        if (t < 128) s2a[t] = pv * pv;
        __syncthreads();
        for (int off = 64; off; off >>= 1) {
            if (t < off) s2a[t] += s2a[t + off];
            __syncthreads();
        }
        if (t == 0) invnorm[0] = 1.0f / sqrtf(s2a[0]);
    } else {
        int i = (bid - 136) * 256 + t;
        new_id[i] = -1;
        if (i < NGRAPH) ghist[i] = 0;
    }
}

// ---------------- edge binning by graph --------------------------------------
__global__ __launch_bounds__(256) void hist_kernel(const int* __restrict__ src,
                                                   int* __restrict__ ghist) {
    __shared__ int lh[NGRAPH];
    int tid = threadIdx.x;
    if (tid < NGRAPH) lh[tid] = 0;
    __syncthreads();
    int e0 = blockIdx.x * 4096;  // 256 blocks
    for (int k = 0; k < 16; k++) atomicAdd(&lh[src[e0 + k * 256 + tid] >> 10], 1);
    __syncthreads();
    if (tid < NGRAPH) atomicAdd(&ghist[tid], lh[tid]);
}
__global__ void scan_kernel(const int* __restrict__ ghist, int* __restrict__ gbase,
                            int* __restrict__ gcursor, int* __restrict__ gcnt) {
    if (threadIdx.x == 0) {
        int s = 0;
        for (int g = 0; g < NGRAPH; g++) {
            gbase[g] = s; gcursor[g] = s; gcnt[g] = ghist[g]; s += ghist[g];
        }
    }
}
__global__ __launch_bounds__(256) void binpass_kernel(const int* __restrict__ src,
                                                      const int* __restrict__ dst,
                                                      int* __restrict__ gcursor,
                                                      unsigned int* __restrict__ elist) {
    __shared__ int lh[NGRAPH];
    __shared__ int lbase[NGRAPH];
    int tid = threadIdx.x;
    int e0 = blockIdx.x * 4096;  // 256 blocks
    if (tid < NGRAPH) lh[tid] = 0;
    __syncthreads();
    int gs[16]; unsigned int pk[16];
    for (int k = 0; k < 16; k++) {
        int e = e0 + k * 256 + tid;
        int s = src[e], d = dst[e];
        gs[k] = s >> 10;
        pk[k] = (unsigned)(s & 1023) | ((unsigned)(d & 1023) << 10);
        atomicAdd(&lh[gs[k]], 1);
    }
    __syncthreads();
    if (tid < NGRAPH) { lbase[tid] = atomicAdd(&gcursor[tid], lh[tid]); lh[tid] = 0; }
    __syncthreads();
    for (int k = 0; k < 16; k++) {
        int g = gs[k];
        int pos = lbase[g] + atomicAdd(&lh[g], 1);
        elist[pos] = pk[k];
    }
}

// ---------------- per-graph LDS counting-sort CSR + deg1 + dinv1 -------------
__global__ __launch_bounds__(1024) void csr_sort_kernel(
    const unsigned int* __restrict__ elist, const int* __restrict__ gbase,
    const int* __restrict__ gcnt, unsigned short* __restrict__ csr16,
    int* __restrict__ node_base, int* __restrict__ deg_out, float* __restrict__ dinv_out) {
    __shared__ unsigned short sc[EMAX];  // 40 KB
    __shared__ int cnt[NPERG];           // 4 KB
    __shared__ int cur[NPERG];           // 4 KB
    int g = blockIdx.x, t = threadIdx.x;
    cnt[t] = 0;
    __syncthreads();
    int base = gbase[g];
    int n = gcnt[g]; if (n > EMAX) n = EMAX;
    for (int j = t; j < n; j += 1024) atomicAdd(&cnt[(elist[base + j] >> 10) & 1023], 1);
    __syncthreads();
    int v = cnt[t];
    for (int off = 1; off < 1024; off <<= 1) {
        int x = (t >= off) ? cnt[t - off] : 0;
        __syncthreads();
        cnt[t] += x;
        __syncthreads();
    }
    int excl = cnt[t] - v;
    cur[t] = excl;
    deg_out[g * NPERG + t] = v;
    dinv_out[g * NPERG + t] = rsqrtf((float)v + 1.0f);
    node_base[g * NPERG + t] = base + excl;
    __syncthreads();
    for (int j = t; j < n; j += 1024) {
        unsigned int pk = elist[base + j];
        int d = (pk >> 10) & 1023;
        int pos = atomicAdd(&cur[d], 1);
        sc[pos] = (unsigned short)(pk & 1023);
    }
    __syncthreads();
    for (int j = t; j < n; j += 1024) csr16[base + j] = sc[j];
}

// ---------------- GEMM1: C = A(flagged dtype) @ W, float4 LDS reads ----------
__global__ __launch_bounds__(256) void gemm_a_kernel(const void* __restrict__ Araw,
                                                     const float* __restrict__ W,
                                                     float* __restrict__ C,
                                                     const int* __restrict__ flag) {
    __shared__ float As[64 * HD];  // 32 KB
    int tid = threadIdx.x;
    int row0 = blockIdx.x * 64;
    if (flag[0]) {
        const unsigned short* Au = (const unsigned short*)Araw + (size_t)row0 * HD;
        for (int i = tid; i < 64 * HD; i += 256) As[i] = bf2f(Au[i]);
    } else {
        const float* Af = (const float*)Araw + (size_t)row0 * HD;
        for (int i = tid; i < 64 * HD / 4; i += 256)
            reinterpret_cast<float4*>(As)[i] = reinterpret_cast<const float4*>(Af)[i];
    }
    __syncthreads();
    int cg = tid & 31;
    int rg = tid >> 5;
    const float4* As4 = reinterpret_cast<const float4*>(As);
    const float4* W4 = reinterpret_cast<const float4*>(W);
    float4 acc[8];
#pragma unroll
    for (int r = 0; r < 8; r++) acc[r] = {0.f, 0.f, 0.f, 0.f};
    for (int k4 = 0; k4 < 32; k4++) {
        float4 wv0 = W4[(k4 * 4 + 0) * 32 + cg];
        float4 wv1 = W4[(k4 * 4 + 1) * 32 + cg];
        float4 wv2 = W4[(k4 * 4 + 2) * 32 + cg];
        float4 wv3 = W4[(k4 * 4 + 3) * 32 + cg];
#pragma unroll
        for (int r = 0; r < 8; r++) {
            float4 av = As4[(rg * 8 + r) * 32 + k4];
            acc[r].x += av.x * wv0.x; acc[r].y += av.x * wv0.y;
            acc[r].z += av.x * wv0.z; acc[r].w += av.x * wv0.w;
            acc[r].x += av.y * wv1.x; acc[r].y += av.y * wv1.y;
            acc[r].z += av.y * wv1.z; acc[r].w += av.y * wv1.w;
            acc[r].x += av.z * wv2.x; acc[r].y += av.z * wv2.y;
            acc[r].z += av.z * wv2.z; acc[r].w += av.z * wv2.w;
            acc[r].x += av.w * wv3.x; acc[r].y += av.w * wv3.y;
            acc[r].z += av.w * wv3.z; acc[r].w += av.w * wv3.w;
        }
    }
#pragma unroll
    for (int r = 0; r < 8; r++)
        reinterpret_cast<float4*>(C + (size_t)(row0 + rg * 8 + r) * HD)[cg] = acc[r];
}

// ---------------- conv1 aggregate (pull, 4-edge-parallel) + relu + score -----
// Wave layout: grp=lane>>4 handles edge slot j0+grp; cl=lane&15 covers
// channels [8*cl,8*cl+8). Edge scalars via 16-lane same-address loads (TCP
// broadcast) — zero shfls in the hot loop. Group-reduce via shfl_xor(16,32);
// replicas are bitwise identical (commutative pairwise adds), so the
// all-64-lane score sum is exactly 4x -> *0.25f exact.
__global__ __launch_bounds__(256) void s1_pull(const unsigned short* __restrict__ csr16,
                                               const int* __restrict__ node_base,
                                               const int* __restrict__ deg,
                                               const float* __restrict__ dinv,
                                               const float* __restrict__ xw,
                                               const float* __restrict__ b1,
                                               const float* __restrict__ pvec,
                                               const float* __restrict__ invnorm,
                                               float* __restrict__ h,
                                               float* __restrict__ score) {
    int b = blockIdx.x;                 // 16384 blocks
    int xcd = b & 7, j = b >> 3;        // XCD-swizzle: graph pinned to one XCD
    int g = (j >> 8) * 8 + xcd;
    int n = g * NPERG + (j & 255) * 4 + (threadIdx.x >> 6);
    int lane = threadIdx.x & 63;
    int grp = lane >> 4, cl = lane & 15;
    int gb = g * NPERG;
    int base = node_base[n], cnt = deg[n];
    const float4* xf4 = (const float4*)xw;  // row stride 32 float4
    float4 a0 = {0.f, 0.f, 0.f, 0.f}, a1 = {0.f, 0.f, 0.f, 0.f};
    for (int j0 = 0; j0 < cnt; j0 += 4) {
        int myj = j0 + grp;
        int s = 0; float ds = 0.f;
        if (myj < cnt) {
            s = csr16[base + myj];        // 16-lane same-address broadcast
            ds = dinv[gb + s];
        }
        const float4* row = xf4 + ((size_t)(gb + s) * 32 + cl * 2);
        float4 v0 = row[0], v1 = row[1];
        a0.x += ds * v0.x; a0.y += ds * v0.y; a0.z += ds * v0.z; a0.w += ds * v0.w;
        a1.x += ds * v1.x; a1.y += ds * v1.y; a1.z += ds * v1.z; a1.w += ds * v1.w;
    }
    // reduce across the 4 edge groups
#pragma unroll
    for (int off = 16; off <= 32; off <<= 1) {
        a0.x += __shfl_xor(a0.x, off); a0.y += __shfl_xor(a0.y, off);
        a0.z += __shfl_xor(a0.z, off); a0.w += __shfl_xor(a0.w, off);
        a1.x += __shfl_xor(a1.x, off); a1.y += __shfl_xor(a1.y, off);
        a1.z += __shfl_xor(a1.z, off); a1.w += __shfl_xor(a1.w, off);
    }
    float dn = dinv[n];
    float self = dn * dn;
    float4 xs0 = xf4[(size_t)n * 32 + cl * 2];
    float4 xs1 = xf4[(size_t)n * 32 + cl * 2 + 1];
    float4 bb0 = ((const float4*)b1)[cl * 2];
    float4 bb1 = ((const float4*)b1)[cl * 2 + 1];
    float4 h0, h1;
    h0.x = fmaxf(dn * a0.x + self * xs0.x + bb0.x, 0.f);
    h0.y = fmaxf(dn * a0.y + self * xs0.y + bb0.y, 0.f);
    h0.z = fmaxf(dn * a0.z + self * xs0.z + bb0.z, 0.f);
    h0.w = fmaxf(dn * a0.w + self * xs0.w + bb0.w, 0.f);
    h1.x = fmaxf(dn * a1.x + self * xs1.x + bb1.x, 0.f);
    h1.y = fmaxf(dn * a1.y + self * xs1.y + bb1.y, 0.f);
    h1.z = fmaxf(dn * a1.z + self * xs1.z + bb1.z, 0.f);
    h1.w = fmaxf(dn * a1.w + self * xs1.w + bb1.w, 0.f);
    if (grp == 0) {
        ((float4*)h)[(size_t)n * 32 + cl * 2] = h0;
        ((float4*)h)[(size_t)n * 32 + cl * 2 + 1] = h1;
    }
    // fused score (all 64 lanes hold replicas -> sum is 4x the true dot)
    float4 pp0 = ((const float4*)pvec)[cl * 2];
    float4 pp1 = ((const float4*)pvec)[cl * 2 + 1];
    float sv = h0.x * pp0.x + h0.y * pp0.y + h0.z * pp0.z + h0.w * pp0.w +
               h1.x * pp1.x + h1.y * pp1.y + h1.z * pp1.z + h1.w * pp1.w;
    for (int off = 32; off; off >>= 1) sv += __shfl_down(sv, off);
    if (lane == 0) score[n] = tanhf(sv * 0.25f * invnorm[0]);
}

// ---------------- top-512 bitonic + fused deg2/dinv2 -------------------------
__global__ __launch_bounds__(1024) void topk_kernel(const float* __restrict__ score,
                                                    const unsigned int* __restrict__ elist,
                                                    const int* __restrict__ gbase,
                                                    const int* __restrict__ gcnt,
                                                    float* __restrict__ vals,
                                                    int* __restrict__ perm,
                                                    int* __restrict__ new_id,
                                                    float* __restrict__ dinv2) {
    __shared__ float sv[1024];
    __shared__ int si[1024];
    __shared__ short nid[1024];
    __shared__ int d2[KEEP];
    int g = blockIdx.x, t = threadIdx.x;
    sv[t] = score[g * NPERG + t];
    si[t] = t;
    nid[t] = -1;
    if (t < KEEP) d2[t] = 0;
    __syncthreads();
    for (int k = 2; k <= 1024; k <<= 1) {
        for (int j = k >> 1; j > 0; j >>= 1) {
            int l = t ^ j;
            if (l > t) {
                bool desc = ((t & k) == 0);
                float va = sv[t], vb = sv[l];
                int ia = si[t], ib = si[l];
                bool gab = (va > vb) || (va == vb && ia < ib);  // lax.top_k tie rule
                if (gab != desc) { sv[t] = vb; si[t] = ib; sv[l] = va; si[l] = ia; }
            }
            __syncthreads();
        }
    }
    if (t < KEEP) {
        int node = g * NPERG + si[t];
        int slot = g * KEEP + t;
        vals[slot] = sv[t];
        perm[slot] = node;
        new_id[node] = slot;
        nid[si[t]] = (short)t;
    }
    __syncthreads();
    int base = gbase[g], n = gcnt[g];
    for (int j = t; j < n; j += 1024) {
        unsigned int pk = elist[base + j];
        int s = pk & 1023, d = (pk >> 10) & 1023;
        short ns = nid[s], nd = nid[d];
        if (ns >= 0 && nd >= 0) atomicAdd(&d2[nd], 1);
    }
    __syncthreads();
    if (t < KEEP) dinv2[g * KEEP + t] = rsqrtf((float)d2[t] + 1.0f);
}

// ---------------- GEMM2 with fused gather+gate A-staging ---------------------
__global__ __launch_bounds__(256) void gemm_gather(const float* __restrict__ h,
                                                   const int* __restrict__ perm,
                                                   const float* __restrict__ vals,
                                                   const float* __restrict__ W,
                                                   float* __restrict__ C) {
    __shared__ float As[64 * HD];
    int tid = threadIdx.x;
    int row0 = blockIdx.x * 64;
    for (int i4 = tid; i4 < 64 * 32; i4 += 256) {
        int r = i4 >> 5, c4 = i4 & 31;
        int m = row0 + r;
        float sc = vals[m];
        float4 v = reinterpret_cast<const float4*>(h + (size_t)perm[m] * HD)[c4];
        v.x *= sc; v.y *= sc; v.z *= sc; v.w *= sc;
        reinterpret_cast<float4*>(As)[i4] = v;
    }
    __syncthreads();
    int cg = tid & 31;
    int rg = tid >> 5;
    const float4* As4 = reinterpret_cast<const float4*>(As);
    const float4* W4 = reinterpret_cast<const float4*>(W);
    float4 acc[8];
#pragma unroll
    for (int r = 0; r < 8; r++) acc[r] = {0.f, 0.f, 0.f, 0.f};
    for (int k4 = 0; k4 < 32; k4++) {
        float4 wv0 = W4[(k4 * 4 + 0) * 32 + cg];
        float4 wv1 = W4[(k4 * 4 + 1) * 32 + cg];
        float4 wv2 = W4[(k4 * 4 + 2) * 32 + cg];
        float4 wv3 = W4[(k4 * 4 + 3) * 32 + cg];
#pragma unroll
        for (int r = 0; r < 8; r++) {
            float4 av = As4[(rg * 8 + r) * 32 + k4];
            acc[r].x += av.x * wv0.x; acc[r].y += av.x * wv0.y;
            acc[r].z += av.x * wv0.z; acc[r].w += av.x * wv0.w;
            acc[r].x += av.y * wv1.x; acc[r].y += av.y * wv1.y;
            acc[r].z += av.y * wv1.z; acc[r].w += av.y * wv1.w;
            acc[r].x += av.z * wv2.x; acc[r].y += av.z * wv2.y;
            acc[r].z += av.z * wv2.z; acc[r].w += av.z * wv2.w;
            acc[r].x += av.w * wv3.x; acc[r].y += av.w * wv3.y;
            acc[r].z += av.w * wv3.z; acc[r].w += av.w * wv3.w;
        }
    }
#pragma unroll
    for (int r = 0; r < 8; r++)
        reinterpret_cast<float4*>(C + (size_t)(row0 + rg * 8 + r) * HD)[cg] = acc[r];
}

// ---------------- conv2 aggregate (pull, 4-edge-parallel) with mask ----------
__global__ __launch_bounds__(256) void s2_pull(const unsigned short* __restrict__ csr16,
                                               const int* __restrict__ node_base,
                                               const int* __restrict__ deg,
                                               const int* __restrict__ perm,
                                               const int* __restrict__ new_id,
                                               const float* __restrict__ dinv2,
                                               const float* __restrict__ xw2,
                                               const float* __restrict__ b2,
                                               float* __restrict__ h3) {
    int b = blockIdx.x;              // 8192 blocks
    int xcd = b & 7, j = b >> 3;
    int g = (j >> 7) * 8 + xcd;
    int m = g * KEEP + (j & 127) * 4 + (threadIdx.x >> 6);
    int lane = threadIdx.x & 63;
    int grp = lane >> 4, cl = lane & 15;
    int node = perm[m];
    int gb = node & ~(NPERG - 1);
    int base = node_base[node], cnt = deg[node];
    const float4* xf4 = (const float4*)xw2;
    float4 a0 = {0.f, 0.f, 0.f, 0.f}, a1 = {0.f, 0.f, 0.f, 0.f};
    for (int j0 = 0; j0 < cnt; j0 += 4) {
        int myj = j0 + grp;
        int ns = -1;
        if (myj < cnt) ns = new_id[gb + csr16[base + myj]];
        float ds = (ns >= 0) ? dinv2[ns] : 0.f;
        int nk = (ns >= 0) ? ns : 0;
        const float4* row = xf4 + ((size_t)nk * 32 + cl * 2);
        float4 v0 = row[0], v1 = row[1];
        a0.x += ds * v0.x; a0.y += ds * v0.y; a0.z += ds * v0.z; a0.w += ds * v0.w;
        a1.x += ds * v1.x; a1.y += ds * v1.y; a1.z += ds * v1.z; a1.w += ds * v1.w;
    }
#pragma unroll
    for (int off = 16; off <= 32; off <<= 1) {
        a0.x += __shfl_xor(a0.x, off); a0.y += __shfl_xor(a0.y, off);
        a0.z += __shfl_xor(a0.z, off); a0.w += __shfl_xor(a0.w, off);
        a1.x += __shfl_xor(a1.x, off); a1.y += __shfl_xor(a1.y, off);
        a1.z += __shfl_xor(a1.z, off); a1.w += __shfl_xor(a1.w, off);
    }
    if (grp == 0) {
        float dn = dinv2[m];
        float self = dn * dn;
        float4 xs0 = xf4[(size_t)m * 32 + cl * 2];
        float4 xs1 = xf4[(size_t)m * 32 + cl * 2 + 1];
        float4 bb0 = ((const float4*)b2)[cl * 2];
        float4 bb1 = ((const float4*)b2)[cl * 2 + 1];
        float4 o0, o1;
        o0.x = fmaxf(dn * a0.x + self * xs0.x + bb0.x, 0.f);
        o0.y = fmaxf(dn * a0.y + self * xs0.y + bb0.y, 0.f);
        o0.z = fmaxf(dn * a0.z + self * xs0.z + bb0.z, 0.f);
        o0.w = fmaxf(dn * a0.w + self * xs0.w + bb0.w, 0.f);
        o1.x = fmaxf(dn * a1.x + self * xs1.x + bb1.x, 0.f);
        o1.y = fmaxf(dn * a1.y + self * xs1.y + bb1.y, 0.f);
        o1.z = fmaxf(dn * a1.z + self * xs1.z + bb1.z, 0.f);
        o1.w = fmaxf(dn * a1.w + self * xs1.w + bb1.w, 0.f);
        ((float4*)h3)[(size_t)m * 32 + cl * 2] = o0;
        ((float4*)h3)[(size_t)m * 32 + cl * 2 + 1] = o1;
    }
}

// ---------------- mean-pool + linear; output dtype follows flag --------------
__global__ __launch_bounds__(512) void pool_kernel(const float* __restrict__ h3,
                                                   const float* __restrict__ Wl,
                                                   const float* __restrict__ bl,
                                                   void* __restrict__ outv,
                                                   const int* __restrict__ flag) {
    int g = blockIdx.x, t = threadIdx.x;  // 512
    int c = t & 127, rg = t >> 7;
    const float* base = h3 + (size_t)g * KEEP * HD;
    float sum = 0.f;
    for (int k = rg; k < KEEP; k += 4) sum += base[(size_t)k * HD + c];
    __shared__ float sp[4][128];
    sp[rg][c] = sum;
    __syncthreads();
    if (t < 128) sp[0][t] = (sp[0][t] + sp[1][t] + sp[2][t] + sp[3][t]) * (1.0f / KEEP);
    __syncthreads();
    if (t < NC) {
        float acc = bl[t];
        for (int hh = 0; hh < HD; hh++) acc += sp[0][hh] * Wl[hh * NC + t];
        if (flag[0]) ((unsigned short*)outv)[g * NC + t] = f2bf(acc);
        else         ((float*)outv)[g * NC + t] = acc;
    }
}

extern "C" void kernel_launch(void* const* d_in, const int* in_sizes, int n_in,
                              void* d_out, int out_size, void* d_ws, size_t ws_size,
                              hipStream_t stream) {
    const int* ei   = (const int*)d_in[1];
    const int* srcv = ei;
    const int* dstv = ei + NEDGES;

    char* w = (char*)d_ws;
    const size_t MB = 1u << 20;
    const size_t KB = 1024;
    float* dinv1     = (float*)(w + 0);                 // 256 KB
    float* score     = (float*)(w + 256 * KB);          // 256 KB
    float* vals      = (float*)(w + 512 * KB);          // 128 KB
    int*   perm      = (int*)(w + 640 * KB);            // 128 KB
    int*   new_id    = (int*)(w + 768 * KB);            // 256 KB
    int*   deg1      = (int*)(w + 1024 * KB);           // 256 KB
    int*   node_base = (int*)(w + 1280 * KB);           // 256 KB
    float* dinv2     = (float*)(w + 1536 * KB);         // 128 KB
    float* invnorm   = (float*)(w + 1664 * KB);
    int*   flag      = (int*)(w + 1664 * KB + 64);
    int*   ghist     = (int*)(w + 1664 * KB + 1024);
    int*   gbase     = (int*)(w + 1664 * KB + 2048);
    int*   gcursor   = (int*)(w + 1664 * KB + 3072);
    int*   gcnt      = (int*)(w + 1664 * KB + 4096);
    float* cw        = (float*)(w + 1700 * KB);         // 135 KB canonical weights
    float* xw1  = (float*)(w + 2 * MB);                 // [2,34) MB
    float* agg  = (float*)(w + 34 * MB);                // [34,66) MB  (h)
    float* xw2  = (float*)(w + 2 * MB);                 // xw1 dead after s1
    float* agg2 = (float*)(w + 34 * MB);                // h dead after gemm_gather
    unsigned int* elist    = (unsigned int*)(w + 66 * MB);   // [66,70) MB
    unsigned short* csr16  = (unsigned short*)(w + 70 * MB); // [70,72) MB

    float* W1f = cw + OW1; float* W2f = cw + OW2; float* Wlf = cw + OWL;
    float* b1f = cw + OB1; float* b2f = cw + OB2; float* pf  = cw + OP;
    float* blf = cw + OBL;

    prep_kernel<<<392, 256, 0, stream>>>(d_in[3], d_in[4], d_in[5], d_in[6], d_in[7],
                                         d_in[8], d_in[9], flag, cw, invnorm, new_id, ghist);
    hist_kernel<<<256, 256, 0, stream>>>(srcv, ghist);
    scan_kernel<<<1, 64, 0, stream>>>(ghist, gbase, gcursor, gcnt);
    binpass_kernel<<<256, 256, 0, stream>>>(srcv, dstv, gcursor, elist);
    gemm_a_kernel<<<NNODES / 64, 256, 0, stream>>>(d_in[0], W1f, xw1, flag);
    csr_sort_kernel<<<NGRAPH, 1024, 0, stream>>>(elist, gbase, gcnt, csr16, node_base,
                                                 deg1, dinv1);
    s1_pull<<<NNODES / 4, 256, 0, stream>>>(csr16, node_base, deg1, dinv1, xw1, b1f, pf,
                                            invnorm, agg, score);
    topk_kernel<<<NGRAPH, 1024, 0, stream>>>(score, elist, gbase, gcnt, vals, perm,
                                             new_id, dinv2);
    gemm_gather<<<M2 / 64, 256, 0, stream>>>(agg, perm, vals, W2f, xw2);
    s2_pull<<<M2 / 4, 256, 0, stream>>>(csr16, node_base, deg1, perm, new_id, dinv2,
                                        xw2, b2f, agg2);
    pool_kernel<<<NGRAPH, 512, 0, stream>>>(agg2, Wlf, blf, d_out, flag);

    (void)in_sizes; (void)n_in; (void)out_size; (void)ws_size;
}

// Round 11
// 303.309 us; speedup vs baseline: 5.1291x; 1.0285x over previous
//
#include <hip/hip_runtime.h>

#define NNODES 65536
#define NEDGES 1048576
#define NGRAPH 64
#define NPERG  1024
#define KEEP   512
#define M2     (NGRAPH * KEEP)   // 32768
#define HD     128
#define NC     10
#define EMAX   20480             // per-graph edge capacity (avg 16384, sigma~127)

// canonical weight block offsets (floats)
#define OW1 0
#define OW2 16384
#define OWL 32768
#define OB1 34048
#define OB2 34176
#define OP  34304
#define OBL 34432
#define NCVT 34448

__device__ __forceinline__ float bf2f(unsigned short u) {
    return __uint_as_float(((unsigned int)u) << 16);
}
__device__ __forceinline__ unsigned short f2bf(float f) {
    unsigned int u = __float_as_uint(f);
    unsigned int r = (u + 0x7FFFu + ((u >> 16) & 1u)) >> 16;
    return (unsigned short)r;
}

// ---------------- prep: detect dtype + cvt weights + pnorm + init ------------
__global__ __launch_bounds__(256) void prep_kernel(
    const void* __restrict__ W1, const void* __restrict__ b1, const void* __restrict__ p,
    const void* __restrict__ W2, const void* __restrict__ b2, const void* __restrict__ Wl,
    const void* __restrict__ bl, int* __restrict__ flag, float* __restrict__ cw,
    float* __restrict__ invnorm, int* __restrict__ new_id, int* __restrict__ ghist,
    int* __restrict__ gcur0, float* __restrict__ pooled) {
    int bid = blockIdx.x, t = threadIdx.x;
    const unsigned short* w1u = (const unsigned short*)W1;
    int local = 0;
    for (int i = t; i < 512; i += 256) {
        unsigned short u = w1u[2 * i];
        int e = (u >> 7) & 0xFF;
        local += (e >= 100 && e <= 140) ? 1 : 0;
    }
    __shared__ int red[256];
    red[t] = local;
    __syncthreads();
    for (int off = 128; off; off >>= 1) {
        if (t < off) red[t] += red[t + off];
        __syncthreads();
    }
    int fl = (red[0] >= 384) ? 1 : 0;
    if (bid == 0 && t == 0) flag[0] = fl;

    if (bid < 135) {
        int gid = bid * 256 + t;
        if (gid < NCVT) {
            const void* srcp; int idx;
            if (gid < OB1) {
                if (gid < OW2)      { srcp = W1; idx = gid - OW1; }
                else if (gid < OWL) { srcp = W2; idx = gid - OW2; }
                else                { srcp = Wl; idx = gid - OWL; }
            } else {
                if (gid < OB2)      { srcp = b1; idx = gid - OB1; }
                else if (gid < OP)  { srcp = b2; idx = gid - OB2; }
                else if (gid < OBL) { srcp = p;  idx = gid - OP; }
                else                { srcp = bl; idx = gid - OBL; }
            }
            float v;
            if (gid >= OWL && gid < OB1 && idx >= 1280) v = 0.f;       // Wl pad
            else if (gid >= OBL && idx >= NC) v = 0.f;                  // bl pad
            else if (fl) v = bf2f(((const unsigned short*)srcp)[idx]);
            else v = ((const float*)srcp)[idx];
            cw[gid] = v;
        }
    } else if (bid == 135) {
        __shared__ float s2a[128];
        float pv = 0.f;
        if (t < 128) pv = fl ? bf2f(((const unsigned short*)p)[t]) : ((const float*)p)[t];
        if (t < 128) s2a[t] = pv * pv;
        __syncthreads();
        for (int off = 64; off; off >>= 1) {
            if (t < off) s2a[t] += s2a[t + off];
            __syncthreads();
        }
        if (t == 0) invnorm[0] = 1.0f / sqrtf(s2a[0]);
    } else {
        int i = (bid - 136) * 256 + t;
        new_id[i] = -1;
        if (i < NGRAPH) { ghist[i] = 0; gcur0[i] = 0; }
        if (i < NGRAPH * HD) pooled[i] = 0.f;
    }
}

// ---------------- edge binning by graph --------------------------------------
__global__ __launch_bounds__(256) void hist_kernel(const int* __restrict__ src,
                                                   int* __restrict__ ghist) {
    __shared__ int lh[NGRAPH];
    int tid = threadIdx.x;
    if (tid < NGRAPH) lh[tid] = 0;
    __syncthreads();
    int e0 = blockIdx.x * 4096;  // 256 blocks
    for (int k = 0; k < 16; k++) atomicAdd(&lh[src[e0 + k * 256 + tid] >> 10], 1);
    __syncthreads();
    if (tid < NGRAPH) atomicAdd(&ghist[tid], lh[tid]);
}
__global__ __launch_bounds__(256) void binpass_kernel(const int* __restrict__ src,
                                                      const int* __restrict__ dst,
                                                      const int* __restrict__ ghist,
                                                      int* __restrict__ gcur0,
                                                      unsigned int* __restrict__ elist) {
    __shared__ int gh[NGRAPH];
    __shared__ int gbS[NGRAPH];
    __shared__ int lh[NGRAPH];
    __shared__ int lbase[NGRAPH];
    int tid = threadIdx.x;
    if (tid < NGRAPH) { gh[tid] = ghist[tid]; lh[tid] = 0; }
    __syncthreads();
    if (tid == 0) {
        int s = 0;
        for (int i = 0; i < NGRAPH; i++) { gbS[i] = s; s += gh[i]; }
    }
    __syncthreads();
    int e0 = blockIdx.x * 4096;  // 256 blocks
    int gs[16]; unsigned int pk[16];
    for (int k = 0; k < 16; k++) {
        int e = e0 + k * 256 + tid;
        int s = src[e], d = dst[e];
        gs[k] = s >> 10;
        pk[k] = (unsigned)(s & 1023) | ((unsigned)(d & 1023) << 10);
        atomicAdd(&lh[gs[k]], 1);
    }
    __syncthreads();
    if (tid < NGRAPH) { lbase[tid] = gbS[tid] + atomicAdd(&gcur0[tid], lh[tid]); lh[tid] = 0; }
    __syncthreads();
    for (int k = 0; k < 16; k++) {
        int g = gs[k];
        int pos = lbase[g] + atomicAdd(&lh[g], 1);
        elist[pos] = pk[k];
    }
}

// ---------------- per-graph LDS counting-sort CSR + deg1 + dinv1 -------------
__global__ __launch_bounds__(1024) void csr_sort_kernel(
    const unsigned int* __restrict__ elist, const int* __restrict__ ghist,
    unsigned short* __restrict__ csr16, int* __restrict__ node_base,
    int* __restrict__ deg_out, float* __restrict__ dinv_out) {
    __shared__ unsigned short sc[EMAX];  // 40 KB
    __shared__ int cnt[NPERG];           // 4 KB
    __shared__ int cur[NPERG];           // 4 KB
    __shared__ int gh[NGRAPH];
    __shared__ int baseS, nS;
    int g = blockIdx.x, t = threadIdx.x;
    cnt[t] = 0;
    if (t < NGRAPH) gh[t] = ghist[t];
    __syncthreads();
    if (t == 0) {
        int s = 0;
        for (int i = 0; i < g; i++) s += gh[i];
        baseS = s; nS = gh[g];
    }
    __syncthreads();
    int base = baseS;
    int n = nS; if (n > EMAX) n = EMAX;
    for (int j = t; j < n; j += 1024) atomicAdd(&cnt[(elist[base + j] >> 10) & 1023], 1);
    __syncthreads();
    int v = cnt[t];
    for (int off = 1; off < 1024; off <<= 1) {
        int x = (t >= off) ? cnt[t - off] : 0;
        __syncthreads();
        cnt[t] += x;
        __syncthreads();
    }
    int excl = cnt[t] - v;
    cur[t] = excl;
    deg_out[g * NPERG + t] = v;
    dinv_out[g * NPERG + t] = rsqrtf((float)v + 1.0f);
    node_base[g * NPERG + t] = base + excl;
    __syncthreads();
    for (int j = t; j < n; j += 1024) {
        unsigned int pk = elist[base + j];
        int d = (pk >> 10) & 1023;
        int pos = atomicAdd(&cur[d], 1);
        sc[pos] = (unsigned short)(pk & 1023);
    }
    __syncthreads();
    for (int j = t; j < n; j += 1024) csr16[base + j] = sc[j];
}

// ---------------- GEMM1: C = A(flagged dtype) @ W, float4 LDS reads ----------
__global__ __launch_bounds__(256) void gemm_a_kernel(const void* __restrict__ Araw,
                                                     const float* __restrict__ W,
                                                     float* __restrict__ C,
                                                     const int* __restrict__ flag) {
    __shared__ float As[64 * HD];  // 32 KB
    int tid = threadIdx.x;
    int row0 = blockIdx.x * 64;
    if (flag[0]) {
        const unsigned short* Au = (const unsigned short*)Araw + (size_t)row0 * HD;
        for (int i = tid; i < 64 * HD; i += 256) As[i] = bf2f(Au[i]);
    } else {
        const float* Af = (const float*)Araw + (size_t)row0 * HD;
        for (int i = tid; i < 64 * HD / 4; i += 256)
            reinterpret_cast<float4*>(As)[i] = reinterpret_cast<const float4*>(Af)[i];
    }
    __syncthreads();
    int cg = tid & 31;
    int rg = tid >> 5;
    const float4* As4 = reinterpret_cast<const float4*>(As);
    const float4* W4 = reinterpret_cast<const float4*>(W);
    float4 acc[8];
#pragma unroll
    for (int r = 0; r < 8; r++) acc[r] = {0.f, 0.f, 0.f, 0.f};
    for (int k4 = 0; k4 < 32; k4++) {
        float4 wv0 = W4[(k4 * 4 + 0) * 32 + cg];
        float4 wv1 = W4[(k4 * 4 + 1) * 32 + cg];
        float4 wv2 = W4[(k4 * 4 + 2) * 32 + cg];
        float4 wv3 = W4[(k4 * 4 + 3) * 32 + cg];
#pragma unroll
        for (int r = 0; r < 8; r++) {
            float4 av = As4[(rg * 8 + r) * 32 + k4];
            acc[r].x += av.x * wv0.x; acc[r].y += av.x * wv0.y;
            acc[r].z += av.x * wv0.z; acc[r].w += av.x * wv0.w;
            acc[r].x += av.y * wv1.x; acc[r].y += av.y * wv1.y;
            acc[r].z += av.y * wv1.z; acc[r].w += av.y * wv1.w;
            acc[r].x += av.z * wv2.x; acc[r].y += av.z * wv2.y;
            acc[r].z += av.z * wv2.z; acc[r].w += av.z * wv2.w;
            acc[r].x += av.w * wv3.x; acc[r].y += av.w * wv3.y;
            acc[r].z += av.w * wv3.z; acc[r].w += av.w * wv3.w;
        }
    }
#pragma unroll
    for (int r = 0; r < 8; r++)
        reinterpret_cast<float4*>(C + (size_t)(row0 + rg * 8 + r) * HD)[cg] = acc[r];
}

// ---------------- conv1 aggregate (pull, 8-edge-parallel) + relu + score -----
// grp=lane>>3 handles edge slot j0+grp; cl=lane&7 covers float4 channels
// {cl+8i, i<4} (stride-8 interleave: each load instruction is 128B-contiguous
// per group). Group-reduce via shfl_xor(8,16,32); replicas bitwise identical;
// 64-lane score sum is exactly 8x -> *0.125f exact.
__global__ __launch_bounds__(256) void s1_pull(const unsigned short* __restrict__ csr16,
                                               const int* __restrict__ node_base,
                                               const int* __restrict__ deg,
                                               const float* __restrict__ dinv,
                                               const float* __restrict__ xw,
                                               const float* __restrict__ b1,
                                               const float* __restrict__ pvec,
                                               const float* __restrict__ invnorm,
                                               float* __restrict__ h,
                                               float* __restrict__ score) {
    int b = blockIdx.x;                 // 16384 blocks
    int xcd = b & 7, j = b >> 3;        // XCD-swizzle: graph pinned to one XCD
    int g = (j >> 8) * 8 + xcd;
    int n = g * NPERG + (j & 255) * 4 + (threadIdx.x >> 6);
    int lane = threadIdx.x & 63;
    int grp = lane >> 3, cl = lane & 7;
    int gb = g * NPERG;
    int base = node_base[n], cnt = deg[n];
    const float4* xf4 = (const float4*)xw;  // row stride 32 float4
    float4 a[4];
#pragma unroll
    for (int i = 0; i < 4; i++) a[i] = {0.f, 0.f, 0.f, 0.f};
    for (int j0 = 0; j0 < cnt; j0 += 8) {
        int myj = j0 + grp;
        int s = 0; float ds = 0.f;
        if (myj < cnt) {
            s = csr16[base + myj];        // 8-lane same-address broadcast
            ds = dinv[gb + s];
        }
        const float4* row = xf4 + ((size_t)(gb + s) * 32 + cl);
#pragma unroll
        for (int i = 0; i < 4; i++) {
            float4 v = row[8 * i];
            a[i].x += ds * v.x; a[i].y += ds * v.y;
            a[i].z += ds * v.z; a[i].w += ds * v.w;
        }
    }
#pragma unroll
    for (int off = 8; off <= 32; off <<= 1) {
#pragma unroll
        for (int i = 0; i < 4; i++) {
            a[i].x += __shfl_xor(a[i].x, off);
            a[i].y += __shfl_xor(a[i].y, off);
            a[i].z += __shfl_xor(a[i].z, off);
            a[i].w += __shfl_xor(a[i].w, off);
        }
    }
    float dn = dinv[n];
    float self = dn * dn;
    float4 hh[4];
    float sv = 0.f;
#pragma unroll
    for (int i = 0; i < 4; i++) {
        float4 xs = xf4[(size_t)n * 32 + cl + 8 * i];
        float4 bb = ((const float4*)b1)[cl + 8 * i];
        hh[i].x = fmaxf(dn * a[i].x + self * xs.x + bb.x, 0.f);
        hh[i].y = fmaxf(dn * a[i].y + self * xs.y + bb.y, 0.f);
        hh[i].z = fmaxf(dn * a[i].z + self * xs.z + bb.z, 0.f);
        hh[i].w = fmaxf(dn * a[i].w + self * xs.w + bb.w, 0.f);
        float4 pp = ((const float4*)pvec)[cl + 8 * i];
        sv += hh[i].x * pp.x + hh[i].y * pp.y + hh[i].z * pp.z + hh[i].w * pp.w;
    }
    if (grp == 0) {
#pragma unroll
        for (int i = 0; i < 4; i++)
            ((float4*)h)[(size_t)n * 32 + cl + 8 * i] = hh[i];
    }
    for (int off = 32; off; off >>= 1) sv += __shfl_down(sv, off);
    if (lane == 0) score[n] = tanhf(sv * 0.125f * invnorm[0]);
}

// ---------------- top-512 bitonic + fused deg2/dinv2 -------------------------
__global__ __launch_bounds__(1024) void topk_kernel(const float* __restrict__ score,
                                                    const unsigned int* __restrict__ elist,
                                                    const int* __restrict__ ghist,
                                                    float* __restrict__ vals,
                                                    int* __restrict__ perm,
                                                    int* __restrict__ new_id,
                                                    float* __restrict__ dinv2) {
    __shared__ float sv[1024];
    __shared__ int si[1024];
    __shared__ short nid[1024];
    __shared__ int d2[KEEP];
    __shared__ int gh[NGRAPH];
    __shared__ int baseS, nS;
    int g = blockIdx.x, t = threadIdx.x;
    sv[t] = score[g * NPERG + t];
    si[t] = t;
    nid[t] = -1;
    if (t < KEEP) d2[t] = 0;
    if (t < NGRAPH) gh[t] = ghist[t];
    __syncthreads();
    if (t == 0) {
        int s = 0;
        for (int i = 0; i < g; i++) s += gh[i];
        baseS = s; nS = gh[g];
    }
    for (int k = 2; k <= 1024; k <<= 1) {
        for (int j = k >> 1; j > 0; j >>= 1) {
            int l = t ^ j;
            if (l > t) {
                bool desc = ((t & k) == 0);
                float va = sv[t], vb = sv[l];
                int ia = si[t], ib = si[l];
                bool gab = (va > vb) || (va == vb && ia < ib);  // lax.top_k tie rule
                if (gab != desc) { sv[t] = vb; si[t] = ib; sv[l] = va; si[l] = ia; }
            }
            __syncthreads();
        }
    }
    if (t < KEEP) {
        int node = g * NPERG + si[t];
        int slot = g * KEEP + t;
        vals[slot] = sv[t];
        perm[slot] = node;
        new_id[node] = slot;
        nid[si[t]] = (short)t;
    }
    __syncthreads();
    int base = baseS, n = nS;
    for (int j = t; j < n; j += 1024) {
        unsigned int pk = elist[base + j];
        int s = pk & 1023, d = (pk >> 10) & 1023;
        short ns = nid[s], nd = nid[d];
        if (ns >= 0 && nd >= 0) atomicAdd(&d2[nd], 1);
    }
    __syncthreads();
    if (t < KEEP) dinv2[g * KEEP + t] = rsqrtf((float)d2[t] + 1.0f);
}

// ---------------- GEMM2 with fused gather+gate A-staging ---------------------
__global__ __launch_bounds__(256) void gemm_gather(const float* __restrict__ h,
                                                   const int* __restrict__ perm,
                                                   const float* __restrict__ vals,
                                                   const float* __restrict__ W,
                                                   float* __restrict__ C) {
    __shared__ float As[64 * HD];
    int tid = threadIdx.x;
    int row0 = blockIdx.x * 64;
    for (int i4 = tid; i4 < 64 * 32; i4 += 256) {
        int r = i4 >> 5, c4 = i4 & 31;
        int m = row0 + r;
        float sc = vals[m];
        float4 v = reinterpret_cast<const float4*>(h + (size_t)perm[m] * HD)[c4];
        v.x *= sc; v.y *= sc; v.z *= sc; v.w *= sc;
        reinterpret_cast<float4*>(As)[i4] = v;
    }
    __syncthreads();
    int cg = tid & 31;
    int rg = tid >> 5;
    const float4* As4 = reinterpret_cast<const float4*>(As);
    const float4* W4 = reinterpret_cast<const float4*>(W);
    float4 acc[8];
#pragma unroll
    for (int r = 0; r < 8; r++) acc[r] = {0.f, 0.f, 0.f, 0.f};
    for (int k4 = 0; k4 < 32; k4++) {
        float4 wv0 = W4[(k4 * 4 + 0) * 32 + cg];
        float4 wv1 = W4[(k4 * 4 + 1) * 32 + cg];
        float4 wv2 = W4[(k4 * 4 + 2) * 32 + cg];
        float4 wv3 = W4[(k4 * 4 + 3) * 32 + cg];
#pragma unroll
        for (int r = 0; r < 8; r++) {
            float4 av = As4[(rg * 8 + r) * 32 + k4];
            acc[r].x += av.x * wv0.x; acc[r].y += av.x * wv0.y;
            acc[r].z += av.x * wv0.z; acc[r].w += av.x * wv0.w;
            acc[r].x += av.y * wv1.x; acc[r].y += av.y * wv1.y;
            acc[r].z += av.y * wv1.z; acc[r].w += av.y * wv1.w;
            acc[r].x += av.z * wv2.x; acc[r].y += av.z * wv2.y;
            acc[r].z += av.z * wv2.z; acc[r].w += av.z * wv2.w;
            acc[r].x += av.w * wv3.x; acc[r].y += av.w * wv3.y;
            acc[r].z += av.w * wv3.z; acc[r].w += av.w * wv3.w;
        }
    }
#pragma unroll
    for (int r = 0; r < 8; r++)
        reinterpret_cast<float4*>(C + (size_t)(row0 + rg * 8 + r) * HD)[cg] = acc[r];
}

// ---------------- conv2 aggregate (pull, 8-edge-parallel) + fused mean-pool --
__global__ __launch_bounds__(256) void s2_pull(const unsigned short* __restrict__ csr16,
                                               const int* __restrict__ node_base,
                                               const int* __restrict__ deg,
                                               const int* __restrict__ perm,
                                               const int* __restrict__ new_id,
                                               const float* __restrict__ dinv2,
                                               const float* __restrict__ xw2,
                                               const float* __restrict__ b2,
                                               float* __restrict__ pooled) {
    __shared__ float pr[HD];
    int tid = threadIdx.x;
    if (tid < HD) pr[tid] = 0.f;
    __syncthreads();
    int b = blockIdx.x;              // 8192 blocks
    int xcd = b & 7, j = b >> 3;
    int g = (j >> 7) * 8 + xcd;
    int m = g * KEEP + (j & 127) * 4 + (tid >> 6);
    int lane = tid & 63;
    int grp = lane >> 3, cl = lane & 7;
    int node = perm[m];
    int gb = node & ~(NPERG - 1);
    int base = node_base[node], cnt = deg[node];
    const float4* xf4 = (const float4*)xw2;
    float4 a[4];
#pragma unroll
    for (int i = 0; i < 4; i++) a[i] = {0.f, 0.f, 0.f, 0.f};
    for (int j0 = 0; j0 < cnt; j0 += 8) {
        int myj = j0 + grp;
        int ns = -1;
        if (myj < cnt) ns = new_id[gb + csr16[base + myj]];
        float ds = (ns >= 0) ? dinv2[ns] : 0.f;
        int nk = (ns >= 0) ? ns : 0;
        const float4* row = xf4 + ((size_t)nk * 32 + cl);
#pragma unroll
        for (int i = 0; i < 4; i++) {
            float4 v = row[8 * i];
            a[i].x += ds * v.x; a[i].y += ds * v.y;
            a[i].z += ds * v.z; a[i].w += ds * v.w;
        }
    }
#pragma unroll
    for (int off = 8; off <= 32; off <<= 1) {
#pragma unroll
        for (int i = 0; i < 4; i++) {
            a[i].x += __shfl_xor(a[i].x, off);
            a[i].y += __shfl_xor(a[i].y, off);
            a[i].z += __shfl_xor(a[i].z, off);
            a[i].w += __shfl_xor(a[i].w, off);
        }
    }
    if (grp == 0) {
        float dn = dinv2[m];
        float self = dn * dn;
#pragma unroll
        for (int i = 0; i < 4; i++) {
            float4 xs = xf4[(size_t)m * 32 + cl + 8 * i];
            float4 bb = ((const float4*)b2)[cl + 8 * i];
            float4 o;
            o.x = fmaxf(dn * a[i].x + self * xs.x + bb.x, 0.f);
            o.y = fmaxf(dn * a[i].y + self * xs.y + bb.y, 0.f);
            o.z = fmaxf(dn * a[i].z + self * xs.z + bb.z, 0.f);
            o.w = fmaxf(dn * a[i].w + self * xs.w + bb.w, 0.f);
            int c = (cl + 8 * i) * 4;
            atomicAdd(&pr[c + 0], o.x);
            atomicAdd(&pr[c + 1], o.y);
            atomicAdd(&pr[c + 2], o.z);
            atomicAdd(&pr[c + 3], o.w);
        }
    }
    __syncthreads();
    if (tid < HD) atomicAdd(&pooled[g * HD + tid], pr[tid]);
}

// ---------------- final linear: out = (pooled/512) @ Wl + bl -----------------
__global__ __launch_bounds__(128) void outk_kernel(const float* __restrict__ pooled,
                                                   const float* __restrict__ Wl,
                                                   const float* __restrict__ bl,
                                                   void* __restrict__ outv,
                                                   const int* __restrict__ flag) {
    int g = blockIdx.x, t = threadIdx.x;  // 128
    __shared__ float sp[HD];
    sp[t] = pooled[g * HD + t] * (1.0f / KEEP);
    __syncthreads();
    if (t < NC) {
        float acc = bl[t];
        for (int hh = 0; hh < HD; hh++) acc += sp[hh] * Wl[hh * NC + t];
        if (flag[0]) ((unsigned short*)outv)[g * NC + t] = f2bf(acc);
        else         ((float*)outv)[g * NC + t] = acc;
    }
}

extern "C" void kernel_launch(void* const* d_in, const int* in_sizes, int n_in,
                              void* d_out, int out_size, void* d_ws, size_t ws_size,
                              hipStream_t stream) {
    const int* ei   = (const int*)d_in[1];
    const int* srcv = ei;
    const int* dstv = ei + NEDGES;

    char* w = (char*)d_ws;
    const size_t MB = 1u << 20;
    const size_t KB = 1024;
    float* dinv1     = (float*)(w + 0);                 // 256 KB
    float* score     = (float*)(w + 256 * KB);          // 256 KB
    float* vals      = (float*)(w + 512 * KB);          // 128 KB
    int*   perm      = (int*)(w + 640 * KB);            // 128 KB
    int*   new_id    = (int*)(w + 768 * KB);            // 256 KB
    int*   deg1      = (int*)(w + 1024 * KB);           // 256 KB
    int*   node_base = (int*)(w + 1280 * KB);           // 256 KB
    float* dinv2     = (float*)(w + 1536 * KB);         // 128 KB
    float* invnorm   = (float*)(w + 1664 * KB);
    int*   flag      = (int*)(w + 1664 * KB + 64);
    int*   ghist     = (int*)(w + 1664 * KB + 1024);
    int*   gcur0     = (int*)(w + 1664 * KB + 2048);
    float* cw        = (float*)(w + 1700 * KB);         // 135 KB canonical weights
    float* pooled    = (float*)(w + 1840 * KB);         // 32 KB
    float* xw1  = (float*)(w + 2 * MB);                 // [2,34) MB
    float* agg  = (float*)(w + 34 * MB);                // [34,66) MB  (h)
    float* xw2  = (float*)(w + 2 * MB);                 // xw1 dead after s1
    unsigned int* elist    = (unsigned int*)(w + 66 * MB);   // [66,70) MB
    unsigned short* csr16  = (unsigned short*)(w + 70 * MB); // [70,72) MB

    float* W1f = cw + OW1; float* W2f = cw + OW2; float* Wlf = cw + OWL;
    float* b1f = cw + OB1; float* b2f = cw + OB2; float* pf  = cw + OP;
    float* blf = cw + OBL;

    prep_kernel<<<392, 256, 0, stream>>>(d_in[3], d_in[4], d_in[5], d_in[6], d_in[7],
                                         d_in[8], d_in[9], flag, cw, invnorm, new_id,
                                         ghist, gcur0, pooled);
    hist_kernel<<<256, 256, 0, stream>>>(srcv, ghist);
    binpass_kernel<<<256, 256, 0, stream>>>(srcv, dstv, ghist, gcur0, elist);
    gemm_a_kernel<<<NNODES / 64, 256, 0, stream>>>(d_in[0], W1f, xw1, flag);
    csr_sort_kernel<<<NGRAPH, 1024, 0, stream>>>(elist, ghist, csr16, node_base,
                                                 deg1, dinv1);
    s1_pull<<<NNODES / 4, 256, 0, stream>>>(csr16, node_base, deg1, dinv1, xw1, b1f, pf,
                                            invnorm, agg, score);
    topk_kernel<<<NGRAPH, 1024, 0, stream>>>(score, elist, ghist, vals, perm,
                                             new_id, dinv2);
    gemm_gather<<<M2 / 64, 256, 0, stream>>>(agg, perm, vals, W2f, xw2);
    s2_pull<<<M2 / 4, 256, 0, stream>>>(csr16, node_base, deg1, perm, new_id, dinv2,
                                        xw2, b2f, pooled);
    outk_kernel<<<NGRAPH, 128, 0, stream>>>(pooled, Wlf, blf, d_out, flag);

    (void)in_sizes; (void)n_in; (void)out_size; (void)ws_size;
}

// Round 12
// 298.374 us; speedup vs baseline: 5.2139x; 1.0165x over previous
//
#include <hip/hip_runtime.h>

#define NNODES 65536
#define NEDGES 1048576
#define NGRAPH 64
#define NPERG  1024
#define KEEP   512
#define M2     (NGRAPH * KEEP)   // 32768
#define HD     128
#define NC     10
#define EMAX   20480             // per-graph edge capacity (avg 16384, sigma~127)

// canonical weight block offsets (floats)
#define OW1 0
#define OW2 16384
#define OWL 32768
#define OB1 34048
#define OB2 34176
#define OP  34304
#define OBL 34432
#define NCVT 34448

__device__ __forceinline__ float bf2f(unsigned short u) {
    return __uint_as_float(((unsigned int)u) << 16);
}
__device__ __forceinline__ unsigned short f2bf(float f) {
    unsigned int u = __float_as_uint(f);
    unsigned int r = (u + 0x7FFFu + ((u >> 16) & 1u)) >> 16;
    return (unsigned short)r;
}

// ---------------- prep: detect dtype + cvt weights + pnorm + init ------------
__global__ __launch_bounds__(256) void prep_kernel(
    const void* __restrict__ W1, const void* __restrict__ b1, const void* __restrict__ p,
    const void* __restrict__ W2, const void* __restrict__ b2, const void* __restrict__ Wl,
    const void* __restrict__ bl, int* __restrict__ flag, float* __restrict__ cw,
    float* __restrict__ invnorm, int* __restrict__ new_id, int* __restrict__ ghist,
    int* __restrict__ gcur0, float* __restrict__ pooled) {
    int bid = blockIdx.x, t = threadIdx.x;
    const unsigned short* w1u = (const unsigned short*)W1;
    int local = 0;
    for (int i = t; i < 512; i += 256) {
        unsigned short u = w1u[2 * i];
        int e = (u >> 7) & 0xFF;
        local += (e >= 100 && e <= 140) ? 1 : 0;
    }
    __shared__ int red[256];
    red[t] = local;
    __syncthreads();
    for (int off = 128; off; off >>= 1) {
        if (t < off) red[t] += red[t + off];
        __syncthreads();
    }
    int fl = (red[0] >= 384) ? 1 : 0;
    if (bid == 0 && t == 0) flag[0] = fl;

    if (bid < 135) {
        int gid = bid * 256 + t;
        if (gid < NCVT) {
            const void* srcp; int idx;
            if (gid < OB1) {
                if (gid < OW2)      { srcp = W1; idx = gid - OW1; }
                else if (gid < OWL) { srcp = W2; idx = gid - OW2; }
                else                { srcp = Wl; idx = gid - OWL; }
            } else {
                if (gid < OB2)      { srcp = b1; idx = gid - OB1; }
                else if (gid < OP)  { srcp = b2; idx = gid - OB2; }
                else if (gid < OBL) { srcp = p;  idx = gid - OP; }
                else                { srcp = bl; idx = gid - OBL; }
            }
            float v;
            if (gid >= OWL && gid < OB1 && idx >= 1280) v = 0.f;       // Wl pad
            else if (gid >= OBL && idx >= NC) v = 0.f;                  // bl pad
            else if (fl) v = bf2f(((const unsigned short*)srcp)[idx]);
            else v = ((const float*)srcp)[idx];
            cw[gid] = v;
        }
    } else if (bid == 135) {
        __shared__ float s2a[128];
        float pv = 0.f;
        if (t < 128) pv = fl ? bf2f(((const unsigned short*)p)[t]) : ((const float*)p)[t];
        if (t < 128) s2a[t] = pv * pv;
        __syncthreads();
        for (int off = 64; off; off >>= 1) {
            if (t < off) s2a[t] += s2a[t + off];
            __syncthreads();
        }
        if (t == 0) invnorm[0] = 1.0f / sqrtf(s2a[0]);
    } else {
        int i = (bid - 136) * 256 + t;
        new_id[i] = -1;
        if (i < NGRAPH) { ghist[i] = 0; gcur0[i] = 0; }
        if (i < NGRAPH * HD) pooled[i] = 0.f;
    }
}

// ---------------- edge binning by graph --------------------------------------
__global__ __launch_bounds__(256) void hist_kernel(const int* __restrict__ src,
                                                   int* __restrict__ ghist) {
    __shared__ int lh[NGRAPH];
    int tid = threadIdx.x;
    if (tid < NGRAPH) lh[tid] = 0;
    __syncthreads();
    int e0 = blockIdx.x * 4096;  // 256 blocks
    for (int k = 0; k < 16; k++) atomicAdd(&lh[src[e0 + k * 256 + tid] >> 10], 1);
    __syncthreads();
    if (tid < NGRAPH) atomicAdd(&ghist[tid], lh[tid]);
}
__global__ __launch_bounds__(256) void binpass_kernel(const int* __restrict__ src,
                                                      const int* __restrict__ dst,
                                                      const int* __restrict__ ghist,
                                                      int* __restrict__ gcur0,
                                                      unsigned int* __restrict__ elist) {
    __shared__ int gh[NGRAPH];
    __shared__ int gbS[NGRAPH];
    __shared__ int lh[NGRAPH];
    __shared__ int lbase[NGRAPH];
    int tid = threadIdx.x;
    if (tid < NGRAPH) { gh[tid] = ghist[tid]; lh[tid] = 0; }
    __syncthreads();
    if (tid == 0) {
        int s = 0;
        for (int i = 0; i < NGRAPH; i++) { gbS[i] = s; s += gh[i]; }
    }
    __syncthreads();
    int e0 = blockIdx.x * 4096;  // 256 blocks
    int gs[16]; unsigned int pk[16];
    for (int k = 0; k < 16; k++) {
        int e = e0 + k * 256 + tid;
        int s = src[e], d = dst[e];
        gs[k] = s >> 10;
        pk[k] = (unsigned)(s & 1023) | ((unsigned)(d & 1023) << 10);
        atomicAdd(&lh[gs[k]], 1);
    }
    __syncthreads();
    if (tid < NGRAPH) { lbase[tid] = gbS[tid] + atomicAdd(&gcur0[tid], lh[tid]); lh[tid] = 0; }
    __syncthreads();
    for (int k = 0; k < 16; k++) {
        int g = gs[k];
        int pos = lbase[g] + atomicAdd(&lh[g], 1);
        elist[pos] = pk[k];
    }
}

// ---------------- per-graph LDS counting-sort CSR + deg1 + dinv1 -------------
__global__ __launch_bounds__(1024) void csr_sort_kernel(
    const unsigned int* __restrict__ elist, const int* __restrict__ ghist,
    unsigned short* __restrict__ csr16, int* __restrict__ node_base,
    int* __restrict__ deg_out, float* __restrict__ dinv_out) {
    __shared__ unsigned short sc[EMAX];  // 40 KB
    __shared__ int cnt[NPERG];           // 4 KB
    __shared__ int cur[NPERG];           // 4 KB
    __shared__ int gh[NGRAPH];
    __shared__ int baseS, nS;
    int g = blockIdx.x, t = threadIdx.x;
    cnt[t] = 0;
    if (t < NGRAPH) gh[t] = ghist[t];
    __syncthreads();
    if (t == 0) {
        int s = 0;
        for (int i = 0; i < g; i++) s += gh[i];
        baseS = s; nS = gh[g];
    }
    __syncthreads();
    int base = baseS;
    int n = nS; if (n > EMAX) n = EMAX;
    for (int j = t; j < n; j += 1024) atomicAdd(&cnt[(elist[base + j] >> 10) & 1023], 1);
    __syncthreads();
    int v = cnt[t];
    for (int off = 1; off < 1024; off <<= 1) {
        int x = (t >= off) ? cnt[t - off] : 0;
        __syncthreads();
        cnt[t] += x;
        __syncthreads();
    }
    int excl = cnt[t] - v;
    cur[t] = excl;
    deg_out[g * NPERG + t] = v;
    dinv_out[g * NPERG + t] = rsqrtf((float)v + 1.0f);
    node_base[g * NPERG + t] = base + excl;
    __syncthreads();
    for (int j = t; j < n; j += 1024) {
        unsigned int pk = elist[base + j];
        int d = (pk >> 10) & 1023;
        int pos = atomicAdd(&cur[d], 1);
        sc[pos] = (unsigned short)(pk & 1023);
    }
    __syncthreads();
    for (int j = t; j < n; j += 1024) csr16[base + j] = sc[j];
}

// ---------------- GEMM1: C = A(flagged dtype) @ W, float4 LDS reads ----------
__global__ __launch_bounds__(256) void gemm_a_kernel(const void* __restrict__ Araw,
                                                     const float* __restrict__ W,
                                                     float* __restrict__ C,
                                                     const int* __restrict__ flag) {
    __shared__ float As[64 * HD];  // 32 KB
    int tid = threadIdx.x;
    int row0 = blockIdx.x * 64;
    if (flag[0]) {
        const unsigned short* Au = (const unsigned short*)Araw + (size_t)row0 * HD;
        for (int i = tid; i < 64 * HD; i += 256) As[i] = bf2f(Au[i]);
    } else {
        const float* Af = (const float*)Araw + (size_t)row0 * HD;
        for (int i = tid; i < 64 * HD / 4; i += 256)
            reinterpret_cast<float4*>(As)[i] = reinterpret_cast<const float4*>(Af)[i];
    }
    __syncthreads();
    int cg = tid & 31;
    int rg = tid >> 5;
    const float4* As4 = reinterpret_cast<const float4*>(As);
    const float4* W4 = reinterpret_cast<const float4*>(W);
    float4 acc[8];
#pragma unroll
    for (int r = 0; r < 8; r++) acc[r] = {0.f, 0.f, 0.f, 0.f};
    for (int k4 = 0; k4 < 32; k4++) {
        float4 wv0 = W4[(k4 * 4 + 0) * 32 + cg];
        float4 wv1 = W4[(k4 * 4 + 1) * 32 + cg];
        float4 wv2 = W4[(k4 * 4 + 2) * 32 + cg];
        float4 wv3 = W4[(k4 * 4 + 3) * 32 + cg];
#pragma unroll
        for (int r = 0; r < 8; r++) {
            float4 av = As4[(rg * 8 + r) * 32 + k4];
            acc[r].x += av.x * wv0.x; acc[r].y += av.x * wv0.y;
            acc[r].z += av.x * wv0.z; acc[r].w += av.x * wv0.w;
            acc[r].x += av.y * wv1.x; acc[r].y += av.y * wv1.y;
            acc[r].z += av.y * wv1.z; acc[r].w += av.y * wv1.w;
            acc[r].x += av.z * wv2.x; acc[r].y += av.z * wv2.y;
            acc[r].z += av.z * wv2.z; acc[r].w += av.z * wv2.w;
            acc[r].x += av.w * wv3.x; acc[r].y += av.w * wv3.y;
            acc[r].z += av.w * wv3.z; acc[r].w += av.w * wv3.w;
        }
    }
#pragma unroll
    for (int r = 0; r < 8; r++)
        reinterpret_cast<float4*>(C + (size_t)(row0 + rg * 8 + r) * HD)[cg] = acc[r];
}

// ---------------- conv1 aggregate (pull, prefetched edges) + relu + score ----
// Wave per node. Edge ids + dinv loaded up-front (lane l -> edge l, 2 memory
// ops total for deg<=64). Row loop broadcasts (s_k,d_k) via __shfl with
// uniform k (v_readlane -> scalar) and issues independent full-wave float2
// row loads, unrolled x4 so 4 loads are in flight per drain.
__global__ __launch_bounds__(256) void s1_pull(const unsigned short* __restrict__ csr16,
                                               const int* __restrict__ node_base,
                                               const int* __restrict__ deg,
                                               const float* __restrict__ dinv,
                                               const float* __restrict__ xw,
                                               const float* __restrict__ b1,
                                               const float* __restrict__ pvec,
                                               const float* __restrict__ invnorm,
                                               float* __restrict__ h,
                                               float* __restrict__ score) {
    int b = blockIdx.x;                 // 16384 blocks
    int xcd = b & 7, j = b >> 3;        // XCD-swizzle: graph pinned to one XCD
    int g = (j >> 8) * 8 + xcd;
    int n = g * NPERG + (j & 255) * 4 + (threadIdx.x >> 6);
    int lane = threadIdx.x & 63;
    int gb = g * NPERG;
    int base = node_base[n], cnt = deg[n];
    int e = 0; float ds = 0.f;
    if (lane < cnt) {
        e = csr16[base + lane];
        ds = dinv[gb + e];
    }
    const float2* xf2 = (const float2*)xw;  // row stride 64 float2
    float a0 = 0.f, a1 = 0.f;
    int klim = cnt < 64 ? cnt : 64;
    int k = 0;
    for (; k + 3 < klim; k += 4) {
        int s0 = __shfl(e, k), s1 = __shfl(e, k + 1);
        int s2 = __shfl(e, k + 2), s3 = __shfl(e, k + 3);
        float d0 = __shfl(ds, k), d1 = __shfl(ds, k + 1);
        float d2 = __shfl(ds, k + 2), d3 = __shfl(ds, k + 3);
        float2 v0 = xf2[(size_t)(gb + s0) * 64 + lane];
        float2 v1 = xf2[(size_t)(gb + s1) * 64 + lane];
        float2 v2 = xf2[(size_t)(gb + s2) * 64 + lane];
        float2 v3 = xf2[(size_t)(gb + s3) * 64 + lane];
        a0 += d0 * v0.x; a1 += d0 * v0.y;
        a0 += d1 * v1.x; a1 += d1 * v1.y;
        a0 += d2 * v2.x; a1 += d2 * v2.y;
        a0 += d3 * v3.x; a1 += d3 * v3.y;
    }
    for (; k < klim; k++) {
        int sk = __shfl(e, k);
        float dk = __shfl(ds, k);
        float2 v = xf2[(size_t)(gb + sk) * 64 + lane];
        a0 += dk * v.x; a1 += dk * v.y;
    }
    for (; k < cnt; k++) {  // deg>64 cold path (P ~ 0, correctness only)
        int sk = csr16[base + k];
        float dk = dinv[gb + sk];
        float2 v = xf2[(size_t)(gb + sk) * 64 + lane];
        a0 += dk * v.x; a1 += dk * v.y;
    }
    float dn = dinv[n];
    float self = dn * dn;
    float2 xs = xf2[(size_t)n * 64 + lane];
    float2 bb = ((const float2*)b1)[lane];
    float h0 = fmaxf(dn * a0 + self * xs.x + bb.x, 0.f);
    float h1 = fmaxf(dn * a1 + self * xs.y + bb.y, 0.f);
    float2 ho = {h0, h1};
    ((float2*)h)[(size_t)n * 64 + lane] = ho;
    float2 pp = ((const float2*)pvec)[lane];
    float sv = h0 * pp.x + h1 * pp.y;
    for (int off = 32; off; off >>= 1) sv += __shfl_down(sv, off);
    if (lane == 0) score[n] = tanhf(sv * invnorm[0]);
}

// ---------------- top-512 bitonic + fused deg2/dinv2 -------------------------
__global__ __launch_bounds__(1024) void topk_kernel(const float* __restrict__ score,
                                                    const unsigned int* __restrict__ elist,
                                                    const int* __restrict__ ghist,
                                                    float* __restrict__ vals,
                                                    int* __restrict__ perm,
                                                    int* __restrict__ new_id,
                                                    float* __restrict__ dinv2) {
    __shared__ float sv[1024];
    __shared__ int si[1024];
    __shared__ short nid[1024];
    __shared__ int d2[KEEP];
    __shared__ int gh[NGRAPH];
    __shared__ int baseS, nS;
    int g = blockIdx.x, t = threadIdx.x;
    sv[t] = score[g * NPERG + t];
    si[t] = t;
    nid[t] = -1;
    if (t < KEEP) d2[t] = 0;
    if (t < NGRAPH) gh[t] = ghist[t];
    __syncthreads();
    if (t == 0) {
        int s = 0;
        for (int i = 0; i < g; i++) s += gh[i];
        baseS = s; nS = gh[g];
    }
    for (int k = 2; k <= 1024; k <<= 1) {
        for (int j = k >> 1; j > 0; j >>= 1) {
            int l = t ^ j;
            if (l > t) {
                bool desc = ((t & k) == 0);
                float va = sv[t], vb = sv[l];
                int ia = si[t], ib = si[l];
                bool gab = (va > vb) || (va == vb && ia < ib);  // lax.top_k tie rule
                if (gab != desc) { sv[t] = vb; si[t] = ib; sv[l] = va; si[l] = ia; }
            }
            __syncthreads();
        }
    }
    if (t < KEEP) {
        int node = g * NPERG + si[t];
        int slot = g * KEEP + t;
        vals[slot] = sv[t];
        perm[slot] = node;
        new_id[node] = slot;
        nid[si[t]] = (short)t;
    }
    __syncthreads();
    int base = baseS, n = nS;
    for (int j = t; j < n; j += 1024) {
        unsigned int pk = elist[base + j];
        int s = pk & 1023, d = (pk >> 10) & 1023;
        short ns = nid[s], nd = nid[d];
        if (ns >= 0 && nd >= 0) atomicAdd(&d2[nd], 1);
    }
    __syncthreads();
    if (t < KEEP) dinv2[g * KEEP + t] = rsqrtf((float)d2[t] + 1.0f);
}

// ---------------- GEMM2 with fused gather+gate A-staging ---------------------
__global__ __launch_bounds__(256) void gemm_gather(const float* __restrict__ h,
                                                   const int* __restrict__ perm,
                                                   const float* __restrict__ vals,
                                                   const float* __restrict__ W,
                                                   float* __restrict__ C) {
    __shared__ float As[64 * HD];
    int tid = threadIdx.x;
    int row0 = blockIdx.x * 64;
    for (int i4 = tid; i4 < 64 * 32; i4 += 256) {
        int r = i4 >> 5, c4 = i4 & 31;
        int m = row0 + r;
        float sc = vals[m];
        float4 v = reinterpret_cast<const float4*>(h + (size_t)perm[m] * HD)[c4];
        v.x *= sc; v.y *= sc; v.z *= sc; v.w *= sc;
        reinterpret_cast<float4*>(As)[i4] = v;
    }
    __syncthreads();
    int cg = tid & 31;
    int rg = tid >> 5;
    const float4* As4 = reinterpret_cast<const float4*>(As);
    const float4* W4 = reinterpret_cast<const float4*>(W);
    float4 acc[8];
#pragma unroll
    for (int r = 0; r < 8; r++) acc[r] = {0.f, 0.f, 0.f, 0.f};
    for (int k4 = 0; k4 < 32; k4++) {
        float4 wv0 = W4[(k4 * 4 + 0) * 32 + cg];
        float4 wv1 = W4[(k4 * 4 + 1) * 32 + cg];
        float4 wv2 = W4[(k4 * 4 + 2) * 32 + cg];
        float4 wv3 = W4[(k4 * 4 + 3) * 32 + cg];
#pragma unroll
        for (int r = 0; r < 8; r++) {
            float4 av = As4[(rg * 8 + r) * 32 + k4];
            acc[r].x += av.x * wv0.x; acc[r].y += av.x * wv0.y;
            acc[r].z += av.x * wv0.z; acc[r].w += av.x * wv0.w;
            acc[r].x += av.y * wv1.x; acc[r].y += av.y * wv1.y;
            acc[r].z += av.y * wv1.z; acc[r].w += av.y * wv1.w;
            acc[r].x += av.z * wv2.x; acc[r].y += av.z * wv2.y;
            acc[r].z += av.z * wv2.z; acc[r].w += av.z * wv2.w;
            acc[r].x += av.w * wv3.x; acc[r].y += av.w * wv3.y;
            acc[r].z += av.w * wv3.z; acc[r].w += av.w * wv3.w;
        }
    }
#pragma unroll
    for (int r = 0; r < 8; r++)
        reinterpret_cast<float4*>(C + (size_t)(row0 + rg * 8 + r) * HD)[cg] = acc[r];
}

// ---------------- conv2 aggregate (pull, prefetched) + mask + fused pool -----
__global__ __launch_bounds__(256) void s2_pull(const unsigned short* __restrict__ csr16,
                                               const int* __restrict__ node_base,
                                               const int* __restrict__ deg,
                                               const int* __restrict__ perm,
                                               const int* __restrict__ new_id,
                                               const float* __restrict__ dinv2,
                                               const float* __restrict__ xw2,
                                               const float* __restrict__ b2,
                                               float* __restrict__ pooled) {
    __shared__ float pr[HD];
    int tid = threadIdx.x;
    if (tid < HD) pr[tid] = 0.f;
    __syncthreads();
    int b = blockIdx.x;              // 8192 blocks
    int xcd = b & 7, j = b >> 3;
    int g = (j >> 7) * 8 + xcd;
    int m = g * KEEP + (j & 127) * 4 + (tid >> 6);
    int lane = tid & 63;
    int node = perm[m];
    int gb = node & ~(NPERG - 1);
    int base = node_base[node], cnt = deg[node];
    int nk = 0; float ds = 0.f;
    if (lane < cnt) {
        int ns = new_id[gb + csr16[base + lane]];
        if (ns >= 0) { nk = ns; ds = dinv2[ns]; }
    }
    const float2* xf2 = (const float2*)xw2;
    float a0 = 0.f, a1 = 0.f;
    int klim = cnt < 64 ? cnt : 64;
    for (int k = 0; k < klim; k++) {
        float dk = __shfl(ds, k);       // uniform k -> readlane (scalar)
        if (dk != 0.f) {                 // wave-uniform skip (~75% masked)
            int sk = __shfl(nk, k);
            float2 v = xf2[(size_t)sk * 64 + lane];
            a0 += dk * v.x; a1 += dk * v.y;
        }
    }
    for (int k = 64; k < cnt; k++) {    // deg>64 cold path
        int ns = new_id[gb + csr16[base + k]];
        if (ns >= 0) {
            float dk = dinv2[ns];
            float2 v = xf2[(size_t)ns * 64 + lane];
            a0 += dk * v.x; a1 += dk * v.y;
        }
    }
    float dn = dinv2[m];
    float self = dn * dn;
    float2 xs = xf2[(size_t)m * 64 + lane];
    float2 bb = ((const float2*)b2)[lane];
    float o0 = fmaxf(dn * a0 + self * xs.x + bb.x, 0.f);
    float o1 = fmaxf(dn * a1 + self * xs.y + bb.y, 0.f);
    atomicAdd(&pr[lane * 2], o0);
    atomicAdd(&pr[lane * 2 + 1], o1);
    __syncthreads();
    if (tid < HD) atomicAdd(&pooled[g * HD + tid], pr[tid]);
}

// ---------------- final linear: out = (pooled/512) @ Wl + bl -----------------
__global__ __launch_bounds__(128) void outk_kernel(const float* __restrict__ pooled,
                                                   const float* __restrict__ Wl,
                                                   const float* __restrict__ bl,
                                                   void* __restrict__ outv,
                                                   const int* __restrict__ flag) {
    int g = blockIdx.x, t = threadIdx.x;  // 128
    __shared__ float sp[HD];
    sp[t] = pooled[g * HD + t] * (1.0f / KEEP);
    __syncthreads();
    if (t < NC) {
        float acc = bl[t];
        for (int hh = 0; hh < HD; hh++) acc += sp[hh] * Wl[hh * NC + t];
        if (flag[0]) ((unsigned short*)outv)[g * NC + t] = f2bf(acc);
        else         ((float*)outv)[g * NC + t] = acc;
    }
}

extern "C" void kernel_launch(void* const* d_in, const int* in_sizes, int n_in,
                              void* d_out, int out_size, void* d_ws, size_t ws_size,
                              hipStream_t stream) {
    const int* ei   = (const int*)d_in[1];
    const int* srcv = ei;
    const int* dstv = ei + NEDGES;

    char* w = (char*)d_ws;
    const size_t MB = 1u << 20;
    const size_t KB = 1024;
    float* dinv1     = (float*)(w + 0);                 // 256 KB
    float* score     = (float*)(w + 256 * KB);          // 256 KB
    float* vals      = (float*)(w + 512 * KB);          // 128 KB
    int*   perm      = (int*)(w + 640 * KB);            // 128 KB
    int*   new_id    = (int*)(w + 768 * KB);            // 256 KB
    int*   deg1      = (int*)(w + 1024 * KB);           // 256 KB
    int*   node_base = (int*)(w + 1280 * KB);           // 256 KB
    float* dinv2     = (float*)(w + 1536 * KB);         // 128 KB
    float* invnorm   = (float*)(w + 1664 * KB);
    int*   flag      = (int*)(w + 1664 * KB + 64);
    int*   ghist     = (int*)(w + 1664 * KB + 1024);
    int*   gcur0     = (int*)(w + 1664 * KB + 2048);
    float* cw        = (float*)(w + 1700 * KB);         // 135 KB canonical weights
    float* pooled    = (float*)(w + 1840 * KB);         // 32 KB
    float* xw1  = (float*)(w + 2 * MB);                 // [2,34) MB
    float* agg  = (float*)(w + 34 * MB);                // [34,66) MB  (h)
    float* xw2  = (float*)(w + 2 * MB);                 // xw1 dead after s1
    unsigned int* elist    = (unsigned int*)(w + 66 * MB);   // [66,70) MB
    unsigned short* csr16  = (unsigned short*)(w + 70 * MB); // [70,72) MB

    float* W1f = cw + OW1; float* W2f = cw + OW2; float* Wlf = cw + OWL;
    float* b1f = cw + OB1; float* b2f = cw + OB2; float* pf  = cw + OP;
    float* blf = cw + OBL;

    prep_kernel<<<392, 256, 0, stream>>>(d_in[3], d_in[4], d_in[5], d_in[6], d_in[7],
                                         d_in[8], d_in[9], flag, cw, invnorm, new_id,
                                         ghist, gcur0, pooled);
    hist_kernel<<<256, 256, 0, stream>>>(srcv, ghist);
    binpass_kernel<<<256, 256, 0, stream>>>(srcv, dstv, ghist, gcur0, elist);
    gemm_a_kernel<<<NNODES / 64, 256, 0, stream>>>(d_in[0], W1f, xw1, flag);
    csr_sort_kernel<<<NGRAPH, 1024, 0, stream>>>(elist, ghist, csr16, node_base,
                                                 deg1, dinv1);
    s1_pull<<<NNODES / 4, 256, 0, stream>>>(csr16, node_base, deg1, dinv1, xw1, b1f, pf,
                                            invnorm, agg, score);
    topk_kernel<<<NGRAPH, 1024, 0, stream>>>(score, elist, ghist, vals, perm,
                                             new_id, dinv2);
    gemm_gather<<<M2 / 64, 256, 0, stream>>>(agg, perm, vals, W2f, xw2);
    s2_pull<<<M2 / 4, 256, 0, stream>>>(csr16, node_base, deg1, perm, new_id, dinv2,
                                        xw2, b2f, pooled);
    outk_kernel<<<NGRAPH, 128, 0, stream>>>(pooled, Wlf, blf, d_out, flag);

    (void)in_sizes; (void)n_in; (void)out_size; (void)ws_size;
}

// Round 13
// 282.099 us; speedup vs baseline: 5.5147x; 1.0577x over previous
//
#include <hip/hip_runtime.h>

#define NNODES 65536
#define NEDGES 1048576
#define NGRAPH 64
#define NPERG  1024
#define KEEP   512
#define M2     (NGRAPH * KEEP)   // 32768
#define HD     128
#define NC     10
#define EMAX   20480             // per-graph edge capacity (avg 16384, sigma~127)

// canonical weight block offsets (floats)
#define OW1 0
#define OW2 16384
#define OWL 32768
#define OB1 34048
#define OB2 34176
#define OP  34304
#define OBL 34432
#define NCVT 34448

__device__ __forceinline__ float bf2f(unsigned short u) {
    return __uint_as_float(((unsigned int)u) << 16);
}
__device__ __forceinline__ unsigned short f2bf(float f) {
    unsigned int u = __float_as_uint(f);
    unsigned int r = (u + 0x7FFFu + ((u >> 16) & 1u)) >> 16;
    return (unsigned short)r;
}

// ---------------- prep: detect dtype + cvt weights + pnorm + init ------------
__global__ __launch_bounds__(256) void prep_kernel(
    const void* __restrict__ W1, const void* __restrict__ b1, const void* __restrict__ p,
    const void* __restrict__ W2, const void* __restrict__ b2, const void* __restrict__ Wl,
    const void* __restrict__ bl, int* __restrict__ flag, float* __restrict__ cw,
    float* __restrict__ invnorm, int* __restrict__ new_id, int* __restrict__ ghist,
    int* __restrict__ gcur0, float* __restrict__ pooled) {
    int bid = blockIdx.x, t = threadIdx.x;
    const unsigned short* w1u = (const unsigned short*)W1;
    int local = 0;
    for (int i = t; i < 512; i += 256) {
        unsigned short u = w1u[2 * i];
        int e = (u >> 7) & 0xFF;
        local += (e >= 100 && e <= 140) ? 1 : 0;
    }
    __shared__ int red[256];
    red[t] = local;
    __syncthreads();
    for (int off = 128; off; off >>= 1) {
        if (t < off) red[t] += red[t + off];
        __syncthreads();
    }
    int fl = (red[0] >= 384) ? 1 : 0;
    if (bid == 0 && t == 0) flag[0] = fl;

    if (bid < 135) {
        int gid = bid * 256 + t;
        if (gid < NCVT) {
            const void* srcp; int idx;
            if (gid < OB1) {
                if (gid < OW2)      { srcp = W1; idx = gid - OW1; }
                else if (gid < OWL) { srcp = W2; idx = gid - OW2; }
                else                { srcp = Wl; idx = gid - OWL; }
            } else {
                if (gid < OB2)      { srcp = b1; idx = gid - OB1; }
                else if (gid < OP)  { srcp = b2; idx = gid - OB2; }
                else if (gid < OBL) { srcp = p;  idx = gid - OP; }
                else                { srcp = bl; idx = gid - OBL; }
            }
            float v;
            if (gid >= OWL && gid < OB1 && idx >= 1280) v = 0.f;       // Wl pad
            else if (gid >= OBL && idx >= NC) v = 0.f;                  // bl pad
            else if (fl) v = bf2f(((const unsigned short*)srcp)[idx]);
            else v = ((const float*)srcp)[idx];
            cw[gid] = v;
        }
    } else if (bid == 135) {
        __shared__ float s2a[128];
        float pv = 0.f;
        if (t < 128) pv = fl ? bf2f(((const unsigned short*)p)[t]) : ((const float*)p)[t];
        if (t < 128) s2a[t] = pv * pv;
        __syncthreads();
        for (int off = 64; off; off >>= 1) {
            if (t < off) s2a[t] += s2a[t + off];
            __syncthreads();
        }
        if (t == 0) invnorm[0] = 1.0f / sqrtf(s2a[0]);
    } else {
        int i = (bid - 136) * 256 + t;
        new_id[i] = -1;
        if (i < NGRAPH) { ghist[i] = 0; gcur0[i] = 0; }
        if (i < NGRAPH * HD) pooled[i] = 0.f;
    }
}

// ---------------- edge binning by graph --------------------------------------
__global__ __launch_bounds__(256) void hist_kernel(const int* __restrict__ src,
                                                   int* __restrict__ ghist) {
    __shared__ int lh[NGRAPH];
    int tid = threadIdx.x;
    if (tid < NGRAPH) lh[tid] = 0;
    __syncthreads();
    int e0 = blockIdx.x * 4096;  // 256 blocks
    for (int k = 0; k < 16; k++) atomicAdd(&lh[src[e0 + k * 256 + tid] >> 10], 1);
    __syncthreads();
    if (tid < NGRAPH) atomicAdd(&ghist[tid], lh[tid]);
}
__global__ __launch_bounds__(256) void binpass_kernel(const int* __restrict__ src,
                                                      const int* __restrict__ dst,
                                                      const int* __restrict__ ghist,
                                                      int* __restrict__ gcur0,
                                                      unsigned int* __restrict__ elist) {
    __shared__ int gh[NGRAPH];
    __shared__ int gbS[NGRAPH];
    __shared__ int lh[NGRAPH];
    __shared__ int lbase[NGRAPH];
    int tid = threadIdx.x;
    if (tid < NGRAPH) { gh[tid] = ghist[tid]; lh[tid] = 0; }
    __syncthreads();
    if (tid == 0) {
        int s = 0;
        for (int i = 0; i < NGRAPH; i++) { gbS[i] = s; s += gh[i]; }
    }
    __syncthreads();
    int e0 = blockIdx.x * 4096;  // 256 blocks
    int gs[16]; unsigned int pk[16];
    for (int k = 0; k < 16; k++) {
        int e = e0 + k * 256 + tid;
        int s = src[e], d = dst[e];
        gs[k] = s >> 10;
        pk[k] = (unsigned)(s & 1023) | ((unsigned)(d & 1023) << 10);
        atomicAdd(&lh[gs[k]], 1);
    }
    __syncthreads();
    if (tid < NGRAPH) { lbase[tid] = gbS[tid] + atomicAdd(&gcur0[tid], lh[tid]); lh[tid] = 0; }
    __syncthreads();
    for (int k = 0; k < 16; k++) {
        int g = gs[k];
        int pos = lbase[g] + atomicAdd(&lh[g], 1);
        elist[pos] = pk[k];
    }
}

// ---------------- per-graph LDS counting-sort CSR + deg1 + dinv1 -------------
// Scan via per-wave shfl prefix + 16-wave cross-scan (2 barriers, not 20).
__global__ __launch_bounds__(1024) void csr_sort_kernel(
    const unsigned int* __restrict__ elist, const int* __restrict__ ghist,
    unsigned short* __restrict__ csr16, int* __restrict__ node_base,
    int* __restrict__ deg_out, float* __restrict__ dinv_out) {
    __shared__ unsigned short sc[EMAX];  // 40 KB
    __shared__ int cnt[NPERG];           // 4 KB
    __shared__ int cur[NPERG];           // 4 KB
    __shared__ int wsum[16];
    __shared__ int gh[NGRAPH];
    __shared__ int baseS, nS;
    int g = blockIdx.x, t = threadIdx.x;
    cnt[t] = 0;
    if (t < NGRAPH) gh[t] = ghist[t];
    __syncthreads();
    if (t == 0) {
        int s = 0;
        for (int i = 0; i < g; i++) s += gh[i];
        baseS = s; nS = gh[g];
    }
    __syncthreads();
    int base = baseS;
    int n = nS; if (n > EMAX) n = EMAX;
    for (int j = t; j < n; j += 1024) atomicAdd(&cnt[(elist[base + j] >> 10) & 1023], 1);
    __syncthreads();
    int v = cnt[t];
    // intra-wave inclusive scan
    int lane = t & 63;
    int x = v;
    for (int off = 1; off < 64; off <<= 1) {
        int y = __shfl_up(x, off);
        if (lane >= off) x += y;
    }
    if (lane == 63) wsum[t >> 6] = x;
    __syncthreads();
    if (t < 16) {
        int wv = wsum[t];
        int wx = wv;
        for (int off = 1; off < 16; off <<= 1) {
            int y = __shfl_up(wx, off);
            if (t >= off) wx += y;
        }
        wsum[t] = wx - wv;  // exclusive wave base
    }
    __syncthreads();
    int excl = x - v + wsum[t >> 6];
    cur[t] = excl;
    deg_out[g * NPERG + t] = v;
    dinv_out[g * NPERG + t] = rsqrtf((float)v + 1.0f);
    node_base[g * NPERG + t] = base + excl;
    __syncthreads();
    for (int j = t; j < n; j += 1024) {
        unsigned int pk = elist[base + j];
        int d = (pk >> 10) & 1023;
        int pos = atomicAdd(&cur[d], 1);
        sc[pos] = (unsigned short)(pk & 1023);
    }
    __syncthreads();
    for (int j = t; j < n; j += 1024) csr16[base + j] = sc[j];
}

// ---------------- GEMM1: C = A(flagged dtype) @ W, fp32 math, bf16-packed out -
__global__ __launch_bounds__(256) void gemm_a_kernel(const void* __restrict__ Araw,
                                                     const float* __restrict__ W,
                                                     unsigned int* __restrict__ Cb,
                                                     const int* __restrict__ flag) {
    __shared__ float As[64 * HD];  // 32 KB
    int tid = threadIdx.x;
    int row0 = blockIdx.x * 64;
    if (flag[0]) {
        const unsigned short* Au = (const unsigned short*)Araw + (size_t)row0 * HD;
        for (int i = tid; i < 64 * HD; i += 256) As[i] = bf2f(Au[i]);
    } else {
        const float* Af = (const float*)Araw + (size_t)row0 * HD;
        for (int i = tid; i < 64 * HD / 4; i += 256)
            reinterpret_cast<float4*>(As)[i] = reinterpret_cast<const float4*>(Af)[i];
    }
    __syncthreads();
    int cg = tid & 31;
    int rg = tid >> 5;
    const float4* As4 = reinterpret_cast<const float4*>(As);
    const float4* W4 = reinterpret_cast<const float4*>(W);
    float4 acc[8];
#pragma unroll
    for (int r = 0; r < 8; r++) acc[r] = {0.f, 0.f, 0.f, 0.f};
    for (int k4 = 0; k4 < 32; k4++) {
        float4 wv0 = W4[(k4 * 4 + 0) * 32 + cg];
        float4 wv1 = W4[(k4 * 4 + 1) * 32 + cg];
        float4 wv2 = W4[(k4 * 4 + 2) * 32 + cg];
        float4 wv3 = W4[(k4 * 4 + 3) * 32 + cg];
#pragma unroll
        for (int r = 0; r < 8; r++) {
            float4 av = As4[(rg * 8 + r) * 32 + k4];
            acc[r].x += av.x * wv0.x; acc[r].y += av.x * wv0.y;
            acc[r].z += av.x * wv0.z; acc[r].w += av.x * wv0.w;
            acc[r].x += av.y * wv1.x; acc[r].y += av.y * wv1.y;
            acc[r].z += av.y * wv1.z; acc[r].w += av.y * wv1.w;
            acc[r].x += av.z * wv2.x; acc[r].y += av.z * wv2.y;
            acc[r].z += av.z * wv2.z; acc[r].w += av.z * wv2.w;
            acc[r].x += av.w * wv3.x; acc[r].y += av.w * wv3.y;
            acc[r].z += av.w * wv3.z; acc[r].w += av.w * wv3.w;
        }
    }
    // pack to bf16 pairs: uint = ch(2c) | ch(2c+1)<<16
#pragma unroll
    for (int r = 0; r < 8; r++) {
        unsigned int lo = (unsigned int)f2bf(acc[r].x) | ((unsigned int)f2bf(acc[r].y) << 16);
        unsigned int hi = (unsigned int)f2bf(acc[r].z) | ((unsigned int)f2bf(acc[r].w) << 16);
        uint2 o = {lo, hi};
        reinterpret_cast<uint2*>(Cb + (size_t)(row0 + rg * 8 + r) * 64)[cg] = o;
    }
}

// ---------------- conv1 aggregate (pull, prefetched, bf16 rows) --------------
// Row = 128 bf16 = 256B = 1 dword/lane. Unpack: even ch = u<<16, odd = u&hi.
__global__ __launch_bounds__(256) void s1_pull(const unsigned short* __restrict__ csr16,
                                               const int* __restrict__ node_base,
                                               const int* __restrict__ deg,
                                               const float* __restrict__ dinv,
                                               const unsigned int* __restrict__ xwb,
                                               const float* __restrict__ b1,
                                               const float* __restrict__ pvec,
                                               const float* __restrict__ invnorm,
                                               float* __restrict__ h,
                                               float* __restrict__ score) {
    int b = blockIdx.x;                 // 16384 blocks
    int xcd = b & 7, j = b >> 3;        // XCD-swizzle: graph pinned to one XCD
    int g = (j >> 8) * 8 + xcd;
    int n = g * NPERG + (j & 255) * 4 + (threadIdx.x >> 6);
    int lane = threadIdx.x & 63;
    int gb = g * NPERG;
    int base = node_base[n], cnt = deg[n];
    int e = 0; float ds = 0.f;
    if (lane < cnt) {
        e = csr16[base + lane];
        ds = dinv[gb + e];
    }
    float a0 = 0.f, a1 = 0.f;
    int klim = cnt < 64 ? cnt : 64;
    int k = 0;
    for (; k + 3 < klim; k += 4) {
        int s0 = __shfl(e, k), s1 = __shfl(e, k + 1);
        int s2 = __shfl(e, k + 2), s3 = __shfl(e, k + 3);
        float d0 = __shfl(ds, k), d1 = __shfl(ds, k + 1);
        float d2 = __shfl(ds, k + 2), d3 = __shfl(ds, k + 3);
        unsigned int u0 = xwb[(size_t)(gb + s0) * 64 + lane];
        unsigned int u1 = xwb[(size_t)(gb + s1) * 64 + lane];
        unsigned int u2 = xwb[(size_t)(gb + s2) * 64 + lane];
        unsigned int u3 = xwb[(size_t)(gb + s3) * 64 + lane];
        a0 += d0 * __uint_as_float(u0 << 16); a1 += d0 * __uint_as_float(u0 & 0xFFFF0000u);
        a0 += d1 * __uint_as_float(u1 << 16); a1 += d1 * __uint_as_float(u1 & 0xFFFF0000u);
        a0 += d2 * __uint_as_float(u2 << 16); a1 += d2 * __uint_as_float(u2 & 0xFFFF0000u);
        a0 += d3 * __uint_as_float(u3 << 16); a1 += d3 * __uint_as_float(u3 & 0xFFFF0000u);
    }
    for (; k < klim; k++) {
        int sk = __shfl(e, k);
        float dk = __shfl(ds, k);
        unsigned int u = xwb[(size_t)(gb + sk) * 64 + lane];
        a0 += dk * __uint_as_float(u << 16); a1 += dk * __uint_as_float(u & 0xFFFF0000u);
    }
    for (; k < cnt; k++) {  // deg>64 cold path (P ~ 0, correctness only)
        int sk = csr16[base + k];
        float dk = dinv[gb + sk];
        unsigned int u = xwb[(size_t)(gb + sk) * 64 + lane];
        a0 += dk * __uint_as_float(u << 16); a1 += dk * __uint_as_float(u & 0xFFFF0000u);
    }
    float dn = dinv[n];
    float self = dn * dn;
    unsigned int us = xwb[(size_t)n * 64 + lane];
    float2 bb = ((const float2*)b1)[lane];
    float h0 = fmaxf(dn * a0 + self * __uint_as_float(us << 16) + bb.x, 0.f);
    float h1 = fmaxf(dn * a1 + self * __uint_as_float(us & 0xFFFF0000u) + bb.y, 0.f);
    float2 ho = {h0, h1};
    ((float2*)h)[(size_t)n * 64 + lane] = ho;
    float2 pp = ((const float2*)pvec)[lane];
    float sv = h0 * pp.x + h1 * pp.y;
    for (int off = 32; off; off >>= 1) sv += __shfl_down(sv, off);
    if (lane == 0) score[n] = tanhf(sv * invnorm[0]);
}

// ---------------- top-512 bitonic + fused deg2/dinv2 -------------------------
__global__ __launch_bounds__(1024) void topk_kernel(const float* __restrict__ score,
                                                    const unsigned int* __restrict__ elist,
                                                    const int* __restrict__ ghist,
                                                    float* __restrict__ vals,
                                                    int* __restrict__ perm,
                                                    int* __restrict__ new_id,
                                                    float* __restrict__ dinv2) {
    __shared__ float sv[1024];
    __shared__ int si[1024];
    __shared__ short nid[1024];
    __shared__ int d2[KEEP];
    __shared__ int gh[NGRAPH];
    __shared__ int baseS, nS;
    int g = blockIdx.x, t = threadIdx.x;
    sv[t] = score[g * NPERG + t];
    si[t] = t;
    nid[t] = -1;
    if (t < KEEP) d2[t] = 0;
    if (t < NGRAPH) gh[t] = ghist[t];
    __syncthreads();
    if (t == 0) {
        int s = 0;
        for (int i = 0; i < g; i++) s += gh[i];
        baseS = s; nS = gh[g];
    }
    for (int k = 2; k <= 1024; k <<= 1) {
        for (int j = k >> 1; j > 0; j >>= 1) {
            int l = t ^ j;
            if (l > t) {
                bool desc = ((t & k) == 0);
                float va = sv[t], vb = sv[l];
                int ia = si[t], ib = si[l];
                bool gab = (va > vb) || (va == vb && ia < ib);  // lax.top_k tie rule
                if (gab != desc) { sv[t] = vb; si[t] = ib; sv[l] = va; si[l] = ia; }
            }
            __syncthreads();
        }
    }
    if (t < KEEP) {
        int node = g * NPERG + si[t];
        int slot = g * KEEP + t;
        vals[slot] = sv[t];
        perm[slot] = node;
        new_id[node] = slot;
        nid[si[t]] = (short)t;
    }
    __syncthreads();
    int base = baseS, n = nS;
    for (int j = t; j < n; j += 1024) {
        unsigned int pk = elist[base + j];
        int s = pk & 1023, d = (pk >> 10) & 1023;
        short ns = nid[s], nd = nid[d];
        if (ns >= 0 && nd >= 0) atomicAdd(&d2[nd], 1);
    }
    __syncthreads();
    if (t < KEEP) dinv2[g * KEEP + t] = rsqrtf((float)d2[t] + 1.0f);
}

// ---------------- GEMM2 with fused gather+gate A-staging ---------------------
__global__ __launch_bounds__(256) void gemm_gather(const float* __restrict__ h,
                                                   const int* __restrict__ perm,
                                                   const float* __restrict__ vals,
                                                   const float* __restrict__ W,
                                                   float* __restrict__ C) {
    __shared__ float As[64 * HD];
    int tid = threadIdx.x;
    int row0 = blockIdx.x * 64;
    for (int i4 = tid; i4 < 64 * 32; i4 += 256) {
        int r = i4 >> 5, c4 = i4 & 31;
        int m = row0 + r;
        float sc = vals[m];
        float4 v = reinterpret_cast<const float4*>(h + (size_t)perm[m] * HD)[c4];
        v.x *= sc; v.y *= sc; v.z *= sc; v.w *= sc;
        reinterpret_cast<float4*>(As)[i4] = v;
    }
    __syncthreads();
    int cg = tid & 31;
    int rg = tid >> 5;
    const float4* As4 = reinterpret_cast<const float4*>(As);
    const float4* W4 = reinterpret_cast<const float4*>(W);
    float4 acc[8];
#pragma unroll
    for (int r = 0; r < 8; r++) acc[r] = {0.f, 0.f, 0.f, 0.f};
    for (int k4 = 0; k4 < 32; k4++) {
        float4 wv0 = W4[(k4 * 4 + 0) * 32 + cg];
        float4 wv1 = W4[(k4 * 4 + 1) * 32 + cg];
        float4 wv2 = W4[(k4 * 4 + 2) * 32 + cg];
        float4 wv3 = W4[(k4 * 4 + 3) * 32 + cg];
#pragma unroll
        for (int r = 0; r < 8; r++) {
            float4 av = As4[(rg * 8 + r) * 32 + k4];
            acc[r].x += av.x * wv0.x; acc[r].y += av.x * wv0.y;
            acc[r].z += av.x * wv0.z; acc[r].w += av.x * wv0.w;
            acc[r].x += av.y * wv1.x; acc[r].y += av.y * wv1.y;
            acc[r].z += av.y * wv1.z; acc[r].w += av.y * wv1.w;
            acc[r].x += av.z * wv2.x; acc[r].y += av.z * wv2.y;
            acc[r].z += av.z * wv2.z; acc[r].w += av.z * wv2.w;
            acc[r].x += av.w * wv3.x; acc[r].y += av.w * wv3.y;
            acc[r].z += av.w * wv3.z; acc[r].w += av.w * wv3.w;
        }
    }
#pragma unroll
    for (int r = 0; r < 8; r++)
        reinterpret_cast<float4*>(C + (size_t)(row0 + rg * 8 + r) * HD)[cg] = acc[r];
}

// ---------------- conv2 aggregate (pull, prefetched) + mask + fused pool -----
__global__ __launch_bounds__(256) void s2_pull(const unsigned short* __restrict__ csr16,
                                               const int* __restrict__ node_base,
                                               const int* __restrict__ deg,
                                               const int* __restrict__ perm,
                                               const int* __restrict__ new_id,
                                               const float* __restrict__ dinv2,
                                               const float* __restrict__ xw2,
                                               const float* __restrict__ b2,
                                               float* __restrict__ pooled) {
    __shared__ float pr[HD];
    int tid = threadIdx.x;
    if (tid < HD) pr[tid] = 0.f;
    __syncthreads();
    int b = blockIdx.x;              // 8192 blocks
    int xcd = b & 7, j = b >> 3;
    int g = (j >> 7) * 8 + xcd;
    int m = g * KEEP + (j & 127) * 4 + (tid >> 6);
    int lane = tid & 63;
    int node = perm[m];
    int gb = node & ~(NPERG - 1);
    int base = node_base[node], cnt = deg[node];
    int nk = 0; float ds = 0.f;
    if (lane < cnt) {
        int ns = new_id[gb + csr16[base + lane]];
        if (ns >= 0) { nk = ns; ds = dinv2[ns]; }
    }
    const float2* xf2 = (const float2*)xw2;
    float a0 = 0.f, a1 = 0.f;
    int klim = cnt < 64 ? cnt : 64;
    for (int k = 0; k < klim; k++) {
        float dk = __shfl(ds, k);       // uniform k -> readlane (scalar)
        if (dk != 0.f) {                 // wave-uniform skip (~75% masked)
            int sk = __shfl(nk, k);
            float2 v = xf2[(size_t)sk * 64 + lane];
            a0 += dk * v.x; a1 += dk * v.y;
        }
    }
    for (int k = 64; k < cnt; k++) {    // deg>64 cold path
        int ns = new_id[gb + csr16[base + k]];
        if (ns >= 0) {
            float dk = dinv2[ns];
            float2 v = xf2[(size_t)ns * 64 + lane];
            a0 += dk * v.x; a1 += dk * v.y;
        }
    }
    float dn = dinv2[m];
    float self = dn * dn;
    float2 xs = xf2[(size_t)m * 64 + lane];
    float2 bb = ((const float2*)b2)[lane];
    float o0 = fmaxf(dn * a0 + self * xs.x + bb.x, 0.f);
    float o1 = fmaxf(dn * a1 + self * xs.y + bb.y, 0.f);
    atomicAdd(&pr[lane * 2], o0);
    atomicAdd(&pr[lane * 2 + 1], o1);
    __syncthreads();
    if (tid < HD) atomicAdd(&pooled[g * HD + tid], pr[tid]);
}

// ---------------- final linear: out = (pooled/512) @ Wl + bl -----------------
__global__ __launch_bounds__(128) void outk_kernel(const float* __restrict__ pooled,
                                                   const float* __restrict__ Wl,
                                                   const float* __restrict__ bl,
                                                   void* __restrict__ outv,
                                                   const int* __restrict__ flag) {
    int g = blockIdx.x, t = threadIdx.x;  // 128
    __shared__ float sp[HD];
    sp[t] = pooled[g * HD + t] * (1.0f / KEEP);
    __syncthreads();
    if (t < NC) {
        float acc = bl[t];
        for (int hh = 0; hh < HD; hh++) acc += sp[hh] * Wl[hh * NC + t];
        if (flag[0]) ((unsigned short*)outv)[g * NC + t] = f2bf(acc);
        else         ((float*)outv)[g * NC + t] = acc;
    }
}

extern "C" void kernel_launch(void* const* d_in, const int* in_sizes, int n_in,
                              void* d_out, int out_size, void* d_ws, size_t ws_size,
                              hipStream_t stream) {
    const int* ei   = (const int*)d_in[1];
    const int* srcv = ei;
    const int* dstv = ei + NEDGES;

    char* w = (char*)d_ws;
    const size_t MB = 1u << 20;
    const size_t KB = 1024;
    float* dinv1     = (float*)(w + 0);                 // 256 KB
    float* score     = (float*)(w + 256 * KB);          // 256 KB
    float* vals      = (float*)(w + 512 * KB);          // 128 KB
    int*   perm      = (int*)(w + 640 * KB);            // 128 KB
    int*   new_id    = (int*)(w + 768 * KB);            // 256 KB
    int*   deg1      = (int*)(w + 1024 * KB);           // 256 KB
    int*   node_base = (int*)(w + 1280 * KB);           // 256 KB
    float* dinv2     = (float*)(w + 1536 * KB);         // 128 KB
    float* invnorm   = (float*)(w + 1664 * KB);
    int*   flag      = (int*)(w + 1664 * KB + 64);
    int*   ghist     = (int*)(w + 1664 * KB + 1024);
    int*   gcur0     = (int*)(w + 1664 * KB + 2048);
    float* cw        = (float*)(w + 1700 * KB);         // 135 KB canonical weights
    float* pooled    = (float*)(w + 1840 * KB);         // 32 KB
    unsigned int* xw1b = (unsigned int*)(w + 2 * MB);   // [2,18) MB  bf16-packed xw1
    float* xw2  = (float*)(w + 18 * MB);                // [18,34) MB
    float* agg  = (float*)(w + 34 * MB);                // [34,66) MB  (h)
    unsigned int* elist    = (unsigned int*)(w + 66 * MB);   // [66,70) MB
    unsigned short* csr16  = (unsigned short*)(w + 70 * MB); // [70,72) MB

    float* W1f = cw + OW1; float* W2f = cw + OW2; float* Wlf = cw + OWL;
    float* b1f = cw + OB1; float* b2f = cw + OB2; float* pf  = cw + OP;
    float* blf = cw + OBL;

    prep_kernel<<<392, 256, 0, stream>>>(d_in[3], d_in[4], d_in[5], d_in[6], d_in[7],
                                         d_in[8], d_in[9], flag, cw, invnorm, new_id,
                                         ghist, gcur0, pooled);
    hist_kernel<<<256, 256, 0, stream>>>(srcv, ghist);
    binpass_kernel<<<256, 256, 0, stream>>>(srcv, dstv, ghist, gcur0, elist);
    gemm_a_kernel<<<NNODES / 64, 256, 0, stream>>>(d_in[0], W1f, xw1b, flag);
    csr_sort_kernel<<<NGRAPH, 1024, 0, stream>>>(elist, ghist, csr16, node_base,
                                                 deg1, dinv1);
    s1_pull<<<NNODES / 4, 256, 0, stream>>>(csr16, node_base, deg1, dinv1, xw1b, b1f, pf,
                                            invnorm, agg, score);
    topk_kernel<<<NGRAPH, 1024, 0, stream>>>(score, elist, ghist, vals, perm,
                                             new_id, dinv2);
    gemm_gather<<<M2 / 64, 256, 0, stream>>>(agg, perm, vals, W2f, xw2);
    s2_pull<<<M2 / 4, 256, 0, stream>>>(csr16, node_base, deg1, perm, new_id, dinv2,
                                        xw2, b2f, pooled);
    outk_kernel<<<NGRAPH, 128, 0, stream>>>(pooled, Wlf, blf, d_out, flag);

    (void)in_sizes; (void)n_in; (void)out_size; (void)ws_size;
}

// Round 14
// 278.825 us; speedup vs baseline: 5.5795x; 1.0117x over previous
//
#include <hip/hip_runtime.h>

#define NNODES 65536
#define NEDGES 1048576
#define NGRAPH 64
#define NPERG  1024
#define KEEP   512
#define M2     (NGRAPH * KEEP)   // 32768
#define HD     128
#define NC     10
#define EMAX   20480             // per-graph edge capacity (avg 16384, sigma~127)

// canonical weight block offsets (floats)
#define OW1 0
#define OW2 16384
#define OWL 32768
#define OB1 34048
#define OB2 34176
#define OP  34304
#define OBL 34432
#define NCVT 34448

__device__ __forceinline__ float bf2f(unsigned short u) {
    return __uint_as_float(((unsigned int)u) << 16);
}
__device__ __forceinline__ unsigned short f2bf(float f) {
    unsigned int u = __float_as_uint(f);
    unsigned int r = (u + 0x7FFFu + ((u >> 16) & 1u)) >> 16;
    return (unsigned short)r;
}

// ---------------- prep: detect dtype + cvt weights + pnorm + init ------------
__global__ __launch_bounds__(256) void prep_kernel(
    const void* __restrict__ W1, const void* __restrict__ b1, const void* __restrict__ p,
    const void* __restrict__ W2, const void* __restrict__ b2, const void* __restrict__ Wl,
    const void* __restrict__ bl, int* __restrict__ flag, float* __restrict__ cw,
    float* __restrict__ invnorm, int* __restrict__ new_id, int* __restrict__ ghist,
    int* __restrict__ gcur0, float* __restrict__ pooled) {
    int bid = blockIdx.x, t = threadIdx.x;
    const unsigned short* w1u = (const unsigned short*)W1;
    int local = 0;
    for (int i = t; i < 512; i += 256) {
        unsigned short u = w1u[2 * i];
        int e = (u >> 7) & 0xFF;
        local += (e >= 100 && e <= 140) ? 1 : 0;
    }
    __shared__ int red[256];
    red[t] = local;
    __syncthreads();
    for (int off = 128; off; off >>= 1) {
        if (t < off) red[t] += red[t + off];
        __syncthreads();
    }
    int fl = (red[0] >= 384) ? 1 : 0;
    if (bid == 0 && t == 0) flag[0] = fl;

    if (bid < 135) {
        int gid = bid * 256 + t;
        if (gid < NCVT) {
            const void* srcp; int idx;
            if (gid < OB1) {
                if (gid < OW2)      { srcp = W1; idx = gid - OW1; }
                else if (gid < OWL) { srcp = W2; idx = gid - OW2; }
                else                { srcp = Wl; idx = gid - OWL; }
            } else {
                if (gid < OB2)      { srcp = b1; idx = gid - OB1; }
                else if (gid < OP)  { srcp = b2; idx = gid - OB2; }
                else if (gid < OBL) { srcp = p;  idx = gid - OP; }
                else                { srcp = bl; idx = gid - OBL; }
            }
            float v;
            if (gid >= OWL && gid < OB1 && idx >= 1280) v = 0.f;       // Wl pad
            else if (gid >= OBL && idx >= NC) v = 0.f;                  // bl pad
            else if (fl) v = bf2f(((const unsigned short*)srcp)[idx]);
            else v = ((const float*)srcp)[idx];
            cw[gid] = v;
        }
    } else if (bid == 135) {
        __shared__ float s2a[128];
        float pv = 0.f;
        if (t < 128) pv = fl ? bf2f(((const unsigned short*)p)[t]) : ((const float*)p)[t];
        if (t < 128) s2a[t] = pv * pv;
        __syncthreads();
        for (int off = 64; off; off >>= 1) {
            if (t < off) s2a[t] += s2a[t + off];
            __syncthreads();
        }
        if (t == 0) invnorm[0] = 1.0f / sqrtf(s2a[0]);
    } else {
        int i = (bid - 136) * 256 + t;
        new_id[i] = -1;
        if (i < NGRAPH) { ghist[i] = 0; gcur0[i] = 0; }
        if (i < NGRAPH * HD) pooled[i] = 0.f;
    }
}

// ---------------- edge binning by graph --------------------------------------
__global__ __launch_bounds__(256) void hist_kernel(const int* __restrict__ src,
                                                   int* __restrict__ ghist) {
    __shared__ int lh[NGRAPH];
    int tid = threadIdx.x;
    if (tid < NGRAPH) lh[tid] = 0;
    __syncthreads();
    int e0 = blockIdx.x * 4096;  // 256 blocks
    for (int k = 0; k < 16; k++) atomicAdd(&lh[src[e0 + k * 256 + tid] >> 10], 1);
    __syncthreads();
    if (tid < NGRAPH) atomicAdd(&ghist[tid], lh[tid]);
}
__global__ __launch_bounds__(256) void binpass_kernel(const int* __restrict__ src,
                                                      const int* __restrict__ dst,
                                                      const int* __restrict__ ghist,
                                                      int* __restrict__ gcur0,
                                                      unsigned int* __restrict__ elist) {
    __shared__ int gh[NGRAPH];
    __shared__ int gbS[NGRAPH];
    __shared__ int lh[NGRAPH];
    __shared__ int lbase[NGRAPH];
    int tid = threadIdx.x;
    if (tid < NGRAPH) { gh[tid] = ghist[tid]; lh[tid] = 0; }
    __syncthreads();
    if (tid == 0) {
        int s = 0;
        for (int i = 0; i < NGRAPH; i++) { gbS[i] = s; s += gh[i]; }
    }
    __syncthreads();
    int e0 = blockIdx.x * 4096;  // 256 blocks
    int gs[16]; unsigned int pk[16];
    for (int k = 0; k < 16; k++) {
        int e = e0 + k * 256 + tid;
        int s = src[e], d = dst[e];
        gs[k] = s >> 10;
        pk[k] = (unsigned)(s & 1023) | ((unsigned)(d & 1023) << 10);
        atomicAdd(&lh[gs[k]], 1);
    }
    __syncthreads();
    if (tid < NGRAPH) { lbase[tid] = gbS[tid] + atomicAdd(&gcur0[tid], lh[tid]); lh[tid] = 0; }
    __syncthreads();
    for (int k = 0; k < 16; k++) {
        int g = gs[k];
        int pos = lbase[g] + atomicAdd(&lh[g], 1);
        elist[pos] = pk[k];
    }
}

// ---------------- per-graph LDS counting-sort CSR + deg1 + dinv1 -------------
// Scan via per-wave shfl prefix + 16-wave cross-scan (2 barriers, not 20).
__global__ __launch_bounds__(1024) void csr_sort_kernel(
    const unsigned int* __restrict__ elist, const int* __restrict__ ghist,
    unsigned short* __restrict__ csr16, int* __restrict__ node_base,
    int* __restrict__ deg_out, float* __restrict__ dinv_out) {
    __shared__ unsigned short sc[EMAX];  // 40 KB
    __shared__ int cnt[NPERG];           // 4 KB
    __shared__ int cur[NPERG];           // 4 KB
    __shared__ int wsum[16];
    __shared__ int gh[NGRAPH];
    __shared__ int baseS, nS;
    int g = blockIdx.x, t = threadIdx.x;
    cnt[t] = 0;
    if (t < NGRAPH) gh[t] = ghist[t];
    __syncthreads();
    if (t == 0) {
        int s = 0;
        for (int i = 0; i < g; i++) s += gh[i];
        baseS = s; nS = gh[g];
    }
    __syncthreads();
    int base = baseS;
    int n = nS; if (n > EMAX) n = EMAX;
    for (int j = t; j < n; j += 1024) atomicAdd(&cnt[(elist[base + j] >> 10) & 1023], 1);
    __syncthreads();
    int v = cnt[t];
    int lane = t & 63;
    int x = v;
    for (int off = 1; off < 64; off <<= 1) {
        int y = __shfl_up(x, off);
        if (lane >= off) x += y;
    }
    if (lane == 63) wsum[t >> 6] = x;
    __syncthreads();
    if (t < 16) {
        int wv = wsum[t];
        int wx = wv;
        for (int off = 1; off < 16; off <<= 1) {
            int y = __shfl_up(wx, off);
            if (t >= off) wx += y;
        }
        wsum[t] = wx - wv;  // exclusive wave base
    }
    __syncthreads();
    int excl = x - v + wsum[t >> 6];
    cur[t] = excl;
    deg_out[g * NPERG + t] = v;
    dinv_out[g * NPERG + t] = rsqrtf((float)v + 1.0f);
    node_base[g * NPERG + t] = base + excl;
    __syncthreads();
    for (int j = t; j < n; j += 1024) {
        unsigned int pk = elist[base + j];
        int d = (pk >> 10) & 1023;
        int pos = atomicAdd(&cur[d], 1);
        sc[pos] = (unsigned short)(pk & 1023);
    }
    __syncthreads();
    for (int j = t; j < n; j += 1024) csr16[base + j] = sc[j];
}

// ---------------- GEMM1: C = A(flagged dtype) @ W, fp32 math, bf16-packed out -
__global__ __launch_bounds__(256) void gemm_a_kernel(const void* __restrict__ Araw,
                                                     const float* __restrict__ W,
                                                     unsigned int* __restrict__ Cb,
                                                     const int* __restrict__ flag) {
    __shared__ float As[64 * HD];  // 32 KB
    int tid = threadIdx.x;
    int row0 = blockIdx.x * 64;
    if (flag[0]) {
        const unsigned short* Au = (const unsigned short*)Araw + (size_t)row0 * HD;
        for (int i = tid; i < 64 * HD; i += 256) As[i] = bf2f(Au[i]);
    } else {
        const float* Af = (const float*)Araw + (size_t)row0 * HD;
        for (int i = tid; i < 64 * HD / 4; i += 256)
            reinterpret_cast<float4*>(As)[i] = reinterpret_cast<const float4*>(Af)[i];
    }
    __syncthreads();
    int cg = tid & 31;
    int rg = tid >> 5;
    const float4* As4 = reinterpret_cast<const float4*>(As);
    const float4* W4 = reinterpret_cast<const float4*>(W);
    float4 acc[8];
#pragma unroll
    for (int r = 0; r < 8; r++) acc[r] = {0.f, 0.f, 0.f, 0.f};
    for (int k4 = 0; k4 < 32; k4++) {
        float4 wv0 = W4[(k4 * 4 + 0) * 32 + cg];
        float4 wv1 = W4[(k4 * 4 + 1) * 32 + cg];
        float4 wv2 = W4[(k4 * 4 + 2) * 32 + cg];
        float4 wv3 = W4[(k4 * 4 + 3) * 32 + cg];
#pragma unroll
        for (int r = 0; r < 8; r++) {
            float4 av = As4[(rg * 8 + r) * 32 + k4];
            acc[r].x += av.x * wv0.x; acc[r].y += av.x * wv0.y;
            acc[r].z += av.x * wv0.z; acc[r].w += av.x * wv0.w;
            acc[r].x += av.y * wv1.x; acc[r].y += av.y * wv1.y;
            acc[r].z += av.y * wv1.z; acc[r].w += av.y * wv1.w;
            acc[r].x += av.z * wv2.x; acc[r].y += av.z * wv2.y;
            acc[r].z += av.z * wv2.z; acc[r].w += av.z * wv2.w;
            acc[r].x += av.w * wv3.x; acc[r].y += av.w * wv3.y;
            acc[r].z += av.w * wv3.z; acc[r].w += av.w * wv3.w;
        }
    }
#pragma unroll
    for (int r = 0; r < 8; r++) {
        unsigned int lo = (unsigned int)f2bf(acc[r].x) | ((unsigned int)f2bf(acc[r].y) << 16);
        unsigned int hi = (unsigned int)f2bf(acc[r].z) | ((unsigned int)f2bf(acc[r].w) << 16);
        uint2 o = {lo, hi};
        reinterpret_cast<uint2*>(Cb + (size_t)(row0 + rg * 8 + r) * 64)[cg] = o;
    }
}

// ---------------- conv1 aggregate (pull, prefetched, bf16 rows) --------------
__global__ __launch_bounds__(256) void s1_pull(const unsigned short* __restrict__ csr16,
                                               const int* __restrict__ node_base,
                                               const int* __restrict__ deg,
                                               const float* __restrict__ dinv,
                                               const unsigned int* __restrict__ xwb,
                                               const float* __restrict__ b1,
                                               const float* __restrict__ pvec,
                                               const float* __restrict__ invnorm,
                                               float* __restrict__ h,
                                               float* __restrict__ score) {
    int b = blockIdx.x;                 // 16384 blocks
    int xcd = b & 7, j = b >> 3;        // XCD-swizzle: graph pinned to one XCD
    int g = (j >> 8) * 8 + xcd;
    int n = g * NPERG + (j & 255) * 4 + (threadIdx.x >> 6);
    int lane = threadIdx.x & 63;
    int gb = g * NPERG;
    int base = node_base[n], cnt = deg[n];
    int e = 0; float ds = 0.f;
    if (lane < cnt) {
        e = csr16[base + lane];
        ds = dinv[gb + e];
    }
    float a0 = 0.f, a1 = 0.f;
    int klim = cnt < 64 ? cnt : 64;
    int k = 0;
    for (; k + 3 < klim; k += 4) {
        int s0 = __shfl(e, k), s1 = __shfl(e, k + 1);
        int s2 = __shfl(e, k + 2), s3 = __shfl(e, k + 3);
        float d0 = __shfl(ds, k), d1 = __shfl(ds, k + 1);
        float d2 = __shfl(ds, k + 2), d3 = __shfl(ds, k + 3);
        unsigned int u0 = xwb[(size_t)(gb + s0) * 64 + lane];
        unsigned int u1 = xwb[(size_t)(gb + s1) * 64 + lane];
        unsigned int u2 = xwb[(size_t)(gb + s2) * 64 + lane];
        unsigned int u3 = xwb[(size_t)(gb + s3) * 64 + lane];
        a0 += d0 * __uint_as_float(u0 << 16); a1 += d0 * __uint_as_float(u0 & 0xFFFF0000u);
        a0 += d1 * __uint_as_float(u1 << 16); a1 += d1 * __uint_as_float(u1 & 0xFFFF0000u);
        a0 += d2 * __uint_as_float(u2 << 16); a1 += d2 * __uint_as_float(u2 & 0xFFFF0000u);
        a0 += d3 * __uint_as_float(u3 << 16); a1 += d3 * __uint_as_float(u3 & 0xFFFF0000u);
    }
    for (; k < klim; k++) {
        int sk = __shfl(e, k);
        float dk = __shfl(ds, k);
        unsigned int u = xwb[(size_t)(gb + sk) * 64 + lane];
        a0 += dk * __uint_as_float(u << 16); a1 += dk * __uint_as_float(u & 0xFFFF0000u);
    }
    for (; k < cnt; k++) {  // deg>64 cold path (P ~ 0, correctness only)
        int sk = csr16[base + k];
        float dk = dinv[gb + sk];
        unsigned int u = xwb[(size_t)(gb + sk) * 64 + lane];
        a0 += dk * __uint_as_float(u << 16); a1 += dk * __uint_as_float(u & 0xFFFF0000u);
    }
    float dn = dinv[n];
    float self = dn * dn;
    unsigned int us = xwb[(size_t)n * 64 + lane];
    float2 bb = ((const float2*)b1)[lane];
    float h0 = fmaxf(dn * a0 + self * __uint_as_float(us << 16) + bb.x, 0.f);
    float h1 = fmaxf(dn * a1 + self * __uint_as_float(us & 0xFFFF0000u) + bb.y, 0.f);
    float2 ho = {h0, h1};
    ((float2*)h)[(size_t)n * 64 + lane] = ho;
    float2 pp = ((const float2*)pvec)[lane];
    float sv = h0 * pp.x + h1 * pp.y;
    for (int off = 32; off; off >>= 1) sv += __shfl_down(sv, off);
    if (lane == 0) score[n] = tanhf(sv * invnorm[0]);
}

// ---------------- top-512 bitonic + fused deg2/dinv2 -------------------------
__global__ __launch_bounds__(1024) void topk_kernel(const float* __restrict__ score,
                                                    const unsigned int* __restrict__ elist,
                                                    const int* __restrict__ ghist,
                                                    float* __restrict__ vals,
                                                    int* __restrict__ perm,
                                                    int* __restrict__ new_id,
                                                    float* __restrict__ dinv2) {
    __shared__ float sv[1024];
    __shared__ int si[1024];
    __shared__ short nid[1024];
    __shared__ int d2[KEEP];
    __shared__ int gh[NGRAPH];
    __shared__ int baseS, nS;
    int g = blockIdx.x, t = threadIdx.x;
    sv[t] = score[g * NPERG + t];
    si[t] = t;
    nid[t] = -1;
    if (t < KEEP) d2[t] = 0;
    if (t < NGRAPH) gh[t] = ghist[t];
    __syncthreads();
    if (t == 0) {
        int s = 0;
        for (int i = 0; i < g; i++) s += gh[i];
        baseS = s; nS = gh[g];
    }
    for (int k = 2; k <= 1024; k <<= 1) {
        for (int j = k >> 1; j > 0; j >>= 1) {
            int l = t ^ j;
            if (l > t) {
                bool desc = ((t & k) == 0);
                float va = sv[t], vb = sv[l];
                int ia = si[t], ib = si[l];
                bool gab = (va > vb) || (va == vb && ia < ib);  // lax.top_k tie rule
                if (gab != desc) { sv[t] = vb; si[t] = ib; sv[l] = va; si[l] = ia; }
            }
            __syncthreads();
        }
    }
    if (t < KEEP) {
        int node = g * NPERG + si[t];
        int slot = g * KEEP + t;
        vals[slot] = sv[t];
        perm[slot] = node;
        new_id[node] = slot;
        nid[si[t]] = (short)t;
    }
    __syncthreads();
    int base = baseS, n = nS;
    for (int j = t; j < n; j += 1024) {
        unsigned int pk = elist[base + j];
        int s = pk & 1023, d = (pk >> 10) & 1023;
        short ns = nid[s], nd = nid[d];
        if (ns >= 0 && nd >= 0) atomicAdd(&d2[nd], 1);
    }
    __syncthreads();
    if (t < KEEP) dinv2[g * KEEP + t] = rsqrtf((float)d2[t] + 1.0f);
}

// ---------------- GEMM2 with fused gather+gate A-staging ---------------------
__global__ __launch_bounds__(256) void gemm_gather(const float* __restrict__ h,
                                                   const int* __restrict__ perm,
                                                   const float* __restrict__ vals,
                                                   const float* __restrict__ W,
                                                   float* __restrict__ C) {
    __shared__ float As[64 * HD];
    int tid = threadIdx.x;
    int row0 = blockIdx.x * 64;
    for (int i4 = tid; i4 < 64 * 32; i4 += 256) {
        int r = i4 >> 5, c4 = i4 & 31;
        int m = row0 + r;
        float sc = vals[m];
        float4 v = reinterpret_cast<const float4*>(h + (size_t)perm[m] * HD)[c4];
        v.x *= sc; v.y *= sc; v.z *= sc; v.w *= sc;
        reinterpret_cast<float4*>(As)[i4] = v;
    }
    __syncthreads();
    int cg = tid & 31;
    int rg = tid >> 5;
    const float4* As4 = reinterpret_cast<const float4*>(As);
    const float4* W4 = reinterpret_cast<const float4*>(W);
    float4 acc[8];
#pragma unroll
    for (int r = 0; r < 8; r++) acc[r] = {0.f, 0.f, 0.f, 0.f};
    for (int k4 = 0; k4 < 32; k4++) {
        float4 wv0 = W4[(k4 * 4 + 0) * 32 + cg];
        float4 wv1 = W4[(k4 * 4 + 1) * 32 + cg];
        float4 wv2 = W4[(k4 * 4 + 2) * 32 + cg];
        float4 wv3 = W4[(k4 * 4 + 3) * 32 + cg];
#pragma unroll
        for (int r = 0; r < 8; r++) {
            float4 av = As4[(rg * 8 + r) * 32 + k4];
            acc[r].x += av.x * wv0.x; acc[r].y += av.x * wv0.y;
            acc[r].z += av.x * wv0.z; acc[r].w += av.x * wv0.w;
            acc[r].x += av.y * wv1.x; acc[r].y += av.y * wv1.y;
            acc[r].z += av.y * wv1.z; acc[r].w += av.y * wv1.w;
            acc[r].x += av.z * wv2.x; acc[r].y += av.z * wv2.y;
            acc[r].z += av.z * wv2.z; acc[r].w += av.z * wv2.w;
            acc[r].x += av.w * wv3.x; acc[r].y += av.w * wv3.y;
            acc[r].z += av.w * wv3.z; acc[r].w += av.w * wv3.w;
        }
    }
#pragma unroll
    for (int r = 0; r < 8; r++)
        reinterpret_cast<float4*>(C + (size_t)(row0 + rg * 8 + r) * HD)[cg] = acc[r];
}

// ---------------- conv2 aggregate: ballot-compact + batched loads + pool -----
// Surviving edges compacted into per-wave LDS via ballot prefix (wave-
// synchronous, no barrier), then branch-free x4-unrolled loop like s1.
// Compaction keeps ascending edge order -> sum bitwise identical to masked.
__global__ __launch_bounds__(256) void s2_pull(const unsigned short* __restrict__ csr16,
                                               const int* __restrict__ node_base,
                                               const int* __restrict__ deg,
                                               const int* __restrict__ perm,
                                               const int* __restrict__ new_id,
                                               const float* __restrict__ dinv2,
                                               const float* __restrict__ xw2,
                                               const float* __restrict__ b2,
                                               float* __restrict__ pooled) {
    __shared__ float pr[HD];
    __shared__ int cnk[4][64];
    __shared__ float cds[4][64];
    int tid = threadIdx.x;
    if (tid < HD) pr[tid] = 0.f;
    __syncthreads();
    int b = blockIdx.x;              // 8192 blocks
    int xcd = b & 7, j = b >> 3;
    int g = (j >> 7) * 8 + xcd;
    int wv = tid >> 6;
    int m = g * KEEP + (j & 127) * 4 + wv;
    int lane = tid & 63;
    int node = perm[m];
    int gb = node & ~(NPERG - 1);
    int base = node_base[node], cnt = deg[node];
    int nk = 0; float ds = 0.f;
    if (lane < cnt) {
        int ns = new_id[gb + csr16[base + lane]];
        if (ns >= 0) { nk = ns; ds = dinv2[ns]; }
    }
    // ballot-compact survivors into per-wave LDS (ascending lane order)
    unsigned long long msk = __ballot(ds != 0.f);
    int pos = __popcll(msk & ((1ull << lane) - 1ull));
    if (ds != 0.f) { cnk[wv][pos] = nk; cds[wv][pos] = ds; }
    int na = __popcll(msk);
    const float2* xf2 = (const float2*)xw2;
    float a0 = 0.f, a1 = 0.f;
    int k = 0;
    for (; k + 3 < na; k += 4) {
        int s0 = cnk[wv][k], s1 = cnk[wv][k + 1];
        int s2 = cnk[wv][k + 2], s3 = cnk[wv][k + 3];
        float d0 = cds[wv][k], d1 = cds[wv][k + 1];
        float d2 = cds[wv][k + 2], d3 = cds[wv][k + 3];
        float2 v0 = xf2[(size_t)s0 * 64 + lane];
        float2 v1 = xf2[(size_t)s1 * 64 + lane];
        float2 v2 = xf2[(size_t)s2 * 64 + lane];
        float2 v3 = xf2[(size_t)s3 * 64 + lane];
        a0 += d0 * v0.x; a1 += d0 * v0.y;
        a0 += d1 * v1.x; a1 += d1 * v1.y;
        a0 += d2 * v2.x; a1 += d2 * v2.y;
        a0 += d3 * v3.x; a1 += d3 * v3.y;
    }
    for (; k < na; k++) {
        int sk = cnk[wv][k];
        float dk = cds[wv][k];
        float2 v = xf2[(size_t)sk * 64 + lane];
        a0 += dk * v.x; a1 += dk * v.y;
    }
    for (int kk = 64; kk < cnt; kk++) {    // deg>64 cold path
        int ns = new_id[gb + csr16[base + kk]];
        if (ns >= 0) {
            float dk = dinv2[ns];
            float2 v = xf2[(size_t)ns * 64 + lane];
            a0 += dk * v.x; a1 += dk * v.y;
        }
    }
    float dn = dinv2[m];
    float self = dn * dn;
    float2 xs = xf2[(size_t)m * 64 + lane];
    float2 bb = ((const float2*)b2)[lane];
    float o0 = fmaxf(dn * a0 + self * xs.x + bb.x, 0.f);
    float o1 = fmaxf(dn * a1 + self * xs.y + bb.y, 0.f);
    atomicAdd(&pr[lane * 2], o0);
    atomicAdd(&pr[lane * 2 + 1], o1);
    __syncthreads();
    if (tid < HD) atomicAdd(&pooled[g * HD + tid], pr[tid]);
}

// ---------------- final linear: out = (pooled/512) @ Wl + bl -----------------
__global__ __launch_bounds__(128) void outk_kernel(const float* __restrict__ pooled,
                                                   const float* __restrict__ Wl,
                                                   const float* __restrict__ bl,
                                                   void* __restrict__ outv,
                                                   const int* __restrict__ flag) {
    int g = blockIdx.x, t = threadIdx.x;  // 128
    __shared__ float sp[HD];
    sp[t] = pooled[g * HD + t] * (1.0f / KEEP);
    __syncthreads();
    if (t < NC) {
        float acc = bl[t];
        for (int hh = 0; hh < HD; hh++) acc += sp[hh] * Wl[hh * NC + t];
        if (flag[0]) ((unsigned short*)outv)[g * NC + t] = f2bf(acc);
        else         ((float*)outv)[g * NC + t] = acc;
    }
}

extern "C" void kernel_launch(void* const* d_in, const int* in_sizes, int n_in,
                              void* d_out, int out_size, void* d_ws, size_t ws_size,
                              hipStream_t stream) {
    const int* ei   = (const int*)d_in[1];
    const int* srcv = ei;
    const int* dstv = ei + NEDGES;

    char* w = (char*)d_ws;
    const size_t MB = 1u << 20;
    const size_t KB = 1024;
    float* dinv1     = (float*)(w + 0);                 // 256 KB
    float* score     = (float*)(w + 256 * KB);          // 256 KB
    float* vals      = (float*)(w + 512 * KB);          // 128 KB
    int*   perm      = (int*)(w + 640 * KB);            // 128 KB
    int*   new_id    = (int*)(w + 768 * KB);            // 256 KB
    int*   deg1      = (int*)(w + 1024 * KB);           // 256 KB
    int*   node_base = (int*)(w + 1280 * KB);           // 256 KB
    float* dinv2     = (float*)(w + 1536 * KB);         // 128 KB
    float* invnorm   = (float*)(w + 1664 * KB);
    int*   flag      = (int*)(w + 1664 * KB + 64);
    int*   ghist     = (int*)(w + 1664 * KB + 1024);
    int*   gcur0     = (int*)(w + 1664 * KB + 2048);
    float* cw        = (float*)(w + 1700 * KB);         // 135 KB canonical weights
    float* pooled    = (float*)(w + 1840 * KB);         // 32 KB
    unsigned int* xw1b = (unsigned int*)(w + 2 * MB);   // [2,18) MB  bf16-packed xw1
    float* xw2  = (float*)(w + 18 * MB);                // [18,34) MB
    float* agg  = (float*)(w + 34 * MB);                // [34,66) MB  (h)
    unsigned int* elist    = (unsigned int*)(w + 66 * MB);   // [66,70) MB
    unsigned short* csr16  = (unsigned short*)(w + 70 * MB); // [70,72) MB

    float* W1f = cw + OW1; float* W2f = cw + OW2; float* Wlf = cw + OWL;
    float* b1f = cw + OB1; float* b2f = cw + OB2; float* pf  = cw + OP;
    float* blf = cw + OBL;

    prep_kernel<<<392, 256, 0, stream>>>(d_in[3], d_in[4], d_in[5], d_in[6], d_in[7],
                                         d_in[8], d_in[9], flag, cw, invnorm, new_id,
                                         ghist, gcur0, pooled);
    hist_kernel<<<256, 256, 0, stream>>>(srcv, ghist);
    binpass_kernel<<<256, 256, 0, stream>>>(srcv, dstv, ghist, gcur0, elist);
    gemm_a_kernel<<<NNODES / 64, 256, 0, stream>>>(d_in[0], W1f, xw1b, flag);
    csr_sort_kernel<<<NGRAPH, 1024, 0, stream>>>(elist, ghist, csr16, node_base,
                                                 deg1, dinv1);
    s1_pull<<<NNODES / 4, 256, 0, stream>>>(csr16, node_base, deg1, dinv1, xw1b, b1f, pf,
                                            invnorm, agg, score);
    topk_kernel<<<NGRAPH, 1024, 0, stream>>>(score, elist, ghist, vals, perm,
                                             new_id, dinv2);
    gemm_gather<<<M2 / 64, 256, 0, stream>>>(agg, perm, vals, W2f, xw2);
    s2_pull<<<M2 / 4, 256, 0, stream>>>(csr16, node_base, deg1, perm, new_id, dinv2,
                                        xw2, b2f, pooled);
    outk_kernel<<<NGRAPH, 128, 0, stream>>>(pooled, Wlf, blf, d_out, flag);

    (void)in_sizes; (void)n_in; (void)out_size; (void)ws_size;
}